// Round 6
// baseline (1260.980 us; speedup 1.0000x reference)
//
#include <hip/hip_runtime.h>
#include <hip/hip_bf16.h>

// ---------------------------------------------------------------------------
// DGCNN-ish network, B=16, N=128, K=20.  (R16: dispatch-count reduction)
// R15 budget analysis: per-kernel work sums to ~250us of 590 -> the serial
// ~40-dispatch chain (launch gaps) is the dominant remaining cost.
// Tier P2 (ws >= ~77MB, observed ws ~268MB via harness fill size):
//   - ONE fused convert+pack_all launch (all 5 weight packs are activation-
//     independent; each gets a private PACK region).           (-5 launches)
//   - topk || gemm fused per edge block (independent; Gram moved to a
//     dedicated GRAM2 buffer so gemm's PS writes can't race topk). (-4)
//   - se1+se2 fused (z in LDS; exact same lane/reduce order).     (-4)
//   40 -> 27 dispatches. All arithmetic bit-identical to R15.
// Tier P: R15 path (fallback if ws smaller). Tier A/B: R5 fallbacks.
// ---------------------------------------------------------------------------

#define BN_ALL 2048   // B*N = 16*128
typedef __hip_bfloat16 bf16;
typedef __attribute__((ext_vector_type(8))) short short8;
typedef __attribute__((ext_vector_type(4))) float float4v;

__device__ __forceinline__ float b2f(bf16 v) { return __bfloat162float(v); }
__device__ __forceinline__ float lrelu(float v) { return v >= 0.f ? v : 0.2f * v; }
__device__ __forceinline__ short f2bs(float v) {
    bf16 h = __float2bfloat16(v);
    return *reinterpret_cast<short*>(&h);
}

// async 16-byte global->LDS DMA. LDS dest must be linear in lane.
__device__ __forceinline__ void gll16(const void* g, void* l) {
    __builtin_amdgcn_global_load_lds(
        (const __attribute__((address_space(1))) unsigned int*)g,
        (__attribute__((address_space(3))) unsigned int*)l,
        16, 0, 0);
}

// dual-dtype input load: isb=1 -> bf16, isb=0 -> f32
__device__ __forceinline__ float ldin(const void* p, size_t i, int isb) {
    return isb ? __bfloat162float(((const bf16*)p)[i]) : ((const float*)p)[i];
}

__device__ __forceinline__ float ld1(const float* p) { return *p; }
__device__ __forceinline__ float ld1(const bf16* p)  { return __bfloat162float(*p); }
__device__ __forceinline__ void st1(float* p, float v) { *p = v; }
__device__ __forceinline__ void st1(bf16* p, float v)  { *p = __float2bfloat16(v); }

// ---- dtype detection: sample 4096 dwords of x; f32 data -> sane exponents ---
__global__ __launch_bounds__(256) void detect_dtype(const void* __restrict__ x, int* __restrict__ flag) {
    const unsigned* u = (const unsigned*)x;
    int sane = 0;
    for (int i = threadIdx.x; i < 4096; i += 256) {
        unsigned e = (u[i] >> 23) & 0xFF;
        sane += (e >= 87 && e <= 167) ? 1 : 0;   // |v| in [2^-40, 2^40]
    }
    __shared__ int sh[256];
    sh[threadIdx.x] = sane;
    __syncthreads();
    for (int off = 128; off > 0; off >>= 1) {
        if (threadIdx.x < off) sh[threadIdx.x] += sh[threadIdx.x + off];
        __syncthreads();
    }
    if (threadIdx.x == 0) *flag = (sh[0] < 2048) ? 1 : 0;   // 1 = bf16, 0 = f32
}

// ---- convert core: input x (B,C,N) -> X0 k-packed bf16 ----------------------
__device__ __forceinline__ void convert_core(int bid, int tid, const void* __restrict__ x,
                                             bf16* __restrict__ X0, int isb) {
    int item = bid * 256 + tid;   // cg*2048 + bn  (cg = c/8)
    int cg = item >> 11, bn = item & 2047;
    int b = bn >> 7, n = bn & 127;
    short8 pk;
#pragma unroll
    for (int j = 0; j < 8; ++j)
        pk[j] = f2bs(ldin(x, ((size_t)(b * 512 + cg * 8 + j)) * 128 + n, isb));
    *(short8*)((short*)X0 + ((size_t)cg * BN_ALL + bn) * 8) = pk;
}

__global__ __launch_bounds__(256) void convert_kp(const void* __restrict__ x, bf16* __restrict__ X0,
                                                  const int* __restrict__ dflag) {
    convert_core(blockIdx.x, threadIdx.x, x, X0, *dflag);
}

// ---- pack core: f32/bf16 weights -> bf16 in LDS-tile image ------------------
__device__ __forceinline__ void pack_core(int item, int isb, const void* __restrict__ w, int ldw,
                                          const void* __restrict__ res, int Cin, int O,
                                          int Mtot, int K, short* __restrict__ out) {
    if (item >= Mtot * (K >> 3)) return;
    int m_local = item & 127;
    int rest = item >> 7;            // (tm*KC + kc)*4 + q
    int q = rest & 3; rest >>= 2;
    int KC = K >> 5;
    int kc = rest % KC, tm = rest / KC;
    int grow = tm * 128 + m_local;
    int k = kc * 32 + q * 8;
    const void* src; size_t base; int dif = 0;
    if (grow < O)          { src = w;   base = (size_t)grow * ldw + k; }
    else if (grow < 2 * O) { src = w;   base = (size_t)(grow - O) * ldw + k; dif = 1; }
    else                   { src = res; base = (size_t)(grow - 2 * O) * Cin + k; }
    short8 pk;
#pragma unroll
    for (int j = 0; j < 8; ++j) {
        float v = ldin(src, base + j, isb);
        if (dif) v = ldin(src, base + Cin + j, isb) - v;
        pk[j] = f2bs(v);
    }
    *(short8*)&out[(size_t)item * 8] = pk;
}

__global__ __launch_bounds__(256) void pack_w(const void* __restrict__ w, int ldw,
                                              const void* __restrict__ res, int Cin, int O,
                                              int Mtot, int K, short* __restrict__ out,
                                              const int* __restrict__ dflag) {
    pack_core(blockIdx.x * 256 + threadIdx.x, *dflag, w, ldw, res, Cin, O, Mtot, K, out);
}

// ---- fused convert + ALL weight packs (tier P2) -----------------------------
// blocks [0,512): convert; [512,768): p1; [768,1152): p2; [1152,1920): p3;
// [1920,3456): p4; [3456,6528): p5.
__global__ __launch_bounds__(256) void convert_pack_all(
        const void* __restrict__ x, bf16* __restrict__ X0,
        const void* __restrict__ w1c, const void* __restrict__ w2c, const void* __restrict__ w3c,
        const void* __restrict__ w4c, const void* __restrict__ w5c,
        const void* __restrict__ r1, const void* __restrict__ r2, const void* __restrict__ r3,
        short* __restrict__ p1, short* __restrict__ p2, short* __restrict__ p3,
        short* __restrict__ p4, short* __restrict__ p5,
        const int* __restrict__ dflag) {
    int isb = *dflag;
    int bid = blockIdx.x, tid = threadIdx.x;
    if (bid < 512) { convert_core(bid, tid, x, X0, isb); return; }
    int pb = bid - 512;
    if (pb < 256)       pack_core(pb * 256 + tid,          isb, w1c, 1024, nullptr, 512, 512, 1024, 512, p1);
    else if (pb < 640)  pack_core((pb - 256) * 256 + tid,  isb, w2c, 1024, r1,      512, 512, 1536, 512, p2);
    else if (pb < 1408) pack_core((pb - 640) * 256 + tid,  isb, w3c, 1024, r2,      512, 1024, 3072, 512, p3);
    else if (pb < 2944) pack_core((pb - 1408) * 256 + tid, isb, w4c, 2048, r3,      1024, 1024, 3072, 1024, p4);
    else                pack_core((pb - 2944) * 256 + tid, isb, w5c, 3072, nullptr, 3072, 2048, 2048, 3072, p5);
}

// ---- Gram via MFMA from k-packed X; one block per batch ---------------------
__global__ __launch_bounds__(256) void gram_k(const bf16* __restrict__ X, int C,
                                              float* __restrict__ G) {
    __shared__ __align__(16) short Bsm[2][8192];   // 128 points x 64 k
    int tid = threadIdx.x;
    int b = blockIdx.x;
    int lane = tid & 63, wv = tid >> 6, wm = wv & 1, wn = wv >> 1;
    int lq = lane >> 4, lr = lane & 15;
    int KC = C >> 6;
    const short* Xs = (const short*)X;

    float4v acc[4][4];
#pragma unroll
    for (int i = 0; i < 4; i++)
#pragma unroll
        for (int j = 0; j < 4; j++) acc[i][j] = (float4v){0.f, 0.f, 0.f, 0.f};

#pragma unroll
    for (int it = 0; it < 4; ++it) {
        int i = tid + it * 256;
        int q = i >> 7, c = i & 127;
        gll16(Xs + ((size_t)q * BN_ALL + b * 128 + c) * 8, &Bsm[0][(size_t)i * 8]);
    }
    __syncthreads();

    int p = 0;
    for (int kc = 0; kc < KC; ++kc) {
        if (kc + 1 < KC) {
#pragma unroll
            for (int it = 0; it < 4; ++it) {
                int i = tid + it * 256;
                int q = i >> 7, c = i & 127;
                gll16(Xs + ((size_t)((kc + 1) * 8 + q) * BN_ALL + b * 128 + c) * 8,
                      &Bsm[p ^ 1][(size_t)i * 8]);
            }
        }
#pragma unroll
        for (int h = 0; h < 2; ++h) {
            short8 av[4], bv[4];
#pragma unroll
            for (int mt = 0; mt < 4; ++mt)
                av[mt] = *(const short8*)&Bsm[p][(size_t)(h * 512 + (lq << 7) + wm * 64 + mt * 16 + lr) * 8];
#pragma unroll
            for (int nt = 0; nt < 4; ++nt)
                bv[nt] = *(const short8*)&Bsm[p][(size_t)(h * 512 + (lq << 7) + wn * 64 + nt * 16 + lr) * 8];
#pragma unroll
            for (int mt = 0; mt < 4; ++mt)
#pragma unroll
                for (int nt = 0; nt < 4; ++nt)
                    acc[mt][nt] = __builtin_amdgcn_mfma_f32_16x16x32_bf16(av[mt], bv[nt], acc[mt][nt], 0, 0, 0);
        }
        __syncthreads();
        p ^= 1;
    }

    float* Gb = G + (size_t)b * 16384;
#pragma unroll
    for (int mt = 0; mt < 4; ++mt)
#pragma unroll
        for (int r = 0; r < 4; ++r) {
            int row = wm * 64 + mt * 16 + lq * 4 + r;
#pragma unroll
            for (int nt = 0; nt < 4; ++nt) {
                int col = wn * 64 + nt * 16 + lr;
                Gb[row * 128 + col] = acc[mt][nt][r];
            }
        }
}

// ---- top-20 core: one wave per (b,n) row; ties -> lower index ---------------
__device__ __forceinline__ void topk_core(int bid, int tid, const float* __restrict__ G,
                                          int* __restrict__ idx) {
    int gw = (bid * 256 + tid) >> 6;   // 0..2047 = b*128+n
    int lane = tid & 63;
    int b = gw >> 7, n = gw & 127;
    const float* Gb = G + (size_t)b * 16384;
    float g0 = Gb[n * 128 + lane];
    float g1 = Gb[n * 128 + 64 + lane];
    float dnn = Gb[n * 129];
    float dm0 = Gb[lane * 129];
    float dm1 = Gb[(64 + lane) * 129];
    float d0 = 2.f * g0 - dnn - dm0;
    float d1 = 2.f * g1 - dnn - dm1;
#pragma unroll
    for (int k = 0; k < 20; ++k) {
        float v; int i;
        if (d1 > d0) { v = d1; i = 64 + lane; } else { v = d0; i = lane; }
#pragma unroll
        for (int off = 1; off < 64; off <<= 1) {
            float ov = __shfl_xor(v, off, 64);
            int   oi = __shfl_xor(i, off, 64);
            if (ov > v || (ov == v && oi < i)) { v = ov; i = oi; }
        }
        if (lane == 0) idx[gw * 20 + k] = i;
        if (i < 64) { if (lane == i) d0 = -3.0e38f; }
        else        { if (lane == i - 64) d1 = -3.0e38f; }
    }
}

__global__ __launch_bounds__(256) void topk_k(const float* __restrict__ G, int* __restrict__ idx) {
    topk_core(blockIdx.x, threadIdx.x, G, idx);
}

// ---- gemm core: packed-A / k-packed-B bf16 MFMA, 128x64 tile, BK=64 ---------
// R12 form: staging via global_load_lds double-buffer; 16 MFMA/wave/barrier.
__device__ __forceinline__ void gemm_core(int bx, int by, int tid,
        const short* __restrict__ packA, const bf16* __restrict__ X,
        float* __restrict__ Cm, int K,
        const void* __restrict__ bnS, const void* __restrict__ bnB,
        int act, const int* __restrict__ dflag) {
    __shared__ __align__(16) short Asm[2][8192];   // 128 rows x 64 k (bf16)
    __shared__ __align__(16) short Bsm[2][4096];   // [(q*64 + c)*8 + j], q=0..7
    int bm  = bx << 7;
    int bn0 = by << 6;
    int lane = tid & 63, wv = tid >> 6, wm = wv & 1, wn = wv >> 1;
    int lq = lane >> 4, lr = lane & 15;
    int KC = K >> 6;
    const short* abase = packA + (size_t)bx * (K >> 5) * 4096;
    const short* Xs = (const short*)X;
    int bq = tid >> 6, bc = tid & 63;

    float4v acc[4][2];
#pragma unroll
    for (int i = 0; i < 4; i++)
#pragma unroll
        for (int j = 0; j < 2; j++) acc[i][j] = (float4v){0.f, 0.f, 0.f, 0.f};

#pragma unroll
    for (int it = 0; it < 4; ++it)
        gll16(abase + (size_t)(tid + it * 256) * 8, &Asm[0][(size_t)(tid + it * 256) * 8]);
    gll16(Xs + ((size_t)bq * BN_ALL + bn0 + bc) * 8,       &Bsm[0][(size_t)tid * 8]);
    gll16(Xs + ((size_t)(bq + 4) * BN_ALL + bn0 + bc) * 8, &Bsm[0][(size_t)(tid + 256) * 8]);
    __syncthreads();

    int p = 0;
    for (int kc = 0; kc < KC; ++kc) {
        if (kc + 1 < KC) {
            const short* ab = abase + (size_t)(kc + 1) * 8192;
#pragma unroll
            for (int it = 0; it < 4; ++it)
                gll16(ab + (size_t)(tid + it * 256) * 8, &Asm[p ^ 1][(size_t)(tid + it * 256) * 8]);
            gll16(Xs + ((size_t)((kc + 1) * 8 + bq) * BN_ALL + bn0 + bc) * 8,
                  &Bsm[p ^ 1][(size_t)tid * 8]);
            gll16(Xs + ((size_t)((kc + 1) * 8 + bq + 4) * BN_ALL + bn0 + bc) * 8,
                  &Bsm[p ^ 1][(size_t)(tid + 256) * 8]);
        }
#pragma unroll
        for (int h = 0; h < 2; ++h) {
            short8 av[4], bv[2];
#pragma unroll
            for (int mt = 0; mt < 4; ++mt)
                av[mt] = *(const short8*)&Asm[p][(size_t)(h * 512 + (lq << 7) + wm * 64 + mt * 16 + lr) * 8];
#pragma unroll
            for (int nt = 0; nt < 2; ++nt)
                bv[nt] = *(const short8*)&Bsm[p][(size_t)(h * 256 + (lq << 6) + wn * 32 + nt * 16 + lr) * 8];
#pragma unroll
            for (int mt = 0; mt < 4; ++mt)
#pragma unroll
                for (int nt = 0; nt < 2; ++nt)
                    acc[mt][nt] = __builtin_amdgcn_mfma_f32_16x16x32_bf16(av[mt], bv[nt], acc[mt][nt], 0, 0, 0);
        }
        __syncthreads();
        p ^= 1;
    }

    int isb = *dflag;
#pragma unroll
    for (int mt = 0; mt < 4; ++mt) {
#pragma unroll
        for (int r = 0; r < 4; ++r) {
            int row = bm + wm * 64 + mt * 16 + lq * 4 + r;
            float s = 1.f, bb = 0.f;
            if (bnS) { s = ldin(bnS, row, isb); bb = ldin(bnB, row, isb); }
#pragma unroll
            for (int nt = 0; nt < 2; ++nt) {
                int col = bn0 + wn * 32 + nt * 16 + lr;
                float v = acc[mt][nt][r];
                if (bnS) v = v * s + bb;
                if (act) v = lrelu(v);
                Cm[(size_t)row * BN_ALL + col] = v;
            }
        }
    }
}

__global__ __launch_bounds__(256) void gemm_pk(const short* __restrict__ packA,
                                               const bf16* __restrict__ X, float* __restrict__ Cm, int K,
                                               const void* __restrict__ bnS, const void* __restrict__ bnB,
                                               int act, const int* __restrict__ dflag) {
    gemm_core(blockIdx.x, blockIdx.y, threadIdx.x, packA, X, Cm, K, bnS, bnB, act, dflag);
}

// ---- fused topk || gemm (tier P2): blocks [0,512)=topk, rest=gemm -----------
// topk reads GRAM2 (dedicated buffer), gemm writes PS -> no overlap.
__global__ __launch_bounds__(256) void topk_gemm_k(const float* __restrict__ G, int* __restrict__ idx,
                                                   const short* __restrict__ packA,
                                                   const bf16* __restrict__ X, float* __restrict__ Cm,
                                                   int K, const int* __restrict__ dflag) {
    if (blockIdx.x < 512) {
        topk_core(blockIdx.x, threadIdx.x, G, idx);
    } else {
        int g = blockIdx.x - 512;
        gemm_core(g >> 5, g & 31, threadIdx.x, packA, X, Cm, K, nullptr, nullptr, 0, dflag);
    }
}

// ---- legacy kNN (fallback tiers) --------------------------------------------
template <typename S>
__global__ __launch_bounds__(128) void knn_topk(const S* __restrict__ X, int C, int* __restrict__ idx) {
    int b = blockIdx.x >> 7;
    int n = blockIdx.x & 127;
    int m = threadIdx.x;
    const S* base = X + b * 128;
    float s0 = 0, s1 = 0, q0 = 0, q1 = 0;
    for (int c = 0; c < C; c += 2) {
        const S* p = base + (size_t)c * BN_ALL;
        float xm0 = ld1(p + m),          xn0 = ld1(p + n);
        float xm1 = ld1(p + BN_ALL + m), xn1 = ld1(p + BN_ALL + n);
        s0 += xm0 * xn0; q0 += xm0 * xm0;
        s1 += xm1 * xn1; q1 += xm1 * xm1;
    }
    float inner = s0 + s1;
    float xxm   = q0 + q1;
    __shared__ float xx[128];
    __shared__ float dist[128];
    __shared__ float rv[128];
    __shared__ int   ri[128];
    xx[m] = xxm;
    __syncthreads();
    dist[m] = 2.0f * inner - xx[n] - xxm;
    for (int k = 0; k < 20; k++) {
        __syncthreads();
        rv[m] = dist[m]; ri[m] = m;
        __syncthreads();
        for (int off = 64; off > 0; off >>= 1) {
            if (m < off) {
                float a = rv[m], bv = rv[m + off];
                int ia = ri[m], ib = ri[m + off];
                if (bv > a || (bv == a && ib < ia)) { rv[m] = bv; ri[m] = ib; }
            }
            __syncthreads();
        }
        if (m == 0) { idx[blockIdx.x * 20 + k] = ri[0]; dist[ri[0]] = -3.0e38f; }
    }
}

// ---- R5 fallback GEMM (on-the-fly staging, 128x128, linear layouts) ---------
template <typename S>
__global__ __launch_bounds__(256) void gemm_mfma(const void* __restrict__ w, int ldw,
                                                 const void* __restrict__ res, int Cin, int O,
                                                 const S* __restrict__ X, S* __restrict__ Cm, int K,
                                                 const void* __restrict__ bnS, const void* __restrict__ bnB,
                                                 int act, const int* __restrict__ dflag) {
    int isb = *dflag;
    __shared__ short Asm[4096];
    __shared__ short Bsm[4096];
    int tid = threadIdx.x;
    int bm  = blockIdx.x << 7;
    int bn0 = blockIdx.y << 7;
    int lane = tid & 63, wv = tid >> 6;
    int wm = wv & 1, wn = wv >> 1;
    int lq = lane >> 4, lr = lane & 15;

    float4v acc[4][4];
#pragma unroll
    for (int i = 0; i < 4; i++)
#pragma unroll
        for (int j = 0; j < 4; j++) acc[i][j] = (float4v){0.f, 0.f, 0.f, 0.f};

    for (int k0 = 0; k0 < K; k0 += 32) {
#pragma unroll
        for (int it = 0; it < 2; ++it) {
            int i = tid + it * 256;
            int m = i >> 2, q = i & 3;
            int grow = bm + m;
            const void* asrc; size_t abase; int dif = 0;
            if (grow < O)          { asrc = w;   abase = (size_t)grow * ldw; }
            else if (grow < 2 * O) { asrc = w;   abase = (size_t)(grow - O) * ldw; dif = 1; }
            else                   { asrc = res; abase = (size_t)(grow - 2 * O) * Cin; }
            size_t kk = (size_t)k0 + q * 8;
            short8 pk;
#pragma unroll
            for (int j = 0; j < 8; ++j) {
                float v = ldin(asrc, abase + kk + j, isb);
                if (dif) v = ldin(asrc, abase + Cin + kk + j, isb) - v;
                pk[j] = f2bs(v);
            }
            *(short8*)&Asm[(size_t)(q * 128 + m) * 8] = pk;
        }
#pragma unroll
        for (int it = 0; it < 2; ++it) {
            int i = tid + it * 256;
            int q = i >> 7, c = i & 127;
            const S* xp = X + (size_t)(k0 + q * 8) * BN_ALL + bn0 + c;
            short8 pk;
#pragma unroll
            for (int j = 0; j < 8; ++j) pk[j] = f2bs(ld1(xp + (size_t)j * BN_ALL));
            *(short8*)&Bsm[(size_t)i * 8] = pk;
        }
        __syncthreads();
        short8 av[4], bv[4];
#pragma unroll
        for (int mt = 0; mt < 4; ++mt)
            av[mt] = *(const short8*)&Asm[(size_t)((lq << 7) + wm * 64 + mt * 16 + lr) * 8];
#pragma unroll
        for (int nt = 0; nt < 4; ++nt)
            bv[nt] = *(const short8*)&Bsm[(size_t)((lq << 7) + wn * 64 + nt * 16 + lr) * 8];
#pragma unroll
        for (int mt = 0; mt < 4; ++mt)
#pragma unroll
            for (int nt = 0; nt < 4; ++nt)
                acc[mt][nt] = __builtin_amdgcn_mfma_f32_16x16x32_bf16(av[mt], bv[nt], acc[mt][nt], 0, 0, 0);
        __syncthreads();
    }
#pragma unroll
    for (int mt = 0; mt < 4; ++mt) {
#pragma unroll
        for (int r = 0; r < 4; ++r) {
            int row = bm + wm * 64 + mt * 16 + lq * 4 + r;
            float s = 1.f, bb = 0.f;
            if (bnS) { s = ldin(bnS, row, isb); bb = ldin(bnB, row, isb); }
#pragma unroll
            for (int nt = 0; nt < 4; ++nt) {
                int col = bn0 + wn * 64 + nt * 16 + lr;
                float v = acc[mt][nt][r];
                if (bnS) v = v * s + bb;
                if (act) v = lrelu(v);
                st1(Cm + (size_t)row * BN_ALL + col, v);
            }
        }
    }
}

// ---- gather + k-pool + bn + lrelu; T written IN-PLACE over P row o ----------
// one WAVE per (o,b) row; 2 n's per lane; barrier-free shfl_xor butterfly.
template <typename S>
__global__ __launch_bounds__(256) void gather_pool(S* __restrict__ PS, const int* __restrict__ idx,
                                                   const void* __restrict__ bns, const void* __restrict__ bnb,
                                                   float* __restrict__ Mb, int O,
                                                   const int* __restrict__ dflag) {
    int isb = *dflag;
    int wv = threadIdx.x >> 6, lane = threadIdx.x & 63;
    int gw = blockIdx.x * 4 + wv;          // gw = o*16 + b
    int o = gw >> 4, b = gw & 15;
    S* Prow = PS + (size_t)o * BN_ALL + b * 128;
    const S* Srow = PS + (size_t)(O + o) * BN_ALL + b * 128;
    int n0 = lane, n1 = lane + 64;
    const int* id0 = idx + (b * 128 + n0) * 20;
    const int* id1 = idx + (b * 128 + n1) * 20;
    float mx0 = -3.0e38f, mn0 = 3.0e38f, sm0 = 0.f;
    float mx1 = -3.0e38f, mn1 = 3.0e38f, sm1 = 0.f;
#pragma unroll
    for (int k = 0; k < 20; k++) {
        float p = ld1(Prow + id0[k]);
        mx0 = fmaxf(mx0, p); mn0 = fminf(mn0, p); sm0 += p;
    }
#pragma unroll
    for (int k = 0; k < 20; k++) {
        float p = ld1(Prow + id1[k]);
        mx1 = fmaxf(mx1, p); mn1 = fminf(mn1, p); sm1 += p;
    }
    float Sv0 = ld1(Srow + n0), Sv1 = ld1(Srow + n1);
    float s = ldin(bns, o, isb), bb = ldin(bnb, o, isb);
    float ext0 = (s >= 0.f) ? mx0 : mn0;
    float ext1 = (s >= 0.f) ? mx1 : mn1;
    float t0 = lrelu(s * (ext0 + Sv0) + bb);
    float t1 = lrelu(s * (ext1 + Sv1) + bb);
    st1(Prow + n0, t0);
    st1(Prow + n1, t1);
    float r1 = sm0 + sm1;    // == halving-tree step off=64
    float r2 = Sv0 + Sv1;
#pragma unroll
    for (int off = 32; off > 0; off >>= 1) {
        r1 += __shfl_xor(r1, off, 64);
        r2 += __shfl_xor(r2, off, 64);
    }
    if (lane == 0) Mb[b * O + o] = s * (r1 * (1.f / 2560.f) + r2 * (1.f / 128.f)) + bb;
}

// ---- SE stage 1: z[b,t] = relu(w1[t,:] . M[b,:]) — one wave per (b,t) -------
__global__ __launch_bounds__(256) void se1_k(const float* __restrict__ Mb, const void* __restrict__ w1,
                                             float* __restrict__ Z, int O, int r,
                                             const int* __restrict__ dflag) {
    int isb = *dflag;
    int gw = (blockIdx.x * 256 + threadIdx.x) >> 6;   // b*r + t
    int lane = threadIdx.x & 63;
    int b = gw / r, t = gw - b * r;
    const float* mv = Mb + (size_t)b * O;
    float acc = 0.f;
    for (int c = lane; c < O; c += 64) acc += ldin(w1, (size_t)t * O + c, isb) * mv[c];
#pragma unroll
    for (int off = 32; off > 0; off >>= 1) acc += __shfl_xor(acc, off, 64);
    if (lane == 0) Z[b * r + t] = fmaxf(acc, 0.f);
}

// ---- SE stage 2: Y[b,o] = sigmoid(w2[o,:] . z[b,:]) — one wave per (b,o) ----
__global__ __launch_bounds__(256) void se2_k(const float* __restrict__ Z, const void* __restrict__ w2,
                                             float* __restrict__ Y, int O, int r,
                                             const int* __restrict__ dflag) {
    int isb = *dflag;
    int gw = (blockIdx.x * 256 + threadIdx.x) >> 6;   // b*O + o
    int lane = threadIdx.x & 63;
    int b = gw / O, o = gw - b * O;
    float acc = 0.f;
    if (lane < r) acc = ldin(w2, (size_t)o * r + lane, isb) * Z[b * r + lane];
#pragma unroll
    for (int off = 32; off > 0; off >>= 1) acc += __shfl_xor(acc, off, 64);
    if (lane == 0) Y[b * O + o] = 1.f / (1.f + expf(-acc));
}

// ---- fused SE (tier P2): one block per batch; z staged in LDS ---------------
// se1 part: wave wv handles t = wv, wv+4, ...: per-t op identical to se1_k
// (same per-lane partial order, same xor-reduce). se2 part: wave wv handles
// o = wv, wv+4, ...: per-o op identical to se2_k. -> bit-identical Y.
__global__ __launch_bounds__(256) void se12_k(const float* __restrict__ Mb, const void* __restrict__ w1,
                                              const void* __restrict__ w2, float* __restrict__ Y,
                                              int O, int r, const int* __restrict__ dflag) {
    int isb = *dflag;
    int b = blockIdx.x;
    __shared__ float ml[1024];
    __shared__ float zz[64];
    for (int i = threadIdx.x; i < O; i += 256) ml[i] = Mb[(size_t)b * O + i];
    __syncthreads();
    int wv = threadIdx.x >> 6, lane = threadIdx.x & 63;
    for (int t = wv; t < r; t += 4) {
        float acc = 0.f;
        for (int c = lane; c < O; c += 64) acc += ldin(w1, (size_t)t * O + c, isb) * ml[c];
#pragma unroll
        for (int off = 32; off > 0; off >>= 1) acc += __shfl_xor(acc, off, 64);
        if (lane == 0) zz[t] = fmaxf(acc, 0.f);
    }
    __syncthreads();
    for (int o = wv; o < O; o += 4) {
        float acc = (lane < r) ? ldin(w2, (size_t)o * r + lane, isb) * zz[lane] : 0.f;
#pragma unroll
        for (int off = 32; off > 0; off >>= 1) acc += __shfl_xor(acc, off, 64);
        if (lane == 0) Y[b * O + o] = 1.f / (1.f + expf(-acc));
    }
}

// ---- legacy SE (fallback tiers) ---------------------------------------------
__global__ __launch_bounds__(256) void se_k(const float* __restrict__ Mb, const void* __restrict__ w1,
                                            const void* __restrict__ w2, float* __restrict__ Y, int O, int r,
                                            const int* __restrict__ dflag) {
    int isb = *dflag;
    int b = blockIdx.x, t = threadIdx.x;
    __shared__ float mloc[1024];
    __shared__ float z[64];
    for (int i = t; i < O; i += 256) mloc[i] = Mb[b * O + i];
    __syncthreads();
    if (t < r) {
        float acc = 0.f;
        for (int c = 0; c < O; c++) acc += ldin(w1, (size_t)t * O + c, isb) * mloc[c];
        z[t] = fmaxf(acc, 0.f);
    }
    __syncthreads();
    for (int o = t; o < O; o += 256) {
        float acc = 0.f;
        for (int j = 0; j < r; j++) acc += ldin(w2, (size_t)o * r + j, isb) * z[j];
        Y[b * O + o] = 1.f / (1.f + expf(-acc));
    }
}

// ---- finalize (tier P): x_next = y*T (+res) -> k-packed bf16 slice ----------
__global__ __launch_bounds__(256) void finalize_kp(const float* __restrict__ PS, const float* __restrict__ Y,
                                                   int useR, bf16* __restrict__ Xdst, int O) {
    int item = blockIdx.x * 256 + threadIdx.x;   // og*2048 + bn  (og = o/8)
    int og = item >> 11, bn = item & 2047;
    int b = bn >> 7;
    short8 pk;
#pragma unroll
    for (int j = 0; j < 8; ++j) {
        int r = og * 8 + j;
        float v = Y[b * O + r] * PS[(size_t)r * BN_ALL + bn];
        if (useR) v += PS[(size_t)(2 * O + r) * BN_ALL + bn];
        pk[j] = f2bs(v);
    }
    *(short8*)((short*)Xdst + ((size_t)og * BN_ALL + bn) * 8) = pk;
}

// ---- legacy finalize (fallback tiers, linear layout) ------------------------
template <typename SP, typename SD>
__global__ __launch_bounds__(256) void finalize(const SP* __restrict__ PS, const float* __restrict__ Y,
                                                int useR, SD* __restrict__ Xdst, int O) {
    int tid = blockIdx.x * 256 + threadIdx.x;   // tid = o*2048 + bn
    int o = tid >> 11, bn = tid & 2047;
    int b = bn >> 7;
    float v = Y[b * O + o] * ld1(PS + tid);
    if (useR) v += ld1(PS + (size_t)(2 * O + o) * BN_ALL + bn);
    st1(Xdst + tid, v);
}

// ---- legacy convert (fallback tiers) ----------------------------------------
template <typename S>
__global__ __launch_bounds__(256) void convert_x(const void* __restrict__ x, S* __restrict__ X0,
                                                 const int* __restrict__ dflag) {
    int isb = *dflag;
    int tid = blockIdx.x * 256 + threadIdx.x;
    int c = tid >> 11, bn = tid & 2047;
    int b = bn >> 7, n = bn & 127;
    st1(X0 + tid, ldin(x, (size_t)(b * 512 + c) * 128 + n, isb));
}

// ---- conv5 pool: one WAVE per (m,b); barrier-free butterfly -----------------
template <typename S>
__global__ __launch_bounds__(256) void pool5(const S* __restrict__ H, float* __restrict__ f) {
    int wv = threadIdx.x >> 6, lane = threadIdx.x & 63;
    int gw = blockIdx.x * 4 + wv;          // gw = m*16 + b
    int m = gw >> 4, b = gw & 15;
    const S* Hp = H + (size_t)m * BN_ALL + b * 128;
    float v0 = ld1(Hp + lane), v1 = ld1(Hp + 64 + lane);
    float mx = fmaxf(v0, v1);
    float sm = v0 + v1;
#pragma unroll
    for (int off = 32; off > 0; off >>= 1) {
        mx = fmaxf(mx, __shfl_xor(mx, off, 64));
        sm += __shfl_xor(sm, off, 64);
    }
    if (lane == 0) {
        f[b * 4096 + m] = mx;
        f[b * 4096 + 2048 + m] = sm * (1.f / 128.f);
    }
}

// ---- head: one wave per (b,o) dot product + optional bias/bn/lrelu ----------
__global__ __launch_bounds__(256) void head_k(const float* __restrict__ in, const void* __restrict__ W,
                                              const void* __restrict__ bias, const void* __restrict__ bns,
                                              const void* __restrict__ bnb, float* __restrict__ outf,
                                              void* __restrict__ outb, int Kd, int Od, int act,
                                              const int* __restrict__ dflag) {
    int isb = *dflag;
    int gw = (blockIdx.x * 256 + threadIdx.x) >> 6;
    int lane = threadIdx.x & 63;
    if (gw >= 16 * Od) return;
    int b = gw / Od, o = gw - b * Od;
    const float* iv = in + b * Kd;
    float acc = 0.f;
    for (int k = lane; k < Kd; k += 64) acc += iv[k] * ldin(W, (size_t)o * Kd + k, isb);
    for (int off = 32; off > 0; off >>= 1) acc += __shfl_xor(acc, off, 64);
    if (lane == 0) {
        float v = acc;
        if (bias) v += ldin(bias, o, isb);
        if (bns) v = v * ldin(bns, o, isb) + ldin(bnb, o, isb);
        if (act) v = lrelu(v);
        if (outb) {
            if (isb) ((bf16*)outb)[gw] = __float2bfloat16(v);
            else     ((float*)outb)[gw] = v;
        } else outf[gw] = v;
    }
}

// ---- ws-too-small signal ----------------------------------------------------
__global__ __launch_bounds__(256) void zero_out(bf16* o, int n) {
    int i = blockIdx.x * 256 + threadIdx.x;
    if (i < n) o[i] = __float2bfloat16(0.f);
}

// ---------------------------------------------------------------------------
#define UNPACK_INPUTS()                                                     \
    const void* x_in   = d_in[0];                                           \
    const void* conv1w = d_in[1];  const void* conv2w = d_in[2];            \
    const void* conv3w = d_in[3];  const void* conv4w = d_in[4];            \
    const void* conv5w = d_in[5];                                           \
    const void* bn1s = d_in[6],  * bn1b = d_in[7];                          \
    const void* bn2s = d_in[8],  * bn2b = d_in[9];                          \
    const void* bn3s = d_in[10], * bn3b = d_in[11];                         \
    const void* bn4s = d_in[12], * bn4b = d_in[13];                         \
    const void* bn5s = d_in[14], * bn5b = d_in[15];                         \
    const void* se1w1 = d_in[16], * se1w2 = d_in[17];                       \
    const void* se2w1 = d_in[18], * se2w2 = d_in[19];                       \
    const void* se3w1 = d_in[20], * se3w2 = d_in[21];                       \
    const void* se4w1 = d_in[22], * se4w2 = d_in[23];                       \
    const void* res1w = d_in[24]; const void* res2w = d_in[25];             \
    const void* res3w = d_in[26]; const void* lin1w = d_in[27];             \
    const void* bn6s = d_in[28], * bn6b = d_in[29];                         \
    const void* lin2w = d_in[30], * lin2b = d_in[31];                       \
    const void* bn7s = d_in[32], * bn7b = d_in[33];                         \
    const void* lin3w = d_in[34], * lin3b = d_in[35];

// ---- Tier P2: all packs upfront, fused topk||gemm, fused SE -----------------
static void run_net_packed2(void* const* d_in, void* d_out, void* d_ws, hipStream_t stream) {
    UNPACK_INPUTS();
    float* WS = (float*)d_ws;
    float* PS = WS;                                   // 3072 x 2048 f32
    bf16*  XC = (bf16*)(WS + 6291456);                // 3072 x 2048 bf16 k-packed
    // private PACK regions (shorts)
    short* P1 = (short*)(WS + 12582912);              // 524288 shorts
    short* P2 = P1 + 524288;                          // 786432
    short* P3 = P2 + 786432;                          // 1572864
    short* P4 = P3 + 1572864;                         // 3145728
    short* P5 = P4 + 3145728;                         // 6291456  (ends @ float 18743296)
    float* MB = WS + 18743296;
    float* YB = MB + 16384;
    float* FB = YB + 16384;
    float* F1 = FB + 65536;
    float* F2 = F1 + 8192;
    int* IDX  = (int*)(F2 + 4096);
    int* DFLAG = IDX + 40960;
    float* ZB = (float*)(DFLAG + 16);
    float* GRAM = WS + 18900000;                      // 262144 floats, dedicated
    bf16*  X0 = (bf16*)(PS + (size_t)2048 * BN_ALL);  // PS rows 2048.. (block 1 only)
    bf16* X1 = XC;
    bf16* X2 = XC + (size_t)512 * BN_ALL;
    bf16* X3 = XC + (size_t)1024 * BN_ALL;
    bf16* X4 = XC + (size_t)2048 * BN_ALL;

    detect_dtype<<<1, 256, 0, stream>>>(x_in, DFLAG);
    convert_pack_all<<<6528, 256, 0, stream>>>(x_in, X0,
        conv1w, conv2w, conv3w, conv4w, conv5w, res1w, res2w, res3w,
        P1, P2, P3, P4, P5, DFLAG);

    // block 1: O=512, Mtot=1024, K=512, r=32
    gram_k<<<16, 256, 0, stream>>>(X0, 512, GRAM);
    topk_gemm_k<<<512 + 8 * 32, 256, 0, stream>>>(GRAM, IDX, P1, X0, PS, 512, DFLAG);
    gather_pool<float><<<2048, 256, 0, stream>>>(PS, IDX, bn1s, bn1b, MB, 512, DFLAG);
    se12_k<<<16, 256, 0, stream>>>(MB, se1w1, se1w2, YB, 512, 32, DFLAG);
    finalize_kp<<<512, 256, 0, stream>>>(PS, YB, 0, X1, 512);

    // block 2: Mtot=1536, K=512, res1, r=32
    gram_k<<<16, 256, 0, stream>>>(X1, 512, GRAM);
    topk_gemm_k<<<512 + 12 * 32, 256, 0, stream>>>(GRAM, IDX, P2, X1, PS, 512, DFLAG);
    gather_pool<float><<<2048, 256, 0, stream>>>(PS, IDX, bn2s, bn2b, MB, 512, DFLAG);
    se12_k<<<16, 256, 0, stream>>>(MB, se2w1, se2w2, YB, 512, 32, DFLAG);
    finalize_kp<<<512, 256, 0, stream>>>(PS, YB, 1, X2, 512);

    // block 3: O=1024, Mtot=3072, K=512, res2, r=64
    gram_k<<<16, 256, 0, stream>>>(X2, 512, GRAM);
    topk_gemm_k<<<512 + 24 * 32, 256, 0, stream>>>(GRAM, IDX, P3, X2, PS, 512, DFLAG);
    gather_pool<float><<<4096, 256, 0, stream>>>(PS, IDX, bn3s, bn3b, MB, 1024, DFLAG);
    se12_k<<<16, 256, 0, stream>>>(MB, se3w1, se3w2, YB, 1024, 64, DFLAG);
    finalize_kp<<<1024, 256, 0, stream>>>(PS, YB, 1, X3, 1024);

    // block 4: O=1024, Mtot=3072, K=1024, res3, r=64
    gram_k<<<16, 256, 0, stream>>>(X3, 1024, GRAM);
    topk_gemm_k<<<512 + 24 * 32, 256, 0, stream>>>(GRAM, IDX, P4, X3, PS, 1024, DFLAG);
    gather_pool<float><<<4096, 256, 0, stream>>>(PS, IDX, bn4s, bn4b, MB, 1024, DFLAG);
    se12_k<<<16, 256, 0, stream>>>(MB, se4w1, se4w2, YB, 1024, 64, DFLAG);
    finalize_kp<<<1024, 256, 0, stream>>>(PS, YB, 1, X4, 1024);

    // conv5: Mtot=2048, K=3072, bn5+lrelu
    gemm_pk<<<dim3(16, 32), 256, 0, stream>>>(P5, XC, PS, 3072, bn5s, bn5b, 1, DFLAG);
    pool5<float><<<8192, 256, 0, stream>>>(PS, FB);

    head_k<<<2048, 256, 0, stream>>>(FB, lin1w, nullptr, bn6s, bn6b, F1, nullptr, 4096, 512, 1, DFLAG);
    head_k<<<1024, 256, 0, stream>>>(F1, lin2w, lin2b, bn7s, bn7b, F2, nullptr, 512, 256, 1, DFLAG);
    head_k<<<160, 256, 0, stream>>>(F2, lin3w, lin3b, nullptr, nullptr, nullptr, d_out, 256, 40, 0, DFLAG);
}

// ---- Tier P: R15 path (fallback when ws < P2 but >= 63MB) -------------------
static void run_net_packed(void* const* d_in, void* d_out, void* d_ws, hipStream_t stream) {
    UNPACK_INPUTS();
    float* WS = (float*)d_ws;
    float* PS   = WS;
    bf16*  XC   = (bf16*)(WS + 6291456);
    short* PACK = (short*)(WS + 12582912);
    float* MB = WS + 15728640;
    float* YB = MB + 16384;
    float* FB = YB + 16384;
    float* F1 = FB + 65536;
    float* F2 = F1 + 8192;
    int* IDX  = (int*)(F2 + 4096);
    int* DFLAG = IDX + 40960;
    float* ZB = (float*)(DFLAG + 16);
    bf16*  X0 = (bf16*)(PS + (size_t)2048 * BN_ALL);
    float* GRAM = PS;
    bf16* X1 = XC;
    bf16* X2 = XC + (size_t)512 * BN_ALL;
    bf16* X3 = XC + (size_t)1024 * BN_ALL;
    bf16* X4 = XC + (size_t)2048 * BN_ALL;

    detect_dtype<<<1, 256, 0, stream>>>(x_in, DFLAG);
    convert_kp<<<512, 256, 0, stream>>>(x_in, X0, DFLAG);

    gram_k<<<16, 256, 0, stream>>>(X0, 512, GRAM);
    topk_k<<<512, 256, 0, stream>>>(GRAM, IDX);
    pack_w<<<256, 256, 0, stream>>>(conv1w, 1024, nullptr, 512, 512, 1024, 512, PACK, DFLAG);
    gemm_pk<<<dim3(8, 32), 256, 0, stream>>>(PACK, X0, PS, 512, nullptr, nullptr, 0, DFLAG);
    gather_pool<float><<<2048, 256, 0, stream>>>(PS, IDX, bn1s, bn1b, MB, 512, DFLAG);
    se1_k<<<128, 256, 0, stream>>>(MB, se1w1, ZB, 512, 32, DFLAG);
    se2_k<<<2048, 256, 0, stream>>>(ZB, se1w2, YB, 512, 32, DFLAG);
    finalize_kp<<<512, 256, 0, stream>>>(PS, YB, 0, X1, 512);

    gram_k<<<16, 256, 0, stream>>>(X1, 512, GRAM);
    topk_k<<<512, 256, 0, stream>>>(GRAM, IDX);
    pack_w<<<384, 256, 0, stream>>>(conv2w, 1024, res1w, 512, 512, 1536, 512, PACK, DFLAG);
    gemm_pk<<<dim3(12, 32), 256, 0, stream>>>(PACK, X1, PS, 512, nullptr, nullptr, 0, DFLAG);
    gather_pool<float><<<2048, 256, 0, stream>>>(PS, IDX, bn2s, bn2b, MB, 512, DFLAG);
    se1_k<<<128, 256, 0, stream>>>(MB, se2w1, ZB, 512, 32, DFLAG);
    se2_k<<<2048, 256, 0, stream>>>(ZB, se2w2, YB, 512, 32, DFLAG);
    finalize_kp<<<512, 256, 0, stream>>>(PS, YB, 1, X2, 512);

    gram_k<<<16, 256, 0, stream>>>(X2, 512, GRAM);
    topk_k<<<512, 256, 0, stream>>>(GRAM, IDX);
    pack_w<<<768, 256, 0, stream>>>(conv3w, 1024, res2w, 512, 1024, 3072, 512, PACK, DFLAG);
    gemm_pk<<<dim3(24, 32), 256, 0, stream>>>(PACK, X2, PS, 512, nullptr, nullptr, 0, DFLAG);
    gather_pool<float><<<4096, 256, 0, stream>>>(PS, IDX, bn3s, bn3b, MB, 1024, DFLAG);
    se1_k<<<256, 256, 0, stream>>>(MB, se3w1, ZB, 1024, 64, DFLAG);
    se2_k<<<4096, 256, 0, stream>>>(ZB, se3w2, YB, 1024, 64, DFLAG);
    finalize_kp<<<1024, 256, 0, stream>>>(PS, YB, 1, X3, 1024);

    gram_k<<<16, 256, 0, stream>>>(X3, 1024, GRAM);
    topk_k<<<512, 256, 0, stream>>>(GRAM, IDX);
    pack_w<<<1536, 256, 0, stream>>>(conv4w, 2048, res3w, 1024, 1024, 3072, 1024, PACK, DFLAG);
    gemm_pk<<<dim3(24, 32), 256, 0, stream>>>(PACK, X3, PS, 1024, nullptr, nullptr, 0, DFLAG);
    gather_pool<float><<<4096, 256, 0, stream>>>(PS, IDX, bn4s, bn4b, MB, 1024, DFLAG);
    se1_k<<<256, 256, 0, stream>>>(MB, se4w1, ZB, 1024, 64, DFLAG);
    se2_k<<<4096, 256, 0, stream>>>(ZB, se4w2, YB, 1024, 64, DFLAG);
    finalize_kp<<<1024, 256, 0, stream>>>(PS, YB, 1, X4, 1024);

    pack_w<<<3072, 256, 0, stream>>>(conv5w, 3072, nullptr, 3072, 2048, 2048, 3072, PACK, DFLAG);
    gemm_pk<<<dim3(16, 32), 256, 0, stream>>>(PACK, XC, PS, 3072, bn5s, bn5b, 1, DFLAG);
    pool5<float><<<8192, 256, 0, stream>>>(PS, FB);

    head_k<<<2048, 256, 0, stream>>>(FB, lin1w, nullptr, bn6s, bn6b, F1, nullptr, 4096, 512, 1, DFLAG);
    head_k<<<1024, 256, 0, stream>>>(F1, lin2w, lin2b, bn7s, bn7b, F2, nullptr, 512, 256, 1, DFLAG);
    head_k<<<160, 256, 0, stream>>>(F2, lin3w, lin3b, nullptr, nullptr, nullptr, d_out, 256, 40, 0, DFLAG);
}

// ---- Tier A/B fallback (R5 path, linear layouts) ----------------------------
template <typename S>
static void run_net(void* const* d_in, void* d_out, void* d_ws, hipStream_t stream) {
    UNPACK_INPUTS();
    const size_t RC = (size_t)3072 * BN_ALL;
    S* PS = (S*)d_ws;
    S* XC = PS + RC;
    S* X0 = PS + (size_t)2048 * BN_ALL;
    float* MB = (float*)(XC + RC);
    float* YB = MB + 16 * 1024;
    float* FB = YB + 16 * 1024;
    float* F1 = FB + 16 * 4096;
    float* F2 = F1 + 16 * 512;
    int* IDX  = (int*)(F2 + 16 * 256);
    int* DFLAG = IDX + 16 * 128 * 20;

    S* X1 = XC;
    S* X2 = XC + (size_t)512 * BN_ALL;
    S* X3 = XC + (size_t)1024 * BN_ALL;
    S* X4 = XC + (size_t)2048 * BN_ALL;

    detect_dtype<<<1, 256, 0, stream>>>(x_in, DFLAG);
    convert_x<S><<<4096, 256, 0, stream>>>(x_in, X0, DFLAG);

    knn_topk<S><<<2048, 128, 0, stream>>>(X0, 512, IDX);
    gemm_mfma<S><<<dim3(8, 16), 256, 0, stream>>>(conv1w, 1024, nullptr, 512, 512, X0, PS, 512, nullptr, nullptr, 0, DFLAG);
    gather_pool<S><<<2048, 256, 0, stream>>>(PS, IDX, bn1s, bn1b, MB, 512, DFLAG);
    se_k<<<16, 256, 0, stream>>>(MB, se1w1, se1w2, YB, 512, 32, DFLAG);
    finalize<S, S><<<4096, 256, 0, stream>>>(PS, YB, 0, X1, 512);

    knn_topk<S><<<2048, 128, 0, stream>>>(X1, 512, IDX);
    gemm_mfma<S><<<dim3(12, 16), 256, 0, stream>>>(conv2w, 1024, res1w, 512, 512, X1, PS, 512, nullptr, nullptr, 0, DFLAG);
    gather_pool<S><<<2048, 256, 0, stream>>>(PS, IDX, bn2s, bn2b, MB, 512, DFLAG);
    se_k<<<16, 256, 0, stream>>>(MB, se2w1, se2w2, YB, 512, 32, DFLAG);
    finalize<S, S><<<4096, 256, 0, stream>>>(PS, YB, 1, X2, 512);

    knn_topk<S><<<2048, 128, 0, stream>>>(X2, 512, IDX);
    gemm_mfma<S><<<dim3(24, 16), 256, 0, stream>>>(conv3w, 1024, res2w, 512, 1024, X2, PS, 512, nullptr, nullptr, 0, DFLAG);
    gather_pool<S><<<4096, 256, 0, stream>>>(PS, IDX, bn3s, bn3b, MB, 1024, DFLAG);
    se_k<<<16, 256, 0, stream>>>(MB, se3w1, se3w2, YB, 1024, 64, DFLAG);
    finalize<S, S><<<8192, 256, 0, stream>>>(PS, YB, 1, X3, 1024);

    knn_topk<S><<<2048, 128, 0, stream>>>(X3, 1024, IDX);
    gemm_mfma<S><<<dim3(24, 16), 256, 0, stream>>>(conv4w, 2048, res3w, 1024, 1024, X3, PS, 1024, nullptr, nullptr, 0, DFLAG);
    gather_pool<S><<<4096, 256, 0, stream>>>(PS, IDX, bn4s, bn4b, MB, 1024, DFLAG);
    se_k<<<16, 256, 0, stream>>>(MB, se4w1, se4w2, YB, 1024, 64, DFLAG);
    finalize<S, S><<<8192, 256, 0, stream>>>(PS, YB, 1, X4, 1024);

    gemm_mfma<S><<<dim3(16, 16), 256, 0, stream>>>(conv5w, 3072, nullptr, 3072, 2048, XC, PS, 3072, bn5s, bn5b, 1, DFLAG);
    pool5<S><<<8192, 256, 0, stream>>>(PS, FB);

    head_k<<<2048, 256, 0, stream>>>(FB, lin1w, nullptr, bn6s, bn6b, F1, nullptr, 4096, 512, 1, DFLAG);
    head_k<<<1024, 256, 0, stream>>>(F1, lin2w, lin2b, bn7s, bn7b, F2, nullptr, 512, 256, 1, DFLAG);
    head_k<<<160, 256, 0, stream>>>(F2, lin3w, lin3b, nullptr, nullptr, nullptr, d_out, 256, 40, 0, DFLAG);
}

extern "C" void kernel_launch(void* const* d_in, const int* in_sizes, int n_in,
                              void* d_out, int out_size, void* d_ws, size_t ws_size,
                              hipStream_t stream) {
    const size_t SMALL = (16 * 1024 + 16 * 1024 + 16 * 4096 + 16 * 512 + 16 * 256) * 4
                       + 16 * 128 * 20 * 4 + 8192;
    const size_t NEED_P2     = ((size_t)18900000 + 262144 + 4096) * 4;   // ~76.7MB
    const size_t NEED_PACKED = (size_t)15728640 * 4 + SMALL;
    const size_t NEED_F32    = 2 * ((size_t)3072 * BN_ALL * 4) + SMALL;
    const size_t NEED_BF16   = 2 * ((size_t)3072 * BN_ALL * 2) + SMALL;
    if (ws_size >= NEED_P2) {
        run_net_packed2(d_in, d_out, d_ws, stream);
    } else if (ws_size >= NEED_PACKED) {
        run_net_packed(d_in, d_out, d_ws, stream);
    } else if (ws_size >= NEED_F32) {
        run_net<float>(d_in, d_out, d_ws, stream);
    } else if (ws_size >= NEED_BF16) {
        run_net<bf16>(d_in, d_out, d_ws, stream);
    } else {
        zero_out<<<3, 256, 0, stream>>>((bf16*)d_out, out_size);
    }
}

// Round 7
// 805.564 us; speedup vs baseline: 1.5653x; 1.5653x over previous
//
#include <hip/hip_runtime.h>
#include <hip/hip_bf16.h>

// ---------------------------------------------------------------------------
// DGCNN-ish network, B=16, N=128, K=20.  (R17: R16 fusions + PARALLEL fused SE)
// R16 post-mortem: se12_k at 16 blocks was 0.75% occupancy -> 257us/call
// (1028 of 1261us). The OTHER fusions worked: rest of net = ~233us (vs ~580
// in R15) -> launch gaps were indeed the dominant cost.
// R17: se12_k chunked to 16b x 16o-chunks = 256 blocks; each block
// recomputes z identically (bit-identical; w1 L2-hot) then handles O/16
// outputs. All other kernels unchanged from R16.
// Tier P: R15 path (fallback). Tier A/B: R5 fallbacks.
// ---------------------------------------------------------------------------

#define BN_ALL 2048   // B*N = 16*128
typedef __hip_bfloat16 bf16;
typedef __attribute__((ext_vector_type(8))) short short8;
typedef __attribute__((ext_vector_type(4))) float float4v;

__device__ __forceinline__ float b2f(bf16 v) { return __bfloat162float(v); }
__device__ __forceinline__ float lrelu(float v) { return v >= 0.f ? v : 0.2f * v; }
__device__ __forceinline__ short f2bs(float v) {
    bf16 h = __float2bfloat16(v);
    return *reinterpret_cast<short*>(&h);
}

// async 16-byte global->LDS DMA. LDS dest must be linear in lane.
__device__ __forceinline__ void gll16(const void* g, void* l) {
    __builtin_amdgcn_global_load_lds(
        (const __attribute__((address_space(1))) unsigned int*)g,
        (__attribute__((address_space(3))) unsigned int*)l,
        16, 0, 0);
}

// dual-dtype input load: isb=1 -> bf16, isb=0 -> f32
__device__ __forceinline__ float ldin(const void* p, size_t i, int isb) {
    return isb ? __bfloat162float(((const bf16*)p)[i]) : ((const float*)p)[i];
}

__device__ __forceinline__ float ld1(const float* p) { return *p; }
__device__ __forceinline__ float ld1(const bf16* p)  { return __bfloat162float(*p); }
__device__ __forceinline__ void st1(float* p, float v) { *p = v; }
__device__ __forceinline__ void st1(bf16* p, float v)  { *p = __float2bfloat16(v); }

// ---- dtype detection: sample 4096 dwords of x; f32 data -> sane exponents ---
__global__ __launch_bounds__(256) void detect_dtype(const void* __restrict__ x, int* __restrict__ flag) {
    const unsigned* u = (const unsigned*)x;
    int sane = 0;
    for (int i = threadIdx.x; i < 4096; i += 256) {
        unsigned e = (u[i] >> 23) & 0xFF;
        sane += (e >= 87 && e <= 167) ? 1 : 0;   // |v| in [2^-40, 2^40]
    }
    __shared__ int sh[256];
    sh[threadIdx.x] = sane;
    __syncthreads();
    for (int off = 128; off > 0; off >>= 1) {
        if (threadIdx.x < off) sh[threadIdx.x] += sh[threadIdx.x + off];
        __syncthreads();
    }
    if (threadIdx.x == 0) *flag = (sh[0] < 2048) ? 1 : 0;   // 1 = bf16, 0 = f32
}

// ---- convert core: input x (B,C,N) -> X0 k-packed bf16 ----------------------
__device__ __forceinline__ void convert_core(int bid, int tid, const void* __restrict__ x,
                                             bf16* __restrict__ X0, int isb) {
    int item = bid * 256 + tid;   // cg*2048 + bn  (cg = c/8)
    int cg = item >> 11, bn = item & 2047;
    int b = bn >> 7, n = bn & 127;
    short8 pk;
#pragma unroll
    for (int j = 0; j < 8; ++j)
        pk[j] = f2bs(ldin(x, ((size_t)(b * 512 + cg * 8 + j)) * 128 + n, isb));
    *(short8*)((short*)X0 + ((size_t)cg * BN_ALL + bn) * 8) = pk;
}

__global__ __launch_bounds__(256) void convert_kp(const void* __restrict__ x, bf16* __restrict__ X0,
                                                  const int* __restrict__ dflag) {
    convert_core(blockIdx.x, threadIdx.x, x, X0, *dflag);
}

// ---- pack core: f32/bf16 weights -> bf16 in LDS-tile image ------------------
__device__ __forceinline__ void pack_core(int item, int isb, const void* __restrict__ w, int ldw,
                                          const void* __restrict__ res, int Cin, int O,
                                          int Mtot, int K, short* __restrict__ out) {
    if (item >= Mtot * (K >> 3)) return;
    int m_local = item & 127;
    int rest = item >> 7;            // (tm*KC + kc)*4 + q
    int q = rest & 3; rest >>= 2;
    int KC = K >> 5;
    int kc = rest % KC, tm = rest / KC;
    int grow = tm * 128 + m_local;
    int k = kc * 32 + q * 8;
    const void* src; size_t base; int dif = 0;
    if (grow < O)          { src = w;   base = (size_t)grow * ldw + k; }
    else if (grow < 2 * O) { src = w;   base = (size_t)(grow - O) * ldw + k; dif = 1; }
    else                   { src = res; base = (size_t)(grow - 2 * O) * Cin + k; }
    short8 pk;
#pragma unroll
    for (int j = 0; j < 8; ++j) {
        float v = ldin(src, base + j, isb);
        if (dif) v = ldin(src, base + Cin + j, isb) - v;
        pk[j] = f2bs(v);
    }
    *(short8*)&out[(size_t)item * 8] = pk;
}

__global__ __launch_bounds__(256) void pack_w(const void* __restrict__ w, int ldw,
                                              const void* __restrict__ res, int Cin, int O,
                                              int Mtot, int K, short* __restrict__ out,
                                              const int* __restrict__ dflag) {
    pack_core(blockIdx.x * 256 + threadIdx.x, *dflag, w, ldw, res, Cin, O, Mtot, K, out);
}

// ---- fused convert + ALL weight packs (tier P2) -----------------------------
// blocks [0,512): convert; [512,768): p1; [768,1152): p2; [1152,1920): p3;
// [1920,3456): p4; [3456,6528): p5.
__global__ __launch_bounds__(256) void convert_pack_all(
        const void* __restrict__ x, bf16* __restrict__ X0,
        const void* __restrict__ w1c, const void* __restrict__ w2c, const void* __restrict__ w3c,
        const void* __restrict__ w4c, const void* __restrict__ w5c,
        const void* __restrict__ r1, const void* __restrict__ r2, const void* __restrict__ r3,
        short* __restrict__ p1, short* __restrict__ p2, short* __restrict__ p3,
        short* __restrict__ p4, short* __restrict__ p5,
        const int* __restrict__ dflag) {
    int isb = *dflag;
    int bid = blockIdx.x, tid = threadIdx.x;
    if (bid < 512) { convert_core(bid, tid, x, X0, isb); return; }
    int pb = bid - 512;
    if (pb < 256)       pack_core(pb * 256 + tid,          isb, w1c, 1024, nullptr, 512, 512, 1024, 512, p1);
    else if (pb < 640)  pack_core((pb - 256) * 256 + tid,  isb, w2c, 1024, r1,      512, 512, 1536, 512, p2);
    else if (pb < 1408) pack_core((pb - 640) * 256 + tid,  isb, w3c, 1024, r2,      512, 1024, 3072, 512, p3);
    else if (pb < 2944) pack_core((pb - 1408) * 256 + tid, isb, w4c, 2048, r3,      1024, 1024, 3072, 1024, p4);
    else                pack_core((pb - 2944) * 256 + tid, isb, w5c, 3072, nullptr, 3072, 2048, 2048, 3072, p5);
}

// ---- Gram via MFMA from k-packed X; one block per batch ---------------------
__global__ __launch_bounds__(256) void gram_k(const bf16* __restrict__ X, int C,
                                              float* __restrict__ G) {
    __shared__ __align__(16) short Bsm[2][8192];   // 128 points x 64 k
    int tid = threadIdx.x;
    int b = blockIdx.x;
    int lane = tid & 63, wv = tid >> 6, wm = wv & 1, wn = wv >> 1;
    int lq = lane >> 4, lr = lane & 15;
    int KC = C >> 6;
    const short* Xs = (const short*)X;

    float4v acc[4][4];
#pragma unroll
    for (int i = 0; i < 4; i++)
#pragma unroll
        for (int j = 0; j < 4; j++) acc[i][j] = (float4v){0.f, 0.f, 0.f, 0.f};

#pragma unroll
    for (int it = 0; it < 4; ++it) {
        int i = tid + it * 256;
        int q = i >> 7, c = i & 127;
        gll16(Xs + ((size_t)q * BN_ALL + b * 128 + c) * 8, &Bsm[0][(size_t)i * 8]);
    }
    __syncthreads();

    int p = 0;
    for (int kc = 0; kc < KC; ++kc) {
        if (kc + 1 < KC) {
#pragma unroll
            for (int it = 0; it < 4; ++it) {
                int i = tid + it * 256;
                int q = i >> 7, c = i & 127;
                gll16(Xs + ((size_t)((kc + 1) * 8 + q) * BN_ALL + b * 128 + c) * 8,
                      &Bsm[p ^ 1][(size_t)i * 8]);
            }
        }
#pragma unroll
        for (int h = 0; h < 2; ++h) {
            short8 av[4], bv[4];
#pragma unroll
            for (int mt = 0; mt < 4; ++mt)
                av[mt] = *(const short8*)&Bsm[p][(size_t)(h * 512 + (lq << 7) + wm * 64 + mt * 16 + lr) * 8];
#pragma unroll
            for (int nt = 0; nt < 4; ++nt)
                bv[nt] = *(const short8*)&Bsm[p][(size_t)(h * 512 + (lq << 7) + wn * 64 + nt * 16 + lr) * 8];
#pragma unroll
            for (int mt = 0; mt < 4; ++mt)
#pragma unroll
                for (int nt = 0; nt < 4; ++nt)
                    acc[mt][nt] = __builtin_amdgcn_mfma_f32_16x16x32_bf16(av[mt], bv[nt], acc[mt][nt], 0, 0, 0);
        }
        __syncthreads();
        p ^= 1;
    }

    float* Gb = G + (size_t)b * 16384;
#pragma unroll
    for (int mt = 0; mt < 4; ++mt)
#pragma unroll
        for (int r = 0; r < 4; ++r) {
            int row = wm * 64 + mt * 16 + lq * 4 + r;
#pragma unroll
            for (int nt = 0; nt < 4; ++nt) {
                int col = wn * 64 + nt * 16 + lr;
                Gb[row * 128 + col] = acc[mt][nt][r];
            }
        }
}

// ---- top-20 core: one wave per (b,n) row; ties -> lower index ---------------
__device__ __forceinline__ void topk_core(int bid, int tid, const float* __restrict__ G,
                                          int* __restrict__ idx) {
    int gw = (bid * 256 + tid) >> 6;   // 0..2047 = b*128+n
    int lane = tid & 63;
    int b = gw >> 7, n = gw & 127;
    const float* Gb = G + (size_t)b * 16384;
    float g0 = Gb[n * 128 + lane];
    float g1 = Gb[n * 128 + 64 + lane];
    float dnn = Gb[n * 129];
    float dm0 = Gb[lane * 129];
    float dm1 = Gb[(64 + lane) * 129];
    float d0 = 2.f * g0 - dnn - dm0;
    float d1 = 2.f * g1 - dnn - dm1;
#pragma unroll
    for (int k = 0; k < 20; ++k) {
        float v; int i;
        if (d1 > d0) { v = d1; i = 64 + lane; } else { v = d0; i = lane; }
#pragma unroll
        for (int off = 1; off < 64; off <<= 1) {
            float ov = __shfl_xor(v, off, 64);
            int   oi = __shfl_xor(i, off, 64);
            if (ov > v || (ov == v && oi < i)) { v = ov; i = oi; }
        }
        if (lane == 0) idx[gw * 20 + k] = i;
        if (i < 64) { if (lane == i) d0 = -3.0e38f; }
        else        { if (lane == i - 64) d1 = -3.0e38f; }
    }
}

__global__ __launch_bounds__(256) void topk_k(const float* __restrict__ G, int* __restrict__ idx) {
    topk_core(blockIdx.x, threadIdx.x, G, idx);
}

// ---- gemm core: packed-A / k-packed-B bf16 MFMA, 128x64 tile, BK=64 ---------
// R12 form: staging via global_load_lds double-buffer; 16 MFMA/wave/barrier.
__device__ __forceinline__ void gemm_core(int bx, int by, int tid,
        const short* __restrict__ packA, const bf16* __restrict__ X,
        float* __restrict__ Cm, int K,
        const void* __restrict__ bnS, const void* __restrict__ bnB,
        int act, const int* __restrict__ dflag) {
    __shared__ __align__(16) short Asm[2][8192];   // 128 rows x 64 k (bf16)
    __shared__ __align__(16) short Bsm[2][4096];   // [(q*64 + c)*8 + j], q=0..7
    int bm  = bx << 7;
    int bn0 = by << 6;
    int lane = tid & 63, wv = tid >> 6, wm = wv & 1, wn = wv >> 1;
    int lq = lane >> 4, lr = lane & 15;
    int KC = K >> 6;
    const short* abase = packA + (size_t)bx * (K >> 5) * 4096;
    const short* Xs = (const short*)X;
    int bq = tid >> 6, bc = tid & 63;

    float4v acc[4][2];
#pragma unroll
    for (int i = 0; i < 4; i++)
#pragma unroll
        for (int j = 0; j < 2; j++) acc[i][j] = (float4v){0.f, 0.f, 0.f, 0.f};

#pragma unroll
    for (int it = 0; it < 4; ++it)
        gll16(abase + (size_t)(tid + it * 256) * 8, &Asm[0][(size_t)(tid + it * 256) * 8]);
    gll16(Xs + ((size_t)bq * BN_ALL + bn0 + bc) * 8,       &Bsm[0][(size_t)tid * 8]);
    gll16(Xs + ((size_t)(bq + 4) * BN_ALL + bn0 + bc) * 8, &Bsm[0][(size_t)(tid + 256) * 8]);
    __syncthreads();

    int p = 0;
    for (int kc = 0; kc < KC; ++kc) {
        if (kc + 1 < KC) {
            const short* ab = abase + (size_t)(kc + 1) * 8192;
#pragma unroll
            for (int it = 0; it < 4; ++it)
                gll16(ab + (size_t)(tid + it * 256) * 8, &Asm[p ^ 1][(size_t)(tid + it * 256) * 8]);
            gll16(Xs + ((size_t)((kc + 1) * 8 + bq) * BN_ALL + bn0 + bc) * 8,
                  &Bsm[p ^ 1][(size_t)tid * 8]);
            gll16(Xs + ((size_t)((kc + 1) * 8 + bq + 4) * BN_ALL + bn0 + bc) * 8,
                  &Bsm[p ^ 1][(size_t)(tid + 256) * 8]);
        }
#pragma unroll
        for (int h = 0; h < 2; ++h) {
            short8 av[4], bv[2];
#pragma unroll
            for (int mt = 0; mt < 4; ++mt)
                av[mt] = *(const short8*)&Asm[p][(size_t)(h * 512 + (lq << 7) + wm * 64 + mt * 16 + lr) * 8];
#pragma unroll
            for (int nt = 0; nt < 2; ++nt)
                bv[nt] = *(const short8*)&Bsm[p][(size_t)(h * 256 + (lq << 6) + wn * 32 + nt * 16 + lr) * 8];
#pragma unroll
            for (int mt = 0; mt < 4; ++mt)
#pragma unroll
                for (int nt = 0; nt < 2; ++nt)
                    acc[mt][nt] = __builtin_amdgcn_mfma_f32_16x16x32_bf16(av[mt], bv[nt], acc[mt][nt], 0, 0, 0);
        }
        __syncthreads();
        p ^= 1;
    }

    int isb = *dflag;
#pragma unroll
    for (int mt = 0; mt < 4; ++mt) {
#pragma unroll
        for (int r = 0; r < 4; ++r) {
            int row = bm + wm * 64 + mt * 16 + lq * 4 + r;
            float s = 1.f, bb = 0.f;
            if (bnS) { s = ldin(bnS, row, isb); bb = ldin(bnB, row, isb); }
#pragma unroll
            for (int nt = 0; nt < 2; ++nt) {
                int col = bn0 + wn * 32 + nt * 16 + lr;
                float v = acc[mt][nt][r];
                if (bnS) v = v * s + bb;
                if (act) v = lrelu(v);
                Cm[(size_t)row * BN_ALL + col] = v;
            }
        }
    }
}

__global__ __launch_bounds__(256) void gemm_pk(const short* __restrict__ packA,
                                               const bf16* __restrict__ X, float* __restrict__ Cm, int K,
                                               const void* __restrict__ bnS, const void* __restrict__ bnB,
                                               int act, const int* __restrict__ dflag) {
    gemm_core(blockIdx.x, blockIdx.y, threadIdx.x, packA, X, Cm, K, bnS, bnB, act, dflag);
}

// ---- fused topk || gemm (tier P2): blocks [0,512)=topk, rest=gemm -----------
// topk reads GRAM (dedicated buffer), gemm writes PS -> no overlap.
__global__ __launch_bounds__(256) void topk_gemm_k(const float* __restrict__ G, int* __restrict__ idx,
                                                   const short* __restrict__ packA,
                                                   const bf16* __restrict__ X, float* __restrict__ Cm,
                                                   int K, const int* __restrict__ dflag) {
    if (blockIdx.x < 512) {
        topk_core(blockIdx.x, threadIdx.x, G, idx);
    } else {
        int g = blockIdx.x - 512;
        gemm_core(g >> 5, g & 31, threadIdx.x, packA, X, Cm, K, nullptr, nullptr, 0, dflag);
    }
}

// ---- legacy kNN (fallback tiers) --------------------------------------------
template <typename S>
__global__ __launch_bounds__(128) void knn_topk(const S* __restrict__ X, int C, int* __restrict__ idx) {
    int b = blockIdx.x >> 7;
    int n = blockIdx.x & 127;
    int m = threadIdx.x;
    const S* base = X + b * 128;
    float s0 = 0, s1 = 0, q0 = 0, q1 = 0;
    for (int c = 0; c < C; c += 2) {
        const S* p = base + (size_t)c * BN_ALL;
        float xm0 = ld1(p + m),          xn0 = ld1(p + n);
        float xm1 = ld1(p + BN_ALL + m), xn1 = ld1(p + BN_ALL + n);
        s0 += xm0 * xn0; q0 += xm0 * xm0;
        s1 += xm1 * xn1; q1 += xm1 * xm1;
    }
    float inner = s0 + s1;
    float xxm   = q0 + q1;
    __shared__ float xx[128];
    __shared__ float dist[128];
    __shared__ float rv[128];
    __shared__ int   ri[128];
    xx[m] = xxm;
    __syncthreads();
    dist[m] = 2.0f * inner - xx[n] - xxm;
    for (int k = 0; k < 20; k++) {
        __syncthreads();
        rv[m] = dist[m]; ri[m] = m;
        __syncthreads();
        for (int off = 64; off > 0; off >>= 1) {
            if (m < off) {
                float a = rv[m], bv = rv[m + off];
                int ia = ri[m], ib = ri[m + off];
                if (bv > a || (bv == a && ib < ia)) { rv[m] = bv; ri[m] = ib; }
            }
            __syncthreads();
        }
        if (m == 0) { idx[blockIdx.x * 20 + k] = ri[0]; dist[ri[0]] = -3.0e38f; }
    }
}

// ---- R5 fallback GEMM (on-the-fly staging, 128x128, linear layouts) ---------
template <typename S>
__global__ __launch_bounds__(256) void gemm_mfma(const void* __restrict__ w, int ldw,
                                                 const void* __restrict__ res, int Cin, int O,
                                                 const S* __restrict__ X, S* __restrict__ Cm, int K,
                                                 const void* __restrict__ bnS, const void* __restrict__ bnB,
                                                 int act, const int* __restrict__ dflag) {
    int isb = *dflag;
    __shared__ short Asm[4096];
    __shared__ short Bsm[4096];
    int tid = threadIdx.x;
    int bm  = blockIdx.x << 7;
    int bn0 = blockIdx.y << 7;
    int lane = tid & 63, wv = tid >> 6;
    int wm = wv & 1, wn = wv >> 1;
    int lq = lane >> 4, lr = lane & 15;

    float4v acc[4][4];
#pragma unroll
    for (int i = 0; i < 4; i++)
#pragma unroll
        for (int j = 0; j < 4; j++) acc[i][j] = (float4v){0.f, 0.f, 0.f, 0.f};

    for (int k0 = 0; k0 < K; k0 += 32) {
#pragma unroll
        for (int it = 0; it < 2; ++it) {
            int i = tid + it * 256;
            int m = i >> 2, q = i & 3;
            int grow = bm + m;
            const void* asrc; size_t abase; int dif = 0;
            if (grow < O)          { asrc = w;   abase = (size_t)grow * ldw; }
            else if (grow < 2 * O) { asrc = w;   abase = (size_t)(grow - O) * ldw; dif = 1; }
            else                   { asrc = res; abase = (size_t)(grow - 2 * O) * Cin; }
            size_t kk = (size_t)k0 + q * 8;
            short8 pk;
#pragma unroll
            for (int j = 0; j < 8; ++j) {
                float v = ldin(asrc, abase + kk + j, isb);
                if (dif) v = ldin(asrc, abase + Cin + kk + j, isb) - v;
                pk[j] = f2bs(v);
            }
            *(short8*)&Asm[(size_t)(q * 128 + m) * 8] = pk;
        }
#pragma unroll
        for (int it = 0; it < 2; ++it) {
            int i = tid + it * 256;
            int q = i >> 7, c = i & 127;
            const S* xp = X + (size_t)(k0 + q * 8) * BN_ALL + bn0 + c;
            short8 pk;
#pragma unroll
            for (int j = 0; j < 8; ++j) pk[j] = f2bs(ld1(xp + (size_t)j * BN_ALL));
            *(short8*)&Bsm[(size_t)i * 8] = pk;
        }
        __syncthreads();
        short8 av[4], bv[4];
#pragma unroll
        for (int mt = 0; mt < 4; ++mt)
            av[mt] = *(const short8*)&Asm[(size_t)((lq << 7) + wm * 64 + mt * 16 + lr) * 8];
#pragma unroll
        for (int nt = 0; nt < 4; ++nt)
            bv[nt] = *(const short8*)&Bsm[(size_t)((lq << 7) + wn * 64 + nt * 16 + lr) * 8];
#pragma unroll
        for (int mt = 0; mt < 4; ++mt)
#pragma unroll
            for (int nt = 0; nt < 4; ++nt)
                acc[mt][nt] = __builtin_amdgcn_mfma_f32_16x16x32_bf16(av[mt], bv[nt], acc[mt][nt], 0, 0, 0);
        __syncthreads();
    }
#pragma unroll
    for (int mt = 0; mt < 4; ++mt) {
#pragma unroll
        for (int r = 0; r < 4; ++r) {
            int row = bm + wm * 64 + mt * 16 + lq * 4 + r;
            float s = 1.f, bb = 0.f;
            if (bnS) { s = ldin(bnS, row, isb); bb = ldin(bnB, row, isb); }
#pragma unroll
            for (int nt = 0; nt < 4; ++nt) {
                int col = bn0 + wn * 64 + nt * 16 + lr;
                float v = acc[mt][nt][r];
                if (bnS) v = v * s + bb;
                if (act) v = lrelu(v);
                st1(Cm + (size_t)row * BN_ALL + col, v);
            }
        }
    }
}

// ---- gather + k-pool + bn + lrelu; T written IN-PLACE over P row o ----------
// one WAVE per (o,b) row; 2 n's per lane; barrier-free shfl_xor butterfly.
template <typename S>
__global__ __launch_bounds__(256) void gather_pool(S* __restrict__ PS, const int* __restrict__ idx,
                                                   const void* __restrict__ bns, const void* __restrict__ bnb,
                                                   float* __restrict__ Mb, int O,
                                                   const int* __restrict__ dflag) {
    int isb = *dflag;
    int wv = threadIdx.x >> 6, lane = threadIdx.x & 63;
    int gw = blockIdx.x * 4 + wv;          // gw = o*16 + b
    int o = gw >> 4, b = gw & 15;
    S* Prow = PS + (size_t)o * BN_ALL + b * 128;
    const S* Srow = PS + (size_t)(O + o) * BN_ALL + b * 128;
    int n0 = lane, n1 = lane + 64;
    const int* id0 = idx + (b * 128 + n0) * 20;
    const int* id1 = idx + (b * 128 + n1) * 20;
    float mx0 = -3.0e38f, mn0 = 3.0e38f, sm0 = 0.f;
    float mx1 = -3.0e38f, mn1 = 3.0e38f, sm1 = 0.f;
#pragma unroll
    for (int k = 0; k < 20; k++) {
        float p = ld1(Prow + id0[k]);
        mx0 = fmaxf(mx0, p); mn0 = fminf(mn0, p); sm0 += p;
    }
#pragma unroll
    for (int k = 0; k < 20; k++) {
        float p = ld1(Prow + id1[k]);
        mx1 = fmaxf(mx1, p); mn1 = fminf(mn1, p); sm1 += p;
    }
    float Sv0 = ld1(Srow + n0), Sv1 = ld1(Srow + n1);
    float s = ldin(bns, o, isb), bb = ldin(bnb, o, isb);
    float ext0 = (s >= 0.f) ? mx0 : mn0;
    float ext1 = (s >= 0.f) ? mx1 : mn1;
    float t0 = lrelu(s * (ext0 + Sv0) + bb);
    float t1 = lrelu(s * (ext1 + Sv1) + bb);
    st1(Prow + n0, t0);
    st1(Prow + n1, t1);
    float r1 = sm0 + sm1;    // == halving-tree step off=64
    float r2 = Sv0 + Sv1;
#pragma unroll
    for (int off = 32; off > 0; off >>= 1) {
        r1 += __shfl_xor(r1, off, 64);
        r2 += __shfl_xor(r2, off, 64);
    }
    if (lane == 0) Mb[b * O + o] = s * (r1 * (1.f / 2560.f) + r2 * (1.f / 128.f)) + bb;
}

// ---- SE stage 1: z[b,t] = relu(w1[t,:] . M[b,:]) — one wave per (b,t) -------
__global__ __launch_bounds__(256) void se1_k(const float* __restrict__ Mb, const void* __restrict__ w1,
                                             float* __restrict__ Z, int O, int r,
                                             const int* __restrict__ dflag) {
    int isb = *dflag;
    int gw = (blockIdx.x * 256 + threadIdx.x) >> 6;   // b*r + t
    int lane = threadIdx.x & 63;
    int b = gw / r, t = gw - b * r;
    const float* mv = Mb + (size_t)b * O;
    float acc = 0.f;
    for (int c = lane; c < O; c += 64) acc += ldin(w1, (size_t)t * O + c, isb) * mv[c];
#pragma unroll
    for (int off = 32; off > 0; off >>= 1) acc += __shfl_xor(acc, off, 64);
    if (lane == 0) Z[b * r + t] = fmaxf(acc, 0.f);
}

// ---- SE stage 2: Y[b,o] = sigmoid(w2[o,:] . z[b,:]) — one wave per (b,o) ----
__global__ __launch_bounds__(256) void se2_k(const float* __restrict__ Z, const void* __restrict__ w2,
                                             float* __restrict__ Y, int O, int r,
                                             const int* __restrict__ dflag) {
    int isb = *dflag;
    int gw = (blockIdx.x * 256 + threadIdx.x) >> 6;   // b*O + o
    int lane = threadIdx.x & 63;
    int b = gw / O, o = gw - b * O;
    float acc = 0.f;
    if (lane < r) acc = ldin(w2, (size_t)o * r + lane, isb) * Z[b * r + lane];
#pragma unroll
    for (int off = 32; off > 0; off >>= 1) acc += __shfl_xor(acc, off, 64);
    if (lane == 0) Y[b * O + o] = 1.f / (1.f + expf(-acc));
}

// ---- fused SE (tier P2, R17): 16 b x 16 o-chunks = 256 blocks ---------------
// Each block recomputes z IDENTICALLY (same per-lane partial order as se1_k;
// w1 is L2-hot so 16x redundancy is cheap), then handles O/16 outputs with
// its 4 waves. Per-o op identical to se2_k -> bit-identical Y.
// R16's 16-block version was 0.75% occupancy -> 257us; this is the fix.
__global__ __launch_bounds__(256) void se12_k(const float* __restrict__ Mb, const void* __restrict__ w1,
                                              const void* __restrict__ w2, float* __restrict__ Y,
                                              int O, int r, const int* __restrict__ dflag) {
    int isb = *dflag;
    int b = blockIdx.x >> 4, chunk = blockIdx.x & 15;
    __shared__ float ml[1024];
    __shared__ float zz[64];
    for (int i = threadIdx.x; i < O; i += 256) ml[i] = Mb[(size_t)b * O + i];
    __syncthreads();
    int wv = threadIdx.x >> 6, lane = threadIdx.x & 63;
    for (int t = wv; t < r; t += 4) {
        float acc = 0.f;
        for (int c = lane; c < O; c += 64) acc += ldin(w1, (size_t)t * O + c, isb) * ml[c];
#pragma unroll
        for (int off = 32; off > 0; off >>= 1) acc += __shfl_xor(acc, off, 64);
        if (lane == 0) zz[t] = fmaxf(acc, 0.f);
    }
    __syncthreads();
    int OC = O >> 4;                       // outputs per chunk (32 or 64)
    int oEnd = chunk * OC + OC;
    for (int o = chunk * OC + wv; o < oEnd; o += 4) {
        float acc = (lane < r) ? ldin(w2, (size_t)o * r + lane, isb) * zz[lane] : 0.f;
#pragma unroll
        for (int off = 32; off > 0; off >>= 1) acc += __shfl_xor(acc, off, 64);
        if (lane == 0) Y[b * O + o] = 1.f / (1.f + expf(-acc));
    }
}

// ---- legacy SE (fallback tiers) ---------------------------------------------
__global__ __launch_bounds__(256) void se_k(const float* __restrict__ Mb, const void* __restrict__ w1,
                                            const void* __restrict__ w2, float* __restrict__ Y, int O, int r,
                                            const int* __restrict__ dflag) {
    int isb = *dflag;
    int b = blockIdx.x, t = threadIdx.x;
    __shared__ float mloc[1024];
    __shared__ float z[64];
    for (int i = t; i < O; i += 256) mloc[i] = Mb[b * O + i];
    __syncthreads();
    if (t < r) {
        float acc = 0.f;
        for (int c = 0; c < O; c++) acc += ldin(w1, (size_t)t * O + c, isb) * mloc[c];
        z[t] = fmaxf(acc, 0.f);
    }
    __syncthreads();
    for (int o = t; o < O; o += 256) {
        float acc = 0.f;
        for (int j = 0; j < r; j++) acc += ldin(w2, (size_t)o * r + j, isb) * z[j];
        Y[b * O + o] = 1.f / (1.f + expf(-acc));
    }
}

// ---- finalize (tier P): x_next = y*T (+res) -> k-packed bf16 slice ----------
__global__ __launch_bounds__(256) void finalize_kp(const float* __restrict__ PS, const float* __restrict__ Y,
                                                   int useR, bf16* __restrict__ Xdst, int O) {
    int item = blockIdx.x * 256 + threadIdx.x;   // og*2048 + bn  (og = o/8)
    int og = item >> 11, bn = item & 2047;
    int b = bn >> 7;
    short8 pk;
#pragma unroll
    for (int j = 0; j < 8; ++j) {
        int r = og * 8 + j;
        float v = Y[b * O + r] * PS[(size_t)r * BN_ALL + bn];
        if (useR) v += PS[(size_t)(2 * O + r) * BN_ALL + bn];
        pk[j] = f2bs(v);
    }
    *(short8*)((short*)Xdst + ((size_t)og * BN_ALL + bn) * 8) = pk;
}

// ---- legacy finalize (fallback tiers, linear layout) ------------------------
template <typename SP, typename SD>
__global__ __launch_bounds__(256) void finalize(const SP* __restrict__ PS, const float* __restrict__ Y,
                                                int useR, SD* __restrict__ Xdst, int O) {
    int tid = blockIdx.x * 256 + threadIdx.x;   // tid = o*2048 + bn
    int o = tid >> 11, bn = tid & 2047;
    int b = bn >> 7;
    float v = Y[b * O + o] * ld1(PS + tid);
    if (useR) v += ld1(PS + (size_t)(2 * O + o) * BN_ALL + bn);
    st1(Xdst + tid, v);
}

// ---- legacy convert (fallback tiers) ----------------------------------------
template <typename S>
__global__ __launch_bounds__(256) void convert_x(const void* __restrict__ x, S* __restrict__ X0,
                                                 const int* __restrict__ dflag) {
    int isb = *dflag;
    int tid = blockIdx.x * 256 + threadIdx.x;
    int c = tid >> 11, bn = tid & 2047;
    int b = bn >> 7, n = bn & 127;
    st1(X0 + tid, ldin(x, (size_t)(b * 512 + c) * 128 + n, isb));
}

// ---- conv5 pool: one WAVE per (m,b); barrier-free butterfly -----------------
template <typename S>
__global__ __launch_bounds__(256) void pool5(const S* __restrict__ H, float* __restrict__ f) {
    int wv = threadIdx.x >> 6, lane = threadIdx.x & 63;
    int gw = blockIdx.x * 4 + wv;          // gw = m*16 + b
    int m = gw >> 4, b = gw & 15;
    const S* Hp = H + (size_t)m * BN_ALL + b * 128;
    float v0 = ld1(Hp + lane), v1 = ld1(Hp + 64 + lane);
    float mx = fmaxf(v0, v1);
    float sm = v0 + v1;
#pragma unroll
    for (int off = 32; off > 0; off >>= 1) {
        mx = fmaxf(mx, __shfl_xor(mx, off, 64));
        sm += __shfl_xor(sm, off, 64);
    }
    if (lane == 0) {
        f[b * 4096 + m] = mx;
        f[b * 4096 + 2048 + m] = sm * (1.f / 128.f);
    }
}

// ---- head: one wave per (b,o) dot product + optional bias/bn/lrelu ----------
__global__ __launch_bounds__(256) void head_k(const float* __restrict__ in, const void* __restrict__ W,
                                              const void* __restrict__ bias, const void* __restrict__ bns,
                                              const void* __restrict__ bnb, float* __restrict__ outf,
                                              void* __restrict__ outb, int Kd, int Od, int act,
                                              const int* __restrict__ dflag) {
    int isb = *dflag;
    int gw = (blockIdx.x * 256 + threadIdx.x) >> 6;
    int lane = threadIdx.x & 63;
    if (gw >= 16 * Od) return;
    int b = gw / Od, o = gw - b * Od;
    const float* iv = in + b * Kd;
    float acc = 0.f;
    for (int k = lane; k < Kd; k += 64) acc += iv[k] * ldin(W, (size_t)o * Kd + k, isb);
    for (int off = 32; off > 0; off >>= 1) acc += __shfl_xor(acc, off, 64);
    if (lane == 0) {
        float v = acc;
        if (bias) v += ldin(bias, o, isb);
        if (bns) v = v * ldin(bns, o, isb) + ldin(bnb, o, isb);
        if (act) v = lrelu(v);
        if (outb) {
            if (isb) ((bf16*)outb)[gw] = __float2bfloat16(v);
            else     ((float*)outb)[gw] = v;
        } else outf[gw] = v;
    }
}

// ---- ws-too-small signal ----------------------------------------------------
__global__ __launch_bounds__(256) void zero_out(bf16* o, int n) {
    int i = blockIdx.x * 256 + threadIdx.x;
    if (i < n) o[i] = __float2bfloat16(0.f);
}

// ---------------------------------------------------------------------------
#define UNPACK_INPUTS()                                                     \
    const void* x_in   = d_in[0];                                           \
    const void* conv1w = d_in[1];  const void* conv2w = d_in[2];            \
    const void* conv3w = d_in[3];  const void* conv4w = d_in[4];            \
    const void* conv5w = d_in[5];                                           \
    const void* bn1s = d_in[6],  * bn1b = d_in[7];                          \
    const void* bn2s = d_in[8],  * bn2b = d_in[9];                          \
    const void* bn3s = d_in[10], * bn3b = d_in[11];                         \
    const void* bn4s = d_in[12], * bn4b = d_in[13];                         \
    const void* bn5s = d_in[14], * bn5b = d_in[15];                         \
    const void* se1w1 = d_in[16], * se1w2 = d_in[17];                       \
    const void* se2w1 = d_in[18], * se2w2 = d_in[19];                       \
    const void* se3w1 = d_in[20], * se3w2 = d_in[21];                       \
    const void* se4w1 = d_in[22], * se4w2 = d_in[23];                       \
    const void* res1w = d_in[24]; const void* res2w = d_in[25];             \
    const void* res3w = d_in[26]; const void* lin1w = d_in[27];             \
    const void* bn6s = d_in[28], * bn6b = d_in[29];                         \
    const void* lin2w = d_in[30], * lin2b = d_in[31];                       \
    const void* bn7s = d_in[32], * bn7b = d_in[33];                         \
    const void* lin3w = d_in[34], * lin3b = d_in[35];

// ---- Tier P2: all packs upfront, fused topk||gemm, parallel fused SE --------
static void run_net_packed2(void* const* d_in, void* d_out, void* d_ws, hipStream_t stream) {
    UNPACK_INPUTS();
    float* WS = (float*)d_ws;
    float* PS = WS;                                   // 3072 x 2048 f32
    bf16*  XC = (bf16*)(WS + 6291456);                // 3072 x 2048 bf16 k-packed
    // private PACK regions (shorts)
    short* P1 = (short*)(WS + 12582912);              // 524288 shorts
    short* P2 = P1 + 524288;                          // 786432
    short* P3 = P2 + 786432;                          // 1572864
    short* P4 = P3 + 1572864;                         // 3145728
    short* P5 = P4 + 3145728;                         // 6291456  (ends @ float 18743296)
    float* MB = WS + 18743296;
    float* YB = MB + 16384;
    float* FB = YB + 16384;
    float* F1 = FB + 65536;
    float* F2 = F1 + 8192;
    int* IDX  = (int*)(F2 + 4096);
    int* DFLAG = IDX + 40960;
    float* GRAM = WS + 18900000;                      // 262144 floats, dedicated
    bf16*  X0 = (bf16*)(PS + (size_t)2048 * BN_ALL);  // PS rows 2048.. (block 1 only)
    bf16* X1 = XC;
    bf16* X2 = XC + (size_t)512 * BN_ALL;
    bf16* X3 = XC + (size_t)1024 * BN_ALL;
    bf16* X4 = XC + (size_t)2048 * BN_ALL;

    detect_dtype<<<1, 256, 0, stream>>>(x_in, DFLAG);
    convert_pack_all<<<6528, 256, 0, stream>>>(x_in, X0,
        conv1w, conv2w, conv3w, conv4w, conv5w, res1w, res2w, res3w,
        P1, P2, P3, P4, P5, DFLAG);

    // block 1: O=512, Mtot=1024, K=512, r=32
    gram_k<<<16, 256, 0, stream>>>(X0, 512, GRAM);
    topk_gemm_k<<<512 + 8 * 32, 256, 0, stream>>>(GRAM, IDX, P1, X0, PS, 512, DFLAG);
    gather_pool<float><<<2048, 256, 0, stream>>>(PS, IDX, bn1s, bn1b, MB, 512, DFLAG);
    se12_k<<<256, 256, 0, stream>>>(MB, se1w1, se1w2, YB, 512, 32, DFLAG);
    finalize_kp<<<512, 256, 0, stream>>>(PS, YB, 0, X1, 512);

    // block 2: Mtot=1536, K=512, res1, r=32
    gram_k<<<16, 256, 0, stream>>>(X1, 512, GRAM);
    topk_gemm_k<<<512 + 12 * 32, 256, 0, stream>>>(GRAM, IDX, P2, X1, PS, 512, DFLAG);
    gather_pool<float><<<2048, 256, 0, stream>>>(PS, IDX, bn2s, bn2b, MB, 512, DFLAG);
    se12_k<<<256, 256, 0, stream>>>(MB, se2w1, se2w2, YB, 512, 32, DFLAG);
    finalize_kp<<<512, 256, 0, stream>>>(PS, YB, 1, X2, 512);

    // block 3: O=1024, Mtot=3072, K=512, res2, r=64
    gram_k<<<16, 256, 0, stream>>>(X2, 512, GRAM);
    topk_gemm_k<<<512 + 24 * 32, 256, 0, stream>>>(GRAM, IDX, P3, X2, PS, 512, DFLAG);
    gather_pool<float><<<4096, 256, 0, stream>>>(PS, IDX, bn3s, bn3b, MB, 1024, DFLAG);
    se12_k<<<256, 256, 0, stream>>>(MB, se3w1, se3w2, YB, 1024, 64, DFLAG);
    finalize_kp<<<1024, 256, 0, stream>>>(PS, YB, 1, X3, 1024);

    // block 4: O=1024, Mtot=3072, K=1024, res3, r=64
    gram_k<<<16, 256, 0, stream>>>(X3, 1024, GRAM);
    topk_gemm_k<<<512 + 24 * 32, 256, 0, stream>>>(GRAM, IDX, P4, X3, PS, 1024, DFLAG);
    gather_pool<float><<<4096, 256, 0, stream>>>(PS, IDX, bn4s, bn4b, MB, 1024, DFLAG);
    se12_k<<<256, 256, 0, stream>>>(MB, se4w1, se4w2, YB, 1024, 64, DFLAG);
    finalize_kp<<<1024, 256, 0, stream>>>(PS, YB, 1, X4, 1024);

    // conv5: Mtot=2048, K=3072, bn5+lrelu
    gemm_pk<<<dim3(16, 32), 256, 0, stream>>>(P5, XC, PS, 3072, bn5s, bn5b, 1, DFLAG);
    pool5<float><<<8192, 256, 0, stream>>>(PS, FB);

    head_k<<<2048, 256, 0, stream>>>(FB, lin1w, nullptr, bn6s, bn6b, F1, nullptr, 4096, 512, 1, DFLAG);
    head_k<<<1024, 256, 0, stream>>>(F1, lin2w, lin2b, bn7s, bn7b, F2, nullptr, 512, 256, 1, DFLAG);
    head_k<<<160, 256, 0, stream>>>(F2, lin3w, lin3b, nullptr, nullptr, nullptr, d_out, 256, 40, 0, DFLAG);
}

// ---- Tier P: R15 path (fallback when ws < P2 but >= 63MB) -------------------
static void run_net_packed(void* const* d_in, void* d_out, void* d_ws, hipStream_t stream) {
    UNPACK_INPUTS();
    float* WS = (float*)d_ws;
    float* PS   = WS;
    bf16*  XC   = (bf16*)(WS + 6291456);
    short* PACK = (short*)(WS + 12582912);
    float* MB = WS + 15728640;
    float* YB = MB + 16384;
    float* FB = YB + 16384;
    float* F1 = FB + 65536;
    float* F2 = F1 + 8192;
    int* IDX  = (int*)(F2 + 4096);
    int* DFLAG = IDX + 40960;
    float* ZB = (float*)(DFLAG + 16);
    bf16*  X0 = (bf16*)(PS + (size_t)2048 * BN_ALL);
    float* GRAM = PS;
    bf16* X1 = XC;
    bf16* X2 = XC + (size_t)512 * BN_ALL;
    bf16* X3 = XC + (size_t)1024 * BN_ALL;
    bf16* X4 = XC + (size_t)2048 * BN_ALL;

    detect_dtype<<<1, 256, 0, stream>>>(x_in, DFLAG);
    convert_kp<<<512, 256, 0, stream>>>(x_in, X0, DFLAG);

    gram_k<<<16, 256, 0, stream>>>(X0, 512, GRAM);
    topk_k<<<512, 256, 0, stream>>>(GRAM, IDX);
    pack_w<<<256, 256, 0, stream>>>(conv1w, 1024, nullptr, 512, 512, 1024, 512, PACK, DFLAG);
    gemm_pk<<<dim3(8, 32), 256, 0, stream>>>(PACK, X0, PS, 512, nullptr, nullptr, 0, DFLAG);
    gather_pool<float><<<2048, 256, 0, stream>>>(PS, IDX, bn1s, bn1b, MB, 512, DFLAG);
    se1_k<<<128, 256, 0, stream>>>(MB, se1w1, ZB, 512, 32, DFLAG);
    se2_k<<<2048, 256, 0, stream>>>(ZB, se1w2, YB, 512, 32, DFLAG);
    finalize_kp<<<512, 256, 0, stream>>>(PS, YB, 0, X1, 512);

    gram_k<<<16, 256, 0, stream>>>(X1, 512, GRAM);
    topk_k<<<512, 256, 0, stream>>>(GRAM, IDX);
    pack_w<<<384, 256, 0, stream>>>(conv2w, 1024, res1w, 512, 512, 1536, 512, PACK, DFLAG);
    gemm_pk<<<dim3(12, 32), 256, 0, stream>>>(PACK, X1, PS, 512, nullptr, nullptr, 0, DFLAG);
    gather_pool<float><<<2048, 256, 0, stream>>>(PS, IDX, bn2s, bn2b, MB, 512, DFLAG);
    se1_k<<<128, 256, 0, stream>>>(MB, se2w1, ZB, 512, 32, DFLAG);
    se2_k<<<2048, 256, 0, stream>>>(ZB, se2w2, YB, 512, 32, DFLAG);
    finalize_kp<<<512, 256, 0, stream>>>(PS, YB, 1, X2, 512);

    gram_k<<<16, 256, 0, stream>>>(X2, 512, GRAM);
    topk_k<<<512, 256, 0, stream>>>(GRAM, IDX);
    pack_w<<<768, 256, 0, stream>>>(conv3w, 1024, res2w, 512, 1024, 3072, 512, PACK, DFLAG);
    gemm_pk<<<dim3(24, 32), 256, 0, stream>>>(PACK, X2, PS, 512, nullptr, nullptr, 0, DFLAG);
    gather_pool<float><<<4096, 256, 0, stream>>>(PS, IDX, bn3s, bn3b, MB, 1024, DFLAG);
    se1_k<<<256, 256, 0, stream>>>(MB, se3w1, ZB, 1024, 64, DFLAG);
    se2_k<<<4096, 256, 0, stream>>>(ZB, se3w2, YB, 1024, 64, DFLAG);
    finalize_kp<<<1024, 256, 0, stream>>>(PS, YB, 1, X3, 1024);

    gram_k<<<16, 256, 0, stream>>>(X3, 1024, GRAM);
    topk_k<<<512, 256, 0, stream>>>(GRAM, IDX);
    pack_w<<<1536, 256, 0, stream>>>(conv4w, 2048, res3w, 1024, 1024, 3072, 1024, PACK, DFLAG);
    gemm_pk<<<dim3(24, 32), 256, 0, stream>>>(PACK, X3, PS, 1024, nullptr, nullptr, 0, DFLAG);
    gather_pool<float><<<4096, 256, 0, stream>>>(PS, IDX, bn4s, bn4b, MB, 1024, DFLAG);
    se1_k<<<256, 256, 0, stream>>>(MB, se4w1, ZB, 1024, 64, DFLAG);
    se2_k<<<4096, 256, 0, stream>>>(ZB, se4w2, YB, 1024, 64, DFLAG);
    finalize_kp<<<1024, 256, 0, stream>>>(PS, YB, 1, X4, 1024);

    pack_w<<<3072, 256, 0, stream>>>(conv5w, 3072, nullptr, 3072, 2048, 2048, 3072, PACK, DFLAG);
    gemm_pk<<<dim3(16, 32), 256, 0, stream>>>(PACK, XC, PS, 3072, bn5s, bn5b, 1, DFLAG);
    pool5<float><<<8192, 256, 0, stream>>>(PS, FB);

    head_k<<<2048, 256, 0, stream>>>(FB, lin1w, nullptr, bn6s, bn6b, F1, nullptr, 4096, 512, 1, DFLAG);
    head_k<<<1024, 256, 0, stream>>>(F1, lin2w, lin2b, bn7s, bn7b, F2, nullptr, 512, 256, 1, DFLAG);
    head_k<<<160, 256, 0, stream>>>(F2, lin3w, lin3b, nullptr, nullptr, nullptr, d_out, 256, 40, 0, DFLAG);
}

// ---- Tier A/B fallback (R5 path, linear layouts) ----------------------------
template <typename S>
static void run_net(void* const* d_in, void* d_out, void* d_ws, hipStream_t stream) {
    UNPACK_INPUTS();
    const size_t RC = (size_t)3072 * BN_ALL;
    S* PS = (S*)d_ws;
    S* XC = PS + RC;
    S* X0 = PS + (size_t)2048 * BN_ALL;
    float* MB = (float*)(XC + RC);
    float* YB = MB + 16 * 1024;
    float* FB = YB + 16 * 1024;
    float* F1 = FB + 16 * 4096;
    float* F2 = F1 + 16 * 512;
    int* IDX  = (int*)(F2 + 16 * 256);
    int* DFLAG = IDX + 16 * 128 * 20;

    S* X1 = XC;
    S* X2 = XC + (size_t)512 * BN_ALL;
    S* X3 = XC + (size_t)1024 * BN_ALL;
    S* X4 = XC + (size_t)2048 * BN_ALL;

    detect_dtype<<<1, 256, 0, stream>>>(x_in, DFLAG);
    convert_x<S><<<4096, 256, 0, stream>>>(x_in, X0, DFLAG);

    knn_topk<S><<<2048, 128, 0, stream>>>(X0, 512, IDX);
    gemm_mfma<S><<<dim3(8, 16), 256, 0, stream>>>(conv1w, 1024, nullptr, 512, 512, X0, PS, 512, nullptr, nullptr, 0, DFLAG);
    gather_pool<S><<<2048, 256, 0, stream>>>(PS, IDX, bn1s, bn1b, MB, 512, DFLAG);
    se_k<<<16, 256, 0, stream>>>(MB, se1w1, se1w2, YB, 512, 32, DFLAG);
    finalize<S, S><<<4096, 256, 0, stream>>>(PS, YB, 0, X1, 512);

    knn_topk<S><<<2048, 128, 0, stream>>>(X1, 512, IDX);
    gemm_mfma<S><<<dim3(12, 16), 256, 0, stream>>>(conv2w, 1024, res1w, 512, 512, X1, PS, 512, nullptr, nullptr, 0, DFLAG);
    gather_pool<S><<<2048, 256, 0, stream>>>(PS, IDX, bn2s, bn2b, MB, 512, DFLAG);
    se_k<<<16, 256, 0, stream>>>(MB, se2w1, se2w2, YB, 512, 32, DFLAG);
    finalize<S, S><<<4096, 256, 0, stream>>>(PS, YB, 1, X2, 512);

    knn_topk<S><<<2048, 128, 0, stream>>>(X2, 512, IDX);
    gemm_mfma<S><<<dim3(24, 16), 256, 0, stream>>>(conv3w, 1024, res2w, 512, 1024, X2, PS, 512, nullptr, nullptr, 0, DFLAG);
    gather_pool<S><<<4096, 256, 0, stream>>>(PS, IDX, bn3s, bn3b, MB, 1024, DFLAG);
    se_k<<<16, 256, 0, stream>>>(MB, se3w1, se3w2, YB, 1024, 64, DFLAG);
    finalize<S, S><<<8192, 256, 0, stream>>>(PS, YB, 1, X3, 1024);

    knn_topk<S><<<2048, 128, 0, stream>>>(X3, 1024, IDX);
    gemm_mfma<S><<<dim3(24, 16), 256, 0, stream>>>(conv4w, 2048, res3w, 1024, 1024, X3, PS, 1024, nullptr, nullptr, 0, DFLAG);
    gather_pool<S><<<4096, 256, 0, stream>>>(PS, IDX, bn4s, bn4b, MB, 1024, DFLAG);
    se_k<<<16, 256, 0, stream>>>(MB, se4w1, se4w2, YB, 1024, 64, DFLAG);
    finalize<S, S><<<8192, 256, 0, stream>>>(PS, YB, 1, X4, 1024);

    gemm_mfma<S><<<dim3(16, 16), 256, 0, stream>>>(conv5w, 3072, nullptr, 3072, 2048, XC, PS, 3072, bn5s, bn5b, 1, DFLAG);
    pool5<S><<<8192, 256, 0, stream>>>(PS, FB);

    head_k<<<2048, 256, 0, stream>>>(FB, lin1w, nullptr, bn6s, bn6b, F1, nullptr, 4096, 512, 1, DFLAG);
    head_k<<<1024, 256, 0, stream>>>(F1, lin2w, lin2b, bn7s, bn7b, F2, nullptr, 512, 256, 1, DFLAG);
    head_k<<<160, 256, 0, stream>>>(F2, lin3w, lin3b, nullptr, nullptr, nullptr, d_out, 256, 40, 0, DFLAG);
}

extern "C" void kernel_launch(void* const* d_in, const int* in_sizes, int n_in,
                              void* d_out, int out_size, void* d_ws, size_t ws_size,
                              hipStream_t stream) {
    const size_t SMALL = (16 * 1024 + 16 * 1024 + 16 * 4096 + 16 * 512 + 16 * 256) * 4
                       + 16 * 128 * 20 * 4 + 8192;
    const size_t NEED_P2     = ((size_t)18900000 + 262144 + 4096) * 4;   // ~76.7MB
    const size_t NEED_PACKED = (size_t)15728640 * 4 + SMALL;
    const size_t NEED_F32    = 2 * ((size_t)3072 * BN_ALL * 4) + SMALL;
    const size_t NEED_BF16   = 2 * ((size_t)3072 * BN_ALL * 2) + SMALL;
    if (ws_size >= NEED_P2) {
        run_net_packed2(d_in, d_out, d_ws, stream);
    } else if (ws_size >= NEED_PACKED) {
        run_net_packed(d_in, d_out, d_ws, stream);
    } else if (ws_size >= NEED_F32) {
        run_net<float>(d_in, d_out, d_ws, stream);
    } else if (ws_size >= NEED_BF16) {
        run_net<bf16>(d_in, d_out, d_ws, stream);
    } else {
        zero_out<<<3, 256, 0, stream>>>((bf16*)d_out, out_size);
    }
}

// Round 8
// 562.034 us; speedup vs baseline: 2.2436x; 1.4333x over previous
//
#include <hip/hip_runtime.h>
#include <hip/hip_bf16.h>

// ---------------------------------------------------------------------------
// DGCNN-ish network, B=16, N=128, K=20.  (R18: R17 fusions + UNFUSED SE)
// R17 post-mortem: fused SE (se12_k) was latency-bound (VALUBusy 3.7%,
// 109us/call, 436us of 805): each wave ran up to 256 SERIAL dependent
// global loads with 4 waves/CU TLP. R15's separate se1_k/se2_k (1 output
// per wave, <=16 serial loads, 1000s of waves) never hit top-5. SE stages
// have a hard z->Y dependency: fusing forces low occupancy or redundant
// serial work. Keep the fusions that worked (convert+pack_all, topk||gemm);
// revert SE to the parallel 2-kernel form. Bit-identical numerics.
// Tier P: R15 path (fallback). Tier A/B: R5 fallbacks.
// ---------------------------------------------------------------------------

#define BN_ALL 2048   // B*N = 16*128
typedef __hip_bfloat16 bf16;
typedef __attribute__((ext_vector_type(8))) short short8;
typedef __attribute__((ext_vector_type(4))) float float4v;

__device__ __forceinline__ float b2f(bf16 v) { return __bfloat162float(v); }
__device__ __forceinline__ float lrelu(float v) { return v >= 0.f ? v : 0.2f * v; }
__device__ __forceinline__ short f2bs(float v) {
    bf16 h = __float2bfloat16(v);
    return *reinterpret_cast<short*>(&h);
}

// async 16-byte global->LDS DMA. LDS dest must be linear in lane.
__device__ __forceinline__ void gll16(const void* g, void* l) {
    __builtin_amdgcn_global_load_lds(
        (const __attribute__((address_space(1))) unsigned int*)g,
        (__attribute__((address_space(3))) unsigned int*)l,
        16, 0, 0);
}

// dual-dtype input load: isb=1 -> bf16, isb=0 -> f32
__device__ __forceinline__ float ldin(const void* p, size_t i, int isb) {
    return isb ? __bfloat162float(((const bf16*)p)[i]) : ((const float*)p)[i];
}

__device__ __forceinline__ float ld1(const float* p) { return *p; }
__device__ __forceinline__ float ld1(const bf16* p)  { return __bfloat162float(*p); }
__device__ __forceinline__ void st1(float* p, float v) { *p = v; }
__device__ __forceinline__ void st1(bf16* p, float v)  { *p = __float2bfloat16(v); }

// ---- dtype detection: sample 4096 dwords of x; f32 data -> sane exponents ---
__global__ __launch_bounds__(256) void detect_dtype(const void* __restrict__ x, int* __restrict__ flag) {
    const unsigned* u = (const unsigned*)x;
    int sane = 0;
    for (int i = threadIdx.x; i < 4096; i += 256) {
        unsigned e = (u[i] >> 23) & 0xFF;
        sane += (e >= 87 && e <= 167) ? 1 : 0;   // |v| in [2^-40, 2^40]
    }
    __shared__ int sh[256];
    sh[threadIdx.x] = sane;
    __syncthreads();
    for (int off = 128; off > 0; off >>= 1) {
        if (threadIdx.x < off) sh[threadIdx.x] += sh[threadIdx.x + off];
        __syncthreads();
    }
    if (threadIdx.x == 0) *flag = (sh[0] < 2048) ? 1 : 0;   // 1 = bf16, 0 = f32
}

// ---- convert core: input x (B,C,N) -> X0 k-packed bf16 ----------------------
__device__ __forceinline__ void convert_core(int bid, int tid, const void* __restrict__ x,
                                             bf16* __restrict__ X0, int isb) {
    int item = bid * 256 + tid;   // cg*2048 + bn  (cg = c/8)
    int cg = item >> 11, bn = item & 2047;
    int b = bn >> 7, n = bn & 127;
    short8 pk;
#pragma unroll
    for (int j = 0; j < 8; ++j)
        pk[j] = f2bs(ldin(x, ((size_t)(b * 512 + cg * 8 + j)) * 128 + n, isb));
    *(short8*)((short*)X0 + ((size_t)cg * BN_ALL + bn) * 8) = pk;
}

__global__ __launch_bounds__(256) void convert_kp(const void* __restrict__ x, bf16* __restrict__ X0,
                                                  const int* __restrict__ dflag) {
    convert_core(blockIdx.x, threadIdx.x, x, X0, *dflag);
}

// ---- pack core: f32/bf16 weights -> bf16 in LDS-tile image ------------------
__device__ __forceinline__ void pack_core(int item, int isb, const void* __restrict__ w, int ldw,
                                          const void* __restrict__ res, int Cin, int O,
                                          int Mtot, int K, short* __restrict__ out) {
    if (item >= Mtot * (K >> 3)) return;
    int m_local = item & 127;
    int rest = item >> 7;            // (tm*KC + kc)*4 + q
    int q = rest & 3; rest >>= 2;
    int KC = K >> 5;
    int kc = rest % KC, tm = rest / KC;
    int grow = tm * 128 + m_local;
    int k = kc * 32 + q * 8;
    const void* src; size_t base; int dif = 0;
    if (grow < O)          { src = w;   base = (size_t)grow * ldw + k; }
    else if (grow < 2 * O) { src = w;   base = (size_t)(grow - O) * ldw + k; dif = 1; }
    else                   { src = res; base = (size_t)(grow - 2 * O) * Cin + k; }
    short8 pk;
#pragma unroll
    for (int j = 0; j < 8; ++j) {
        float v = ldin(src, base + j, isb);
        if (dif) v = ldin(src, base + Cin + j, isb) - v;
        pk[j] = f2bs(v);
    }
    *(short8*)&out[(size_t)item * 8] = pk;
}

__global__ __launch_bounds__(256) void pack_w(const void* __restrict__ w, int ldw,
                                              const void* __restrict__ res, int Cin, int O,
                                              int Mtot, int K, short* __restrict__ out,
                                              const int* __restrict__ dflag) {
    pack_core(blockIdx.x * 256 + threadIdx.x, *dflag, w, ldw, res, Cin, O, Mtot, K, out);
}

// ---- fused convert + ALL weight packs (tier P2) -----------------------------
// blocks [0,512): convert; [512,768): p1; [768,1152): p2; [1152,1920): p3;
// [1920,3456): p4; [3456,6528): p5.
__global__ __launch_bounds__(256) void convert_pack_all(
        const void* __restrict__ x, bf16* __restrict__ X0,
        const void* __restrict__ w1c, const void* __restrict__ w2c, const void* __restrict__ w3c,
        const void* __restrict__ w4c, const void* __restrict__ w5c,
        const void* __restrict__ r1, const void* __restrict__ r2, const void* __restrict__ r3,
        short* __restrict__ p1, short* __restrict__ p2, short* __restrict__ p3,
        short* __restrict__ p4, short* __restrict__ p5,
        const int* __restrict__ dflag) {
    int isb = *dflag;
    int bid = blockIdx.x, tid = threadIdx.x;
    if (bid < 512) { convert_core(bid, tid, x, X0, isb); return; }
    int pb = bid - 512;
    if (pb < 256)       pack_core(pb * 256 + tid,          isb, w1c, 1024, nullptr, 512, 512, 1024, 512, p1);
    else if (pb < 640)  pack_core((pb - 256) * 256 + tid,  isb, w2c, 1024, r1,      512, 512, 1536, 512, p2);
    else if (pb < 1408) pack_core((pb - 640) * 256 + tid,  isb, w3c, 1024, r2,      512, 1024, 3072, 512, p3);
    else if (pb < 2944) pack_core((pb - 1408) * 256 + tid, isb, w4c, 2048, r3,      1024, 1024, 3072, 1024, p4);
    else                pack_core((pb - 2944) * 256 + tid, isb, w5c, 3072, nullptr, 3072, 2048, 2048, 3072, p5);
}

// ---- Gram via MFMA from k-packed X; one block per batch ---------------------
__global__ __launch_bounds__(256) void gram_k(const bf16* __restrict__ X, int C,
                                              float* __restrict__ G) {
    __shared__ __align__(16) short Bsm[2][8192];   // 128 points x 64 k
    int tid = threadIdx.x;
    int b = blockIdx.x;
    int lane = tid & 63, wv = tid >> 6, wm = wv & 1, wn = wv >> 1;
    int lq = lane >> 4, lr = lane & 15;
    int KC = C >> 6;
    const short* Xs = (const short*)X;

    float4v acc[4][4];
#pragma unroll
    for (int i = 0; i < 4; i++)
#pragma unroll
        for (int j = 0; j < 4; j++) acc[i][j] = (float4v){0.f, 0.f, 0.f, 0.f};

#pragma unroll
    for (int it = 0; it < 4; ++it) {
        int i = tid + it * 256;
        int q = i >> 7, c = i & 127;
        gll16(Xs + ((size_t)q * BN_ALL + b * 128 + c) * 8, &Bsm[0][(size_t)i * 8]);
    }
    __syncthreads();

    int p = 0;
    for (int kc = 0; kc < KC; ++kc) {
        if (kc + 1 < KC) {
#pragma unroll
            for (int it = 0; it < 4; ++it) {
                int i = tid + it * 256;
                int q = i >> 7, c = i & 127;
                gll16(Xs + ((size_t)((kc + 1) * 8 + q) * BN_ALL + b * 128 + c) * 8,
                      &Bsm[p ^ 1][(size_t)i * 8]);
            }
        }
#pragma unroll
        for (int h = 0; h < 2; ++h) {
            short8 av[4], bv[4];
#pragma unroll
            for (int mt = 0; mt < 4; ++mt)
                av[mt] = *(const short8*)&Bsm[p][(size_t)(h * 512 + (lq << 7) + wm * 64 + mt * 16 + lr) * 8];
#pragma unroll
            for (int nt = 0; nt < 4; ++nt)
                bv[nt] = *(const short8*)&Bsm[p][(size_t)(h * 512 + (lq << 7) + wn * 64 + nt * 16 + lr) * 8];
#pragma unroll
            for (int mt = 0; mt < 4; ++mt)
#pragma unroll
                for (int nt = 0; nt < 4; ++nt)
                    acc[mt][nt] = __builtin_amdgcn_mfma_f32_16x16x32_bf16(av[mt], bv[nt], acc[mt][nt], 0, 0, 0);
        }
        __syncthreads();
        p ^= 1;
    }

    float* Gb = G + (size_t)b * 16384;
#pragma unroll
    for (int mt = 0; mt < 4; ++mt)
#pragma unroll
        for (int r = 0; r < 4; ++r) {
            int row = wm * 64 + mt * 16 + lq * 4 + r;
#pragma unroll
            for (int nt = 0; nt < 4; ++nt) {
                int col = wn * 64 + nt * 16 + lr;
                Gb[row * 128 + col] = acc[mt][nt][r];
            }
        }
}

// ---- top-20 core: one wave per (b,n) row; ties -> lower index ---------------
__device__ __forceinline__ void topk_core(int bid, int tid, const float* __restrict__ G,
                                          int* __restrict__ idx) {
    int gw = (bid * 256 + tid) >> 6;   // 0..2047 = b*128+n
    int lane = tid & 63;
    int b = gw >> 7, n = gw & 127;
    const float* Gb = G + (size_t)b * 16384;
    float g0 = Gb[n * 128 + lane];
    float g1 = Gb[n * 128 + 64 + lane];
    float dnn = Gb[n * 129];
    float dm0 = Gb[lane * 129];
    float dm1 = Gb[(64 + lane) * 129];
    float d0 = 2.f * g0 - dnn - dm0;
    float d1 = 2.f * g1 - dnn - dm1;
#pragma unroll
    for (int k = 0; k < 20; ++k) {
        float v; int i;
        if (d1 > d0) { v = d1; i = 64 + lane; } else { v = d0; i = lane; }
#pragma unroll
        for (int off = 1; off < 64; off <<= 1) {
            float ov = __shfl_xor(v, off, 64);
            int   oi = __shfl_xor(i, off, 64);
            if (ov > v || (ov == v && oi < i)) { v = ov; i = oi; }
        }
        if (lane == 0) idx[gw * 20 + k] = i;
        if (i < 64) { if (lane == i) d0 = -3.0e38f; }
        else        { if (lane == i - 64) d1 = -3.0e38f; }
    }
}

__global__ __launch_bounds__(256) void topk_k(const float* __restrict__ G, int* __restrict__ idx) {
    topk_core(blockIdx.x, threadIdx.x, G, idx);
}

// ---- gemm core: packed-A / k-packed-B bf16 MFMA, 128x64 tile, BK=64 ---------
// R12 form: staging via global_load_lds double-buffer; 16 MFMA/wave/barrier.
__device__ __forceinline__ void gemm_core(int bx, int by, int tid,
        const short* __restrict__ packA, const bf16* __restrict__ X,
        float* __restrict__ Cm, int K,
        const void* __restrict__ bnS, const void* __restrict__ bnB,
        int act, const int* __restrict__ dflag) {
    __shared__ __align__(16) short Asm[2][8192];   // 128 rows x 64 k (bf16)
    __shared__ __align__(16) short Bsm[2][4096];   // [(q*64 + c)*8 + j], q=0..7
    int bm  = bx << 7;
    int bn0 = by << 6;
    int lane = tid & 63, wv = tid >> 6, wm = wv & 1, wn = wv >> 1;
    int lq = lane >> 4, lr = lane & 15;
    int KC = K >> 6;
    const short* abase = packA + (size_t)bx * (K >> 5) * 4096;
    const short* Xs = (const short*)X;
    int bq = tid >> 6, bc = tid & 63;

    float4v acc[4][2];
#pragma unroll
    for (int i = 0; i < 4; i++)
#pragma unroll
        for (int j = 0; j < 2; j++) acc[i][j] = (float4v){0.f, 0.f, 0.f, 0.f};

#pragma unroll
    for (int it = 0; it < 4; ++it)
        gll16(abase + (size_t)(tid + it * 256) * 8, &Asm[0][(size_t)(tid + it * 256) * 8]);
    gll16(Xs + ((size_t)bq * BN_ALL + bn0 + bc) * 8,       &Bsm[0][(size_t)tid * 8]);
    gll16(Xs + ((size_t)(bq + 4) * BN_ALL + bn0 + bc) * 8, &Bsm[0][(size_t)(tid + 256) * 8]);
    __syncthreads();

    int p = 0;
    for (int kc = 0; kc < KC; ++kc) {
        if (kc + 1 < KC) {
            const short* ab = abase + (size_t)(kc + 1) * 8192;
#pragma unroll
            for (int it = 0; it < 4; ++it)
                gll16(ab + (size_t)(tid + it * 256) * 8, &Asm[p ^ 1][(size_t)(tid + it * 256) * 8]);
            gll16(Xs + ((size_t)((kc + 1) * 8 + bq) * BN_ALL + bn0 + bc) * 8,
                  &Bsm[p ^ 1][(size_t)tid * 8]);
            gll16(Xs + ((size_t)((kc + 1) * 8 + bq + 4) * BN_ALL + bn0 + bc) * 8,
                  &Bsm[p ^ 1][(size_t)(tid + 256) * 8]);
        }
#pragma unroll
        for (int h = 0; h < 2; ++h) {
            short8 av[4], bv[2];
#pragma unroll
            for (int mt = 0; mt < 4; ++mt)
                av[mt] = *(const short8*)&Asm[p][(size_t)(h * 512 + (lq << 7) + wm * 64 + mt * 16 + lr) * 8];
#pragma unroll
            for (int nt = 0; nt < 2; ++nt)
                bv[nt] = *(const short8*)&Bsm[p][(size_t)(h * 256 + (lq << 6) + wn * 32 + nt * 16 + lr) * 8];
#pragma unroll
            for (int mt = 0; mt < 4; ++mt)
#pragma unroll
                for (int nt = 0; nt < 2; ++nt)
                    acc[mt][nt] = __builtin_amdgcn_mfma_f32_16x16x32_bf16(av[mt], bv[nt], acc[mt][nt], 0, 0, 0);
        }
        __syncthreads();
        p ^= 1;
    }

    int isb = *dflag;
#pragma unroll
    for (int mt = 0; mt < 4; ++mt) {
#pragma unroll
        for (int r = 0; r < 4; ++r) {
            int row = bm + wm * 64 + mt * 16 + lq * 4 + r;
            float s = 1.f, bb = 0.f;
            if (bnS) { s = ldin(bnS, row, isb); bb = ldin(bnB, row, isb); }
#pragma unroll
            for (int nt = 0; nt < 2; ++nt) {
                int col = bn0 + wn * 32 + nt * 16 + lr;
                float v = acc[mt][nt][r];
                if (bnS) v = v * s + bb;
                if (act) v = lrelu(v);
                Cm[(size_t)row * BN_ALL + col] = v;
            }
        }
    }
}

__global__ __launch_bounds__(256) void gemm_pk(const short* __restrict__ packA,
                                               const bf16* __restrict__ X, float* __restrict__ Cm, int K,
                                               const void* __restrict__ bnS, const void* __restrict__ bnB,
                                               int act, const int* __restrict__ dflag) {
    gemm_core(blockIdx.x, blockIdx.y, threadIdx.x, packA, X, Cm, K, bnS, bnB, act, dflag);
}

// ---- fused topk || gemm (tier P2): blocks [0,512)=topk, rest=gemm -----------
// topk reads GRAM (dedicated buffer), gemm writes PS -> no overlap.
__global__ __launch_bounds__(256) void topk_gemm_k(const float* __restrict__ G, int* __restrict__ idx,
                                                   const short* __restrict__ packA,
                                                   const bf16* __restrict__ X, float* __restrict__ Cm,
                                                   int K, const int* __restrict__ dflag) {
    if (blockIdx.x < 512) {
        topk_core(blockIdx.x, threadIdx.x, G, idx);
    } else {
        int g = blockIdx.x - 512;
        gemm_core(g >> 5, g & 31, threadIdx.x, packA, X, Cm, K, nullptr, nullptr, 0, dflag);
    }
}

// ---- legacy kNN (fallback tiers) --------------------------------------------
template <typename S>
__global__ __launch_bounds__(128) void knn_topk(const S* __restrict__ X, int C, int* __restrict__ idx) {
    int b = blockIdx.x >> 7;
    int n = blockIdx.x & 127;
    int m = threadIdx.x;
    const S* base = X + b * 128;
    float s0 = 0, s1 = 0, q0 = 0, q1 = 0;
    for (int c = 0; c < C; c += 2) {
        const S* p = base + (size_t)c * BN_ALL;
        float xm0 = ld1(p + m),          xn0 = ld1(p + n);
        float xm1 = ld1(p + BN_ALL + m), xn1 = ld1(p + BN_ALL + n);
        s0 += xm0 * xn0; q0 += xm0 * xm0;
        s1 += xm1 * xn1; q1 += xm1 * xm1;
    }
    float inner = s0 + s1;
    float xxm   = q0 + q1;
    __shared__ float xx[128];
    __shared__ float dist[128];
    __shared__ float rv[128];
    __shared__ int   ri[128];
    xx[m] = xxm;
    __syncthreads();
    dist[m] = 2.0f * inner - xx[n] - xxm;
    for (int k = 0; k < 20; k++) {
        __syncthreads();
        rv[m] = dist[m]; ri[m] = m;
        __syncthreads();
        for (int off = 64; off > 0; off >>= 1) {
            if (m < off) {
                float a = rv[m], bv = rv[m + off];
                int ia = ri[m], ib = ri[m + off];
                if (bv > a || (bv == a && ib < ia)) { rv[m] = bv; ri[m] = ib; }
            }
            __syncthreads();
        }
        if (m == 0) { idx[blockIdx.x * 20 + k] = ri[0]; dist[ri[0]] = -3.0e38f; }
    }
}

// ---- R5 fallback GEMM (on-the-fly staging, 128x128, linear layouts) ---------
template <typename S>
__global__ __launch_bounds__(256) void gemm_mfma(const void* __restrict__ w, int ldw,
                                                 const void* __restrict__ res, int Cin, int O,
                                                 const S* __restrict__ X, S* __restrict__ Cm, int K,
                                                 const void* __restrict__ bnS, const void* __restrict__ bnB,
                                                 int act, const int* __restrict__ dflag) {
    int isb = *dflag;
    __shared__ short Asm[4096];
    __shared__ short Bsm[4096];
    int tid = threadIdx.x;
    int bm  = blockIdx.x << 7;
    int bn0 = blockIdx.y << 7;
    int lane = tid & 63, wv = tid >> 6;
    int wm = wv & 1, wn = wv >> 1;
    int lq = lane >> 4, lr = lane & 15;

    float4v acc[4][4];
#pragma unroll
    for (int i = 0; i < 4; i++)
#pragma unroll
        for (int j = 0; j < 4; j++) acc[i][j] = (float4v){0.f, 0.f, 0.f, 0.f};

    for (int k0 = 0; k0 < K; k0 += 32) {
#pragma unroll
        for (int it = 0; it < 2; ++it) {
            int i = tid + it * 256;
            int m = i >> 2, q = i & 3;
            int grow = bm + m;
            const void* asrc; size_t abase; int dif = 0;
            if (grow < O)          { asrc = w;   abase = (size_t)grow * ldw; }
            else if (grow < 2 * O) { asrc = w;   abase = (size_t)(grow - O) * ldw; dif = 1; }
            else                   { asrc = res; abase = (size_t)(grow - 2 * O) * Cin; }
            size_t kk = (size_t)k0 + q * 8;
            short8 pk;
#pragma unroll
            for (int j = 0; j < 8; ++j) {
                float v = ldin(asrc, abase + kk + j, isb);
                if (dif) v = ldin(asrc, abase + Cin + kk + j, isb) - v;
                pk[j] = f2bs(v);
            }
            *(short8*)&Asm[(size_t)(q * 128 + m) * 8] = pk;
        }
#pragma unroll
        for (int it = 0; it < 2; ++it) {
            int i = tid + it * 256;
            int q = i >> 7, c = i & 127;
            const S* xp = X + (size_t)(k0 + q * 8) * BN_ALL + bn0 + c;
            short8 pk;
#pragma unroll
            for (int j = 0; j < 8; ++j) pk[j] = f2bs(ld1(xp + (size_t)j * BN_ALL));
            *(short8*)&Bsm[(size_t)i * 8] = pk;
        }
        __syncthreads();
        short8 av[4], bv[4];
#pragma unroll
        for (int mt = 0; mt < 4; ++mt)
            av[mt] = *(const short8*)&Asm[(size_t)((lq << 7) + wm * 64 + mt * 16 + lr) * 8];
#pragma unroll
        for (int nt = 0; nt < 4; ++nt)
            bv[nt] = *(const short8*)&Bsm[(size_t)((lq << 7) + wn * 64 + nt * 16 + lr) * 8];
#pragma unroll
        for (int mt = 0; mt < 4; ++mt)
#pragma unroll
            for (int nt = 0; nt < 4; ++nt)
                acc[mt][nt] = __builtin_amdgcn_mfma_f32_16x16x32_bf16(av[mt], bv[nt], acc[mt][nt], 0, 0, 0);
        __syncthreads();
    }
#pragma unroll
    for (int mt = 0; mt < 4; ++mt) {
#pragma unroll
        for (int r = 0; r < 4; ++r) {
            int row = bm + wm * 64 + mt * 16 + lq * 4 + r;
            float s = 1.f, bb = 0.f;
            if (bnS) { s = ldin(bnS, row, isb); bb = ldin(bnB, row, isb); }
#pragma unroll
            for (int nt = 0; nt < 4; ++nt) {
                int col = bn0 + wn * 64 + nt * 16 + lr;
                float v = acc[mt][nt][r];
                if (bnS) v = v * s + bb;
                if (act) v = lrelu(v);
                st1(Cm + (size_t)row * BN_ALL + col, v);
            }
        }
    }
}

// ---- gather + k-pool + bn + lrelu; T written IN-PLACE over P row o ----------
// one WAVE per (o,b) row; 2 n's per lane; barrier-free shfl_xor butterfly.
template <typename S>
__global__ __launch_bounds__(256) void gather_pool(S* __restrict__ PS, const int* __restrict__ idx,
                                                   const void* __restrict__ bns, const void* __restrict__ bnb,
                                                   float* __restrict__ Mb, int O,
                                                   const int* __restrict__ dflag) {
    int isb = *dflag;
    int wv = threadIdx.x >> 6, lane = threadIdx.x & 63;
    int gw = blockIdx.x * 4 + wv;          // gw = o*16 + b
    int o = gw >> 4, b = gw & 15;
    S* Prow = PS + (size_t)o * BN_ALL + b * 128;
    const S* Srow = PS + (size_t)(O + o) * BN_ALL + b * 128;
    int n0 = lane, n1 = lane + 64;
    const int* id0 = idx + (b * 128 + n0) * 20;
    const int* id1 = idx + (b * 128 + n1) * 20;
    float mx0 = -3.0e38f, mn0 = 3.0e38f, sm0 = 0.f;
    float mx1 = -3.0e38f, mn1 = 3.0e38f, sm1 = 0.f;
#pragma unroll
    for (int k = 0; k < 20; k++) {
        float p = ld1(Prow + id0[k]);
        mx0 = fmaxf(mx0, p); mn0 = fminf(mn0, p); sm0 += p;
    }
#pragma unroll
    for (int k = 0; k < 20; k++) {
        float p = ld1(Prow + id1[k]);
        mx1 = fmaxf(mx1, p); mn1 = fminf(mn1, p); sm1 += p;
    }
    float Sv0 = ld1(Srow + n0), Sv1 = ld1(Srow + n1);
    float s = ldin(bns, o, isb), bb = ldin(bnb, o, isb);
    float ext0 = (s >= 0.f) ? mx0 : mn0;
    float ext1 = (s >= 0.f) ? mx1 : mn1;
    float t0 = lrelu(s * (ext0 + Sv0) + bb);
    float t1 = lrelu(s * (ext1 + Sv1) + bb);
    st1(Prow + n0, t0);
    st1(Prow + n1, t1);
    float r1 = sm0 + sm1;    // == halving-tree step off=64
    float r2 = Sv0 + Sv1;
#pragma unroll
    for (int off = 32; off > 0; off >>= 1) {
        r1 += __shfl_xor(r1, off, 64);
        r2 += __shfl_xor(r2, off, 64);
    }
    if (lane == 0) Mb[b * O + o] = s * (r1 * (1.f / 2560.f) + r2 * (1.f / 128.f)) + bb;
}

// ---- SE stage 1: z[b,t] = relu(w1[t,:] . M[b,:]) — one wave per (b,t) -------
__global__ __launch_bounds__(256) void se1_k(const float* __restrict__ Mb, const void* __restrict__ w1,
                                             float* __restrict__ Z, int O, int r,
                                             const int* __restrict__ dflag) {
    int isb = *dflag;
    int gw = (blockIdx.x * 256 + threadIdx.x) >> 6;   // b*r + t
    int lane = threadIdx.x & 63;
    int b = gw / r, t = gw - b * r;
    const float* mv = Mb + (size_t)b * O;
    float acc = 0.f;
    for (int c = lane; c < O; c += 64) acc += ldin(w1, (size_t)t * O + c, isb) * mv[c];
#pragma unroll
    for (int off = 32; off > 0; off >>= 1) acc += __shfl_xor(acc, off, 64);
    if (lane == 0) Z[b * r + t] = fmaxf(acc, 0.f);
}

// ---- SE stage 2: Y[b,o] = sigmoid(w2[o,:] . z[b,:]) — one wave per (b,o) ----
__global__ __launch_bounds__(256) void se2_k(const float* __restrict__ Z, const void* __restrict__ w2,
                                             float* __restrict__ Y, int O, int r,
                                             const int* __restrict__ dflag) {
    int isb = *dflag;
    int gw = (blockIdx.x * 256 + threadIdx.x) >> 6;   // b*O + o
    int lane = threadIdx.x & 63;
    int b = gw / O, o = gw - b * O;
    float acc = 0.f;
    if (lane < r) acc = ldin(w2, (size_t)o * r + lane, isb) * Z[b * r + lane];
#pragma unroll
    for (int off = 32; off > 0; off >>= 1) acc += __shfl_xor(acc, off, 64);
    if (lane == 0) Y[b * O + o] = 1.f / (1.f + expf(-acc));
}

// ---- legacy SE (fallback tiers) ---------------------------------------------
__global__ __launch_bounds__(256) void se_k(const float* __restrict__ Mb, const void* __restrict__ w1,
                                            const void* __restrict__ w2, float* __restrict__ Y, int O, int r,
                                            const int* __restrict__ dflag) {
    int isb = *dflag;
    int b = blockIdx.x, t = threadIdx.x;
    __shared__ float mloc[1024];
    __shared__ float z[64];
    for (int i = t; i < O; i += 256) mloc[i] = Mb[b * O + i];
    __syncthreads();
    if (t < r) {
        float acc = 0.f;
        for (int c = 0; c < O; c++) acc += ldin(w1, (size_t)t * O + c, isb) * mloc[c];
        z[t] = fmaxf(acc, 0.f);
    }
    __syncthreads();
    for (int o = t; o < O; o += 256) {
        float acc = 0.f;
        for (int j = 0; j < r; j++) acc += ldin(w2, (size_t)o * r + j, isb) * z[j];
        Y[b * O + o] = 1.f / (1.f + expf(-acc));
    }
}

// ---- finalize (tier P): x_next = y*T (+res) -> k-packed bf16 slice ----------
__global__ __launch_bounds__(256) void finalize_kp(const float* __restrict__ PS, const float* __restrict__ Y,
                                                   int useR, bf16* __restrict__ Xdst, int O) {
    int item = blockIdx.x * 256 + threadIdx.x;   // og*2048 + bn  (og = o/8)
    int og = item >> 11, bn = item & 2047;
    int b = bn >> 7;
    short8 pk;
#pragma unroll
    for (int j = 0; j < 8; ++j) {
        int r = og * 8 + j;
        float v = Y[b * O + r] * PS[(size_t)r * BN_ALL + bn];
        if (useR) v += PS[(size_t)(2 * O + r) * BN_ALL + bn];
        pk[j] = f2bs(v);
    }
    *(short8*)((short*)Xdst + ((size_t)og * BN_ALL + bn) * 8) = pk;
}

// ---- legacy finalize (fallback tiers, linear layout) ------------------------
template <typename SP, typename SD>
__global__ __launch_bounds__(256) void finalize(const SP* __restrict__ PS, const float* __restrict__ Y,
                                                int useR, SD* __restrict__ Xdst, int O) {
    int tid = blockIdx.x * 256 + threadIdx.x;   // tid = o*2048 + bn
    int o = tid >> 11, bn = tid & 2047;
    int b = bn >> 7;
    float v = Y[b * O + o] * ld1(PS + tid);
    if (useR) v += ld1(PS + (size_t)(2 * O + o) * BN_ALL + bn);
    st1(Xdst + tid, v);
}

// ---- legacy convert (fallback tiers) ----------------------------------------
template <typename S>
__global__ __launch_bounds__(256) void convert_x(const void* __restrict__ x, S* __restrict__ X0,
                                                 const int* __restrict__ dflag) {
    int isb = *dflag;
    int tid = blockIdx.x * 256 + threadIdx.x;
    int c = tid >> 11, bn = tid & 2047;
    int b = bn >> 7, n = bn & 127;
    st1(X0 + tid, ldin(x, (size_t)(b * 512 + c) * 128 + n, isb));
}

// ---- conv5 pool: one WAVE per (m,b); barrier-free butterfly -----------------
template <typename S>
__global__ __launch_bounds__(256) void pool5(const S* __restrict__ H, float* __restrict__ f) {
    int wv = threadIdx.x >> 6, lane = threadIdx.x & 63;
    int gw = blockIdx.x * 4 + wv;          // gw = m*16 + b
    int m = gw >> 4, b = gw & 15;
    const S* Hp = H + (size_t)m * BN_ALL + b * 128;
    float v0 = ld1(Hp + lane), v1 = ld1(Hp + 64 + lane);
    float mx = fmaxf(v0, v1);
    float sm = v0 + v1;
#pragma unroll
    for (int off = 32; off > 0; off >>= 1) {
        mx = fmaxf(mx, __shfl_xor(mx, off, 64));
        sm += __shfl_xor(sm, off, 64);
    }
    if (lane == 0) {
        f[b * 4096 + m] = mx;
        f[b * 4096 + 2048 + m] = sm * (1.f / 128.f);
    }
}

// ---- head: one wave per (b,o) dot product + optional bias/bn/lrelu ----------
__global__ __launch_bounds__(256) void head_k(const float* __restrict__ in, const void* __restrict__ W,
                                              const void* __restrict__ bias, const void* __restrict__ bns,
                                              const void* __restrict__ bnb, float* __restrict__ outf,
                                              void* __restrict__ outb, int Kd, int Od, int act,
                                              const int* __restrict__ dflag) {
    int isb = *dflag;
    int gw = (blockIdx.x * 256 + threadIdx.x) >> 6;
    int lane = threadIdx.x & 63;
    if (gw >= 16 * Od) return;
    int b = gw / Od, o = gw - b * Od;
    const float* iv = in + b * Kd;
    float acc = 0.f;
    for (int k = lane; k < Kd; k += 64) acc += iv[k] * ldin(W, (size_t)o * Kd + k, isb);
    for (int off = 32; off > 0; off >>= 1) acc += __shfl_xor(acc, off, 64);
    if (lane == 0) {
        float v = acc;
        if (bias) v += ldin(bias, o, isb);
        if (bns) v = v * ldin(bns, o, isb) + ldin(bnb, o, isb);
        if (act) v = lrelu(v);
        if (outb) {
            if (isb) ((bf16*)outb)[gw] = __float2bfloat16(v);
            else     ((float*)outb)[gw] = v;
        } else outf[gw] = v;
    }
}

// ---- ws-too-small signal ----------------------------------------------------
__global__ __launch_bounds__(256) void zero_out(bf16* o, int n) {
    int i = blockIdx.x * 256 + threadIdx.x;
    if (i < n) o[i] = __float2bfloat16(0.f);
}

// ---------------------------------------------------------------------------
#define UNPACK_INPUTS()                                                     \
    const void* x_in   = d_in[0];                                           \
    const void* conv1w = d_in[1];  const void* conv2w = d_in[2];            \
    const void* conv3w = d_in[3];  const void* conv4w = d_in[4];            \
    const void* conv5w = d_in[5];                                           \
    const void* bn1s = d_in[6],  * bn1b = d_in[7];                          \
    const void* bn2s = d_in[8],  * bn2b = d_in[9];                          \
    const void* bn3s = d_in[10], * bn3b = d_in[11];                         \
    const void* bn4s = d_in[12], * bn4b = d_in[13];                         \
    const void* bn5s = d_in[14], * bn5b = d_in[15];                         \
    const void* se1w1 = d_in[16], * se1w2 = d_in[17];                       \
    const void* se2w1 = d_in[18], * se2w2 = d_in[19];                       \
    const void* se3w1 = d_in[20], * se3w2 = d_in[21];                       \
    const void* se4w1 = d_in[22], * se4w2 = d_in[23];                       \
    const void* res1w = d_in[24]; const void* res2w = d_in[25];             \
    const void* res3w = d_in[26]; const void* lin1w = d_in[27];             \
    const void* bn6s = d_in[28], * bn6b = d_in[29];                         \
    const void* lin2w = d_in[30], * lin2b = d_in[31];                       \
    const void* bn7s = d_in[32], * bn7b = d_in[33];                         \
    const void* lin3w = d_in[34], * lin3b = d_in[35];

// ---- Tier P2: all packs upfront, fused topk||gemm, parallel 2-stage SE ------
static void run_net_packed2(void* const* d_in, void* d_out, void* d_ws, hipStream_t stream) {
    UNPACK_INPUTS();
    float* WS = (float*)d_ws;
    float* PS = WS;                                   // 3072 x 2048 f32
    bf16*  XC = (bf16*)(WS + 6291456);                // 3072 x 2048 bf16 k-packed
    // private PACK regions (shorts)
    short* P1 = (short*)(WS + 12582912);              // 524288 shorts
    short* P2 = P1 + 524288;                          // 786432
    short* P3 = P2 + 786432;                          // 1572864
    short* P4 = P3 + 1572864;                         // 3145728
    short* P5 = P4 + 3145728;                         // 6291456  (ends @ float 18743296)
    float* MB = WS + 18743296;
    float* YB = MB + 16384;
    float* FB = YB + 16384;
    float* F1 = FB + 65536;
    float* F2 = F1 + 8192;
    int* IDX  = (int*)(F2 + 4096);
    int* DFLAG = IDX + 40960;
    float* ZB = (float*)(DFLAG + 16);                 // 1024 floats (< GRAM start)
    float* GRAM = WS + 18900000;                      // 262144 floats, dedicated
    bf16*  X0 = (bf16*)(PS + (size_t)2048 * BN_ALL);  // PS rows 2048.. (block 1 only)
    bf16* X1 = XC;
    bf16* X2 = XC + (size_t)512 * BN_ALL;
    bf16* X3 = XC + (size_t)1024 * BN_ALL;
    bf16* X4 = XC + (size_t)2048 * BN_ALL;

    detect_dtype<<<1, 256, 0, stream>>>(x_in, DFLAG);
    convert_pack_all<<<6528, 256, 0, stream>>>(x_in, X0,
        conv1w, conv2w, conv3w, conv4w, conv5w, res1w, res2w, res3w,
        P1, P2, P3, P4, P5, DFLAG);

    // block 1: O=512, Mtot=1024, K=512, r=32
    gram_k<<<16, 256, 0, stream>>>(X0, 512, GRAM);
    topk_gemm_k<<<512 + 8 * 32, 256, 0, stream>>>(GRAM, IDX, P1, X0, PS, 512, DFLAG);
    gather_pool<float><<<2048, 256, 0, stream>>>(PS, IDX, bn1s, bn1b, MB, 512, DFLAG);
    se1_k<<<128, 256, 0, stream>>>(MB, se1w1, ZB, 512, 32, DFLAG);
    se2_k<<<2048, 256, 0, stream>>>(ZB, se1w2, YB, 512, 32, DFLAG);
    finalize_kp<<<512, 256, 0, stream>>>(PS, YB, 0, X1, 512);

    // block 2: Mtot=1536, K=512, res1, r=32
    gram_k<<<16, 256, 0, stream>>>(X1, 512, GRAM);
    topk_gemm_k<<<512 + 12 * 32, 256, 0, stream>>>(GRAM, IDX, P2, X1, PS, 512, DFLAG);
    gather_pool<float><<<2048, 256, 0, stream>>>(PS, IDX, bn2s, bn2b, MB, 512, DFLAG);
    se1_k<<<128, 256, 0, stream>>>(MB, se2w1, ZB, 512, 32, DFLAG);
    se2_k<<<2048, 256, 0, stream>>>(ZB, se2w2, YB, 512, 32, DFLAG);
    finalize_kp<<<512, 256, 0, stream>>>(PS, YB, 1, X2, 512);

    // block 3: O=1024, Mtot=3072, K=512, res2, r=64
    gram_k<<<16, 256, 0, stream>>>(X2, 512, GRAM);
    topk_gemm_k<<<512 + 24 * 32, 256, 0, stream>>>(GRAM, IDX, P3, X2, PS, 512, DFLAG);
    gather_pool<float><<<4096, 256, 0, stream>>>(PS, IDX, bn3s, bn3b, MB, 1024, DFLAG);
    se1_k<<<256, 256, 0, stream>>>(MB, se3w1, ZB, 1024, 64, DFLAG);
    se2_k<<<4096, 256, 0, stream>>>(ZB, se3w2, YB, 1024, 64, DFLAG);
    finalize_kp<<<1024, 256, 0, stream>>>(PS, YB, 1, X3, 1024);

    // block 4: O=1024, Mtot=3072, K=1024, res3, r=64
    gram_k<<<16, 256, 0, stream>>>(X3, 1024, GRAM);
    topk_gemm_k<<<512 + 24 * 32, 256, 0, stream>>>(GRAM, IDX, P4, X3, PS, 1024, DFLAG);
    gather_pool<float><<<4096, 256, 0, stream>>>(PS, IDX, bn4s, bn4b, MB, 1024, DFLAG);
    se1_k<<<256, 256, 0, stream>>>(MB, se4w1, ZB, 1024, 64, DFLAG);
    se2_k<<<4096, 256, 0, stream>>>(ZB, se4w2, YB, 1024, 64, DFLAG);
    finalize_kp<<<1024, 256, 0, stream>>>(PS, YB, 1, X4, 1024);

    // conv5: Mtot=2048, K=3072, bn5+lrelu
    gemm_pk<<<dim3(16, 32), 256, 0, stream>>>(P5, XC, PS, 3072, bn5s, bn5b, 1, DFLAG);
    pool5<float><<<8192, 256, 0, stream>>>(PS, FB);

    head_k<<<2048, 256, 0, stream>>>(FB, lin1w, nullptr, bn6s, bn6b, F1, nullptr, 4096, 512, 1, DFLAG);
    head_k<<<1024, 256, 0, stream>>>(F1, lin2w, lin2b, bn7s, bn7b, F2, nullptr, 512, 256, 1, DFLAG);
    head_k<<<160, 256, 0, stream>>>(F2, lin3w, lin3b, nullptr, nullptr, nullptr, d_out, 256, 40, 0, DFLAG);
}

// ---- Tier P: R15 path (fallback when ws < P2 but >= 63MB) -------------------
static void run_net_packed(void* const* d_in, void* d_out, void* d_ws, hipStream_t stream) {
    UNPACK_INPUTS();
    float* WS = (float*)d_ws;
    float* PS   = WS;
    bf16*  XC   = (bf16*)(WS + 6291456);
    short* PACK = (short*)(WS + 12582912);
    float* MB = WS + 15728640;
    float* YB = MB + 16384;
    float* FB = YB + 16384;
    float* F1 = FB + 65536;
    float* F2 = F1 + 8192;
    int* IDX  = (int*)(F2 + 4096);
    int* DFLAG = IDX + 40960;
    float* ZB = (float*)(DFLAG + 16);
    bf16*  X0 = (bf16*)(PS + (size_t)2048 * BN_ALL);
    float* GRAM = PS;
    bf16* X1 = XC;
    bf16* X2 = XC + (size_t)512 * BN_ALL;
    bf16* X3 = XC + (size_t)1024 * BN_ALL;
    bf16* X4 = XC + (size_t)2048 * BN_ALL;

    detect_dtype<<<1, 256, 0, stream>>>(x_in, DFLAG);
    convert_kp<<<512, 256, 0, stream>>>(x_in, X0, DFLAG);

    gram_k<<<16, 256, 0, stream>>>(X0, 512, GRAM);
    topk_k<<<512, 256, 0, stream>>>(GRAM, IDX);
    pack_w<<<256, 256, 0, stream>>>(conv1w, 1024, nullptr, 512, 512, 1024, 512, PACK, DFLAG);
    gemm_pk<<<dim3(8, 32), 256, 0, stream>>>(PACK, X0, PS, 512, nullptr, nullptr, 0, DFLAG);
    gather_pool<float><<<2048, 256, 0, stream>>>(PS, IDX, bn1s, bn1b, MB, 512, DFLAG);
    se1_k<<<128, 256, 0, stream>>>(MB, se1w1, ZB, 512, 32, DFLAG);
    se2_k<<<2048, 256, 0, stream>>>(ZB, se1w2, YB, 512, 32, DFLAG);
    finalize_kp<<<512, 256, 0, stream>>>(PS, YB, 0, X1, 512);

    gram_k<<<16, 256, 0, stream>>>(X1, 512, GRAM);
    topk_k<<<512, 256, 0, stream>>>(GRAM, IDX);
    pack_w<<<384, 256, 0, stream>>>(conv2w, 1024, res1w, 512, 512, 1536, 512, PACK, DFLAG);
    gemm_pk<<<dim3(12, 32), 256, 0, stream>>>(PACK, X1, PS, 512, nullptr, nullptr, 0, DFLAG);
    gather_pool<float><<<2048, 256, 0, stream>>>(PS, IDX, bn2s, bn2b, MB, 512, DFLAG);
    se1_k<<<128, 256, 0, stream>>>(MB, se2w1, ZB, 512, 32, DFLAG);
    se2_k<<<2048, 256, 0, stream>>>(ZB, se2w2, YB, 512, 32, DFLAG);
    finalize_kp<<<512, 256, 0, stream>>>(PS, YB, 1, X2, 512);

    gram_k<<<16, 256, 0, stream>>>(X2, 512, GRAM);
    topk_k<<<512, 256, 0, stream>>>(GRAM, IDX);
    pack_w<<<768, 256, 0, stream>>>(conv3w, 1024, res2w, 512, 1024, 3072, 512, PACK, DFLAG);
    gemm_pk<<<dim3(24, 32), 256, 0, stream>>>(PACK, X2, PS, 512, nullptr, nullptr, 0, DFLAG);
    gather_pool<float><<<4096, 256, 0, stream>>>(PS, IDX, bn3s, bn3b, MB, 1024, DFLAG);
    se1_k<<<256, 256, 0, stream>>>(MB, se3w1, ZB, 1024, 64, DFLAG);
    se2_k<<<4096, 256, 0, stream>>>(ZB, se3w2, YB, 1024, 64, DFLAG);
    finalize_kp<<<1024, 256, 0, stream>>>(PS, YB, 1, X3, 1024);

    gram_k<<<16, 256, 0, stream>>>(X3, 1024, GRAM);
    topk_k<<<512, 256, 0, stream>>>(GRAM, IDX);
    pack_w<<<1536, 256, 0, stream>>>(conv4w, 2048, res3w, 1024, 1024, 3072, 1024, PACK, DFLAG);
    gemm_pk<<<dim3(24, 32), 256, 0, stream>>>(PACK, X3, PS, 1024, nullptr, nullptr, 0, DFLAG);
    gather_pool<float><<<4096, 256, 0, stream>>>(PS, IDX, bn4s, bn4b, MB, 1024, DFLAG);
    se1_k<<<256, 256, 0, stream>>>(MB, se4w1, ZB, 1024, 64, DFLAG);
    se2_k<<<4096, 256, 0, stream>>>(ZB, se4w2, YB, 1024, 64, DFLAG);
    finalize_kp<<<1024, 256, 0, stream>>>(PS, YB, 1, X4, 1024);

    pack_w<<<3072, 256, 0, stream>>>(conv5w, 3072, nullptr, 3072, 2048, 2048, 3072, PACK, DFLAG);
    gemm_pk<<<dim3(16, 32), 256, 0, stream>>>(PACK, XC, PS, 3072, bn5s, bn5b, 1, DFLAG);
    pool5<float><<<8192, 256, 0, stream>>>(PS, FB);

    head_k<<<2048, 256, 0, stream>>>(FB, lin1w, nullptr, bn6s, bn6b, F1, nullptr, 4096, 512, 1, DFLAG);
    head_k<<<1024, 256, 0, stream>>>(F1, lin2w, lin2b, bn7s, bn7b, F2, nullptr, 512, 256, 1, DFLAG);
    head_k<<<160, 256, 0, stream>>>(F2, lin3w, lin3b, nullptr, nullptr, nullptr, d_out, 256, 40, 0, DFLAG);
}

// ---- Tier A/B fallback (R5 path, linear layouts) ----------------------------
template <typename S>
static void run_net(void* const* d_in, void* d_out, void* d_ws, hipStream_t stream) {
    UNPACK_INPUTS();
    const size_t RC = (size_t)3072 * BN_ALL;
    S* PS = (S*)d_ws;
    S* XC = PS + RC;
    S* X0 = PS + (size_t)2048 * BN_ALL;
    float* MB = (float*)(XC + RC);
    float* YB = MB + 16 * 1024;
    float* FB = YB + 16 * 1024;
    float* F1 = FB + 16 * 4096;
    float* F2 = F1 + 16 * 512;
    int* IDX  = (int*)(F2 + 16 * 256);
    int* DFLAG = IDX + 16 * 128 * 20;

    S* X1 = XC;
    S* X2 = XC + (size_t)512 * BN_ALL;
    S* X3 = XC + (size_t)1024 * BN_ALL;
    S* X4 = XC + (size_t)2048 * BN_ALL;

    detect_dtype<<<1, 256, 0, stream>>>(x_in, DFLAG);
    convert_x<S><<<4096, 256, 0, stream>>>(x_in, X0, DFLAG);

    knn_topk<S><<<2048, 128, 0, stream>>>(X0, 512, IDX);
    gemm_mfma<S><<<dim3(8, 16), 256, 0, stream>>>(conv1w, 1024, nullptr, 512, 512, X0, PS, 512, nullptr, nullptr, 0, DFLAG);
    gather_pool<S><<<2048, 256, 0, stream>>>(PS, IDX, bn1s, bn1b, MB, 512, DFLAG);
    se_k<<<16, 256, 0, stream>>>(MB, se1w1, se1w2, YB, 512, 32, DFLAG);
    finalize<S, S><<<4096, 256, 0, stream>>>(PS, YB, 0, X1, 512);

    knn_topk<S><<<2048, 128, 0, stream>>>(X1, 512, IDX);
    gemm_mfma<S><<<dim3(12, 16), 256, 0, stream>>>(conv2w, 1024, res1w, 512, 512, X1, PS, 512, nullptr, nullptr, 0, DFLAG);
    gather_pool<S><<<2048, 256, 0, stream>>>(PS, IDX, bn2s, bn2b, MB, 512, DFLAG);
    se_k<<<16, 256, 0, stream>>>(MB, se2w1, se2w2, YB, 512, 32, DFLAG);
    finalize<S, S><<<4096, 256, 0, stream>>>(PS, YB, 1, X2, 512);

    knn_topk<S><<<2048, 128, 0, stream>>>(X2, 512, IDX);
    gemm_mfma<S><<<dim3(24, 16), 256, 0, stream>>>(conv3w, 1024, res2w, 512, 1024, X2, PS, 512, nullptr, nullptr, 0, DFLAG);
    gather_pool<S><<<4096, 256, 0, stream>>>(PS, IDX, bn3s, bn3b, MB, 1024, DFLAG);
    se_k<<<16, 256, 0, stream>>>(MB, se3w1, se3w2, YB, 1024, 64, DFLAG);
    finalize<S, S><<<8192, 256, 0, stream>>>(PS, YB, 1, X3, 1024);

    knn_topk<S><<<2048, 128, 0, stream>>>(X3, 1024, IDX);
    gemm_mfma<S><<<dim3(24, 16), 256, 0, stream>>>(conv4w, 2048, res3w, 1024, 1024, X3, PS, 1024, nullptr, nullptr, 0, DFLAG);
    gather_pool<S><<<4096, 256, 0, stream>>>(PS, IDX, bn4s, bn4b, MB, 1024, DFLAG);
    se_k<<<16, 256, 0, stream>>>(MB, se4w1, se4w2, YB, 1024, 64, DFLAG);
    finalize<S, S><<<8192, 256, 0, stream>>>(PS, YB, 1, X4, 1024);

    gemm_mfma<S><<<dim3(16, 16), 256, 0, stream>>>(conv5w, 3072, nullptr, 3072, 2048, XC, PS, 3072, bn5s, bn5b, 1, DFLAG);
    pool5<S><<<8192, 256, 0, stream>>>(PS, FB);

    head_k<<<2048, 256, 0, stream>>>(FB, lin1w, nullptr, bn6s, bn6b, F1, nullptr, 4096, 512, 1, DFLAG);
    head_k<<<1024, 256, 0, stream>>>(F1, lin2w, lin2b, bn7s, bn7b, F2, nullptr, 512, 256, 1, DFLAG);
    head_k<<<160, 256, 0, stream>>>(F2, lin3w, lin3b, nullptr, nullptr, nullptr, d_out, 256, 40, 0, DFLAG);
}

extern "C" void kernel_launch(void* const* d_in, const int* in_sizes, int n_in,
                              void* d_out, int out_size, void* d_ws, size_t ws_size,
                              hipStream_t stream) {
    const size_t SMALL = (16 * 1024 + 16 * 1024 + 16 * 4096 + 16 * 512 + 16 * 256) * 4
                       + 16 * 128 * 20 * 4 + 8192;
    const size_t NEED_P2     = ((size_t)18900000 + 262144 + 4096) * 4;   // ~76.7MB
    const size_t NEED_PACKED = (size_t)15728640 * 4 + SMALL;
    const size_t NEED_F32    = 2 * ((size_t)3072 * BN_ALL * 4) + SMALL;
    const size_t NEED_BF16   = 2 * ((size_t)3072 * BN_ALL * 2) + SMALL;
    if (ws_size >= NEED_P2) {
        run_net_packed2(d_in, d_out, d_ws, stream);
    } else if (ws_size >= NEED_PACKED) {
        run_net_packed(d_in, d_out, d_ws, stream);
    } else if (ws_size >= NEED_F32) {
        run_net<float>(d_in, d_out, d_ws, stream);
    } else if (ws_size >= NEED_BF16) {
        run_net<bf16>(d_in, d_out, d_ws, stream);
    } else {
        zero_out<<<3, 256, 0, stream>>>((bf16*)d_out, out_size);
    }
}

// Round 9
// 552.219 us; speedup vs baseline: 2.2835x; 1.0178x over previous
//
#include <hip/hip_runtime.h>
#include <hip/hip_bf16.h>

// ---------------------------------------------------------------------------
// DGCNN-ish network, B=16, N=128, K=20.  (R19: vectorized pack loads)
// R18 counters: convert_pack_all is the largest dispatch (56us, HBM 17%,
// VALUBusy 2.5% -> issue-bound). Cause: pack_core did 8-16 SCALAR ldin
// loads per thread, each with a runtime isb branch (G13: hipcc never
// auto-vectorizes these). R19: branch once on isb, then short8 / float4
// vector loads. Same values, same f2bs rounding -> bit-identical.
// Everything else unchanged from R18 (best: 562us).
// ---------------------------------------------------------------------------

#define BN_ALL 2048   // B*N = 16*128
typedef __hip_bfloat16 bf16;
typedef __attribute__((ext_vector_type(8))) short short8;
typedef __attribute__((ext_vector_type(4))) float float4v;

__device__ __forceinline__ float b2f(bf16 v) { return __bfloat162float(v); }
__device__ __forceinline__ float bs2f(short s) { return __bfloat162float(*reinterpret_cast<bf16*>(&s)); }
__device__ __forceinline__ float lrelu(float v) { return v >= 0.f ? v : 0.2f * v; }
__device__ __forceinline__ short f2bs(float v) {
    bf16 h = __float2bfloat16(v);
    return *reinterpret_cast<short*>(&h);
}

// async 16-byte global->LDS DMA. LDS dest must be linear in lane.
__device__ __forceinline__ void gll16(const void* g, void* l) {
    __builtin_amdgcn_global_load_lds(
        (const __attribute__((address_space(1))) unsigned int*)g,
        (__attribute__((address_space(3))) unsigned int*)l,
        16, 0, 0);
}

// dual-dtype input load: isb=1 -> bf16, isb=0 -> f32
__device__ __forceinline__ float ldin(const void* p, size_t i, int isb) {
    return isb ? __bfloat162float(((const bf16*)p)[i]) : ((const float*)p)[i];
}

__device__ __forceinline__ float ld1(const float* p) { return *p; }
__device__ __forceinline__ float ld1(const bf16* p)  { return __bfloat162float(*p); }
__device__ __forceinline__ void st1(float* p, float v) { *p = v; }
__device__ __forceinline__ void st1(bf16* p, float v)  { *p = __float2bfloat16(v); }

// ---- dtype detection: sample 4096 dwords of x; f32 data -> sane exponents ---
__global__ __launch_bounds__(256) void detect_dtype(const void* __restrict__ x, int* __restrict__ flag) {
    const unsigned* u = (const unsigned*)x;
    int sane = 0;
    for (int i = threadIdx.x; i < 4096; i += 256) {
        unsigned e = (u[i] >> 23) & 0xFF;
        sane += (e >= 87 && e <= 167) ? 1 : 0;   // |v| in [2^-40, 2^40]
    }
    __shared__ int sh[256];
    sh[threadIdx.x] = sane;
    __syncthreads();
    for (int off = 128; off > 0; off >>= 1) {
        if (threadIdx.x < off) sh[threadIdx.x] += sh[threadIdx.x + off];
        __syncthreads();
    }
    if (threadIdx.x == 0) *flag = (sh[0] < 2048) ? 1 : 0;   // 1 = bf16, 0 = f32
}

// ---- convert core: input x (B,C,N) -> X0 k-packed bf16 ----------------------
__device__ __forceinline__ void convert_core(int bid, int tid, const void* __restrict__ x,
                                             bf16* __restrict__ X0, int isb) {
    int item = bid * 256 + tid;   // cg*2048 + bn  (cg = c/8)
    int cg = item >> 11, bn = item & 2047;
    int b = bn >> 7, n = bn & 127;
    short8 pk;
#pragma unroll
    for (int j = 0; j < 8; ++j)
        pk[j] = f2bs(ldin(x, ((size_t)(b * 512 + cg * 8 + j)) * 128 + n, isb));
    *(short8*)((short*)X0 + ((size_t)cg * BN_ALL + bn) * 8) = pk;
}

__global__ __launch_bounds__(256) void convert_kp(const void* __restrict__ x, bf16* __restrict__ X0,
                                                  const int* __restrict__ dflag) {
    convert_core(blockIdx.x, threadIdx.x, x, X0, *dflag);
}

// ---- pack core: f32/bf16 weights -> bf16 in LDS-tile image ------------------
// R19: isb branched ONCE; short8 / float4 vector loads (base is a multiple
// of 8 elements -> 16B-aligned for both dtypes). Values + f2bs rounding
// identical to the scalar path -> bit-identical output.
__device__ __forceinline__ void pack_core(int item, int isb, const void* __restrict__ w, int ldw,
                                          const void* __restrict__ res, int Cin, int O,
                                          int Mtot, int K, short* __restrict__ out) {
    if (item >= Mtot * (K >> 3)) return;
    int m_local = item & 127;
    int rest = item >> 7;            // (tm*KC + kc)*4 + q
    int q = rest & 3; rest >>= 2;
    int KC = K >> 5;
    int kc = rest % KC, tm = rest / KC;
    int grow = tm * 128 + m_local;
    int k = kc * 32 + q * 8;
    const void* src; size_t base; int dif = 0;
    if (grow < O)          { src = w;   base = (size_t)grow * ldw + k; }
    else if (grow < 2 * O) { src = w;   base = (size_t)(grow - O) * ldw + k; dif = 1; }
    else                   { src = res; base = (size_t)(grow - 2 * O) * Cin + k; }
    short8 pk;
    if (isb) {
        const short* s = (const short*)src + base;
        short8 a = *(const short8*)s;
        if (dif) {
            short8 b = *(const short8*)(s + Cin);
#pragma unroll
            for (int j = 0; j < 8; ++j) pk[j] = f2bs(bs2f(b[j]) - bs2f(a[j]));
        } else {
            pk = a;   // bf16 -> float -> bf16 is exact: direct copy identical
        }
    } else {
        const float* s = (const float*)src + base;
        float4v a0 = *(const float4v*)s;
        float4v a1 = *(const float4v*)(s + 4);
        if (dif) {
            float4v c0 = *(const float4v*)(s + Cin);
            float4v c1 = *(const float4v*)(s + Cin + 4);
#pragma unroll
            for (int j = 0; j < 4; ++j) {
                pk[j]     = f2bs(c0[j] - a0[j]);
                pk[4 + j] = f2bs(c1[j] - a1[j]);
            }
        } else {
#pragma unroll
            for (int j = 0; j < 4; ++j) {
                pk[j]     = f2bs(a0[j]);
                pk[4 + j] = f2bs(a1[j]);
            }
        }
    }
    *(short8*)&out[(size_t)item * 8] = pk;
}

__global__ __launch_bounds__(256) void pack_w(const void* __restrict__ w, int ldw,
                                              const void* __restrict__ res, int Cin, int O,
                                              int Mtot, int K, short* __restrict__ out,
                                              const int* __restrict__ dflag) {
    pack_core(blockIdx.x * 256 + threadIdx.x, *dflag, w, ldw, res, Cin, O, Mtot, K, out);
}

// ---- fused convert + ALL weight packs (tier P2) -----------------------------
// blocks [0,512): convert; [512,768): p1; [768,1152): p2; [1152,1920): p3;
// [1920,3456): p4; [3456,6528): p5.
__global__ __launch_bounds__(256) void convert_pack_all(
        const void* __restrict__ x, bf16* __restrict__ X0,
        const void* __restrict__ w1c, const void* __restrict__ w2c, const void* __restrict__ w3c,
        const void* __restrict__ w4c, const void* __restrict__ w5c,
        const void* __restrict__ r1, const void* __restrict__ r2, const void* __restrict__ r3,
        short* __restrict__ p1, short* __restrict__ p2, short* __restrict__ p3,
        short* __restrict__ p4, short* __restrict__ p5,
        const int* __restrict__ dflag) {
    int isb = *dflag;
    int bid = blockIdx.x, tid = threadIdx.x;
    if (bid < 512) { convert_core(bid, tid, x, X0, isb); return; }
    int pb = bid - 512;
    if (pb < 256)       pack_core(pb * 256 + tid,          isb, w1c, 1024, nullptr, 512, 512, 1024, 512, p1);
    else if (pb < 640)  pack_core((pb - 256) * 256 + tid,  isb, w2c, 1024, r1,      512, 512, 1536, 512, p2);
    else if (pb < 1408) pack_core((pb - 640) * 256 + tid,  isb, w3c, 1024, r2,      512, 1024, 3072, 512, p3);
    else if (pb < 2944) pack_core((pb - 1408) * 256 + tid, isb, w4c, 2048, r3,      1024, 1024, 3072, 1024, p4);
    else                pack_core((pb - 2944) * 256 + tid, isb, w5c, 3072, nullptr, 3072, 2048, 2048, 3072, p5);
}

// ---- Gram via MFMA from k-packed X; one block per batch ---------------------
__global__ __launch_bounds__(256) void gram_k(const bf16* __restrict__ X, int C,
                                              float* __restrict__ G) {
    __shared__ __align__(16) short Bsm[2][8192];   // 128 points x 64 k
    int tid = threadIdx.x;
    int b = blockIdx.x;
    int lane = tid & 63, wv = tid >> 6, wm = wv & 1, wn = wv >> 1;
    int lq = lane >> 4, lr = lane & 15;
    int KC = C >> 6;
    const short* Xs = (const short*)X;

    float4v acc[4][4];
#pragma unroll
    for (int i = 0; i < 4; i++)
#pragma unroll
        for (int j = 0; j < 4; j++) acc[i][j] = (float4v){0.f, 0.f, 0.f, 0.f};

#pragma unroll
    for (int it = 0; it < 4; ++it) {
        int i = tid + it * 256;
        int q = i >> 7, c = i & 127;
        gll16(Xs + ((size_t)q * BN_ALL + b * 128 + c) * 8, &Bsm[0][(size_t)i * 8]);
    }
    __syncthreads();

    int p = 0;
    for (int kc = 0; kc < KC; ++kc) {
        if (kc + 1 < KC) {
#pragma unroll
            for (int it = 0; it < 4; ++it) {
                int i = tid + it * 256;
                int q = i >> 7, c = i & 127;
                gll16(Xs + ((size_t)((kc + 1) * 8 + q) * BN_ALL + b * 128 + c) * 8,
                      &Bsm[p ^ 1][(size_t)i * 8]);
            }
        }
#pragma unroll
        for (int h = 0; h < 2; ++h) {
            short8 av[4], bv[4];
#pragma unroll
            for (int mt = 0; mt < 4; ++mt)
                av[mt] = *(const short8*)&Bsm[p][(size_t)(h * 512 + (lq << 7) + wm * 64 + mt * 16 + lr) * 8];
#pragma unroll
            for (int nt = 0; nt < 4; ++nt)
                bv[nt] = *(const short8*)&Bsm[p][(size_t)(h * 512 + (lq << 7) + wn * 64 + nt * 16 + lr) * 8];
#pragma unroll
            for (int mt = 0; mt < 4; ++mt)
#pragma unroll
                for (int nt = 0; nt < 4; ++nt)
                    acc[mt][nt] = __builtin_amdgcn_mfma_f32_16x16x32_bf16(av[mt], bv[nt], acc[mt][nt], 0, 0, 0);
        }
        __syncthreads();
        p ^= 1;
    }

    float* Gb = G + (size_t)b * 16384;
#pragma unroll
    for (int mt = 0; mt < 4; ++mt)
#pragma unroll
        for (int r = 0; r < 4; ++r) {
            int row = wm * 64 + mt * 16 + lq * 4 + r;
#pragma unroll
            for (int nt = 0; nt < 4; ++nt) {
                int col = wn * 64 + nt * 16 + lr;
                Gb[row * 128 + col] = acc[mt][nt][r];
            }
        }
}

// ---- top-20 core: one wave per (b,n) row; ties -> lower index ---------------
__device__ __forceinline__ void topk_core(int bid, int tid, const float* __restrict__ G,
                                          int* __restrict__ idx) {
    int gw = (bid * 256 + tid) >> 6;   // 0..2047 = b*128+n
    int lane = tid & 63;
    int b = gw >> 7, n = gw & 127;
    const float* Gb = G + (size_t)b * 16384;
    float g0 = Gb[n * 128 + lane];
    float g1 = Gb[n * 128 + 64 + lane];
    float dnn = Gb[n * 129];
    float dm0 = Gb[lane * 129];
    float dm1 = Gb[(64 + lane) * 129];
    float d0 = 2.f * g0 - dnn - dm0;
    float d1 = 2.f * g1 - dnn - dm1;
#pragma unroll
    for (int k = 0; k < 20; ++k) {
        float v; int i;
        if (d1 > d0) { v = d1; i = 64 + lane; } else { v = d0; i = lane; }
#pragma unroll
        for (int off = 1; off < 64; off <<= 1) {
            float ov = __shfl_xor(v, off, 64);
            int   oi = __shfl_xor(i, off, 64);
            if (ov > v || (ov == v && oi < i)) { v = ov; i = oi; }
        }
        if (lane == 0) idx[gw * 20 + k] = i;
        if (i < 64) { if (lane == i) d0 = -3.0e38f; }
        else        { if (lane == i - 64) d1 = -3.0e38f; }
    }
}

__global__ __launch_bounds__(256) void topk_k(const float* __restrict__ G, int* __restrict__ idx) {
    topk_core(blockIdx.x, threadIdx.x, G, idx);
}

// ---- gemm core: packed-A / k-packed-B bf16 MFMA, 128x64 tile, BK=64 ---------
// R12 form: staging via global_load_lds double-buffer; 16 MFMA/wave/barrier.
__device__ __forceinline__ void gemm_core(int bx, int by, int tid,
        const short* __restrict__ packA, const bf16* __restrict__ X,
        float* __restrict__ Cm, int K,
        const void* __restrict__ bnS, const void* __restrict__ bnB,
        int act, const int* __restrict__ dflag) {
    __shared__ __align__(16) short Asm[2][8192];   // 128 rows x 64 k (bf16)
    __shared__ __align__(16) short Bsm[2][4096];   // [(q*64 + c)*8 + j], q=0..7
    int bm  = bx << 7;
    int bn0 = by << 6;
    int lane = tid & 63, wv = tid >> 6, wm = wv & 1, wn = wv >> 1;
    int lq = lane >> 4, lr = lane & 15;
    int KC = K >> 6;
    const short* abase = packA + (size_t)bx * (K >> 5) * 4096;
    const short* Xs = (const short*)X;
    int bq = tid >> 6, bc = tid & 63;

    float4v acc[4][2];
#pragma unroll
    for (int i = 0; i < 4; i++)
#pragma unroll
        for (int j = 0; j < 2; j++) acc[i][j] = (float4v){0.f, 0.f, 0.f, 0.f};

#pragma unroll
    for (int it = 0; it < 4; ++it)
        gll16(abase + (size_t)(tid + it * 256) * 8, &Asm[0][(size_t)(tid + it * 256) * 8]);
    gll16(Xs + ((size_t)bq * BN_ALL + bn0 + bc) * 8,       &Bsm[0][(size_t)tid * 8]);
    gll16(Xs + ((size_t)(bq + 4) * BN_ALL + bn0 + bc) * 8, &Bsm[0][(size_t)(tid + 256) * 8]);
    __syncthreads();

    int p = 0;
    for (int kc = 0; kc < KC; ++kc) {
        if (kc + 1 < KC) {
            const short* ab = abase + (size_t)(kc + 1) * 8192;
#pragma unroll
            for (int it = 0; it < 4; ++it)
                gll16(ab + (size_t)(tid + it * 256) * 8, &Asm[p ^ 1][(size_t)(tid + it * 256) * 8]);
            gll16(Xs + ((size_t)((kc + 1) * 8 + bq) * BN_ALL + bn0 + bc) * 8,
                  &Bsm[p ^ 1][(size_t)tid * 8]);
            gll16(Xs + ((size_t)((kc + 1) * 8 + bq + 4) * BN_ALL + bn0 + bc) * 8,
                  &Bsm[p ^ 1][(size_t)(tid + 256) * 8]);
        }
#pragma unroll
        for (int h = 0; h < 2; ++h) {
            short8 av[4], bv[2];
#pragma unroll
            for (int mt = 0; mt < 4; ++mt)
                av[mt] = *(const short8*)&Asm[p][(size_t)(h * 512 + (lq << 7) + wm * 64 + mt * 16 + lr) * 8];
#pragma unroll
            for (int nt = 0; nt < 2; ++nt)
                bv[nt] = *(const short8*)&Bsm[p][(size_t)(h * 256 + (lq << 6) + wn * 32 + nt * 16 + lr) * 8];
#pragma unroll
            for (int mt = 0; mt < 4; ++mt)
#pragma unroll
                for (int nt = 0; nt < 2; ++nt)
                    acc[mt][nt] = __builtin_amdgcn_mfma_f32_16x16x32_bf16(av[mt], bv[nt], acc[mt][nt], 0, 0, 0);
        }
        __syncthreads();
        p ^= 1;
    }

    int isb = *dflag;
#pragma unroll
    for (int mt = 0; mt < 4; ++mt) {
#pragma unroll
        for (int r = 0; r < 4; ++r) {
            int row = bm + wm * 64 + mt * 16 + lq * 4 + r;
            float s = 1.f, bb = 0.f;
            if (bnS) { s = ldin(bnS, row, isb); bb = ldin(bnB, row, isb); }
#pragma unroll
            for (int nt = 0; nt < 2; ++nt) {
                int col = bn0 + wn * 32 + nt * 16 + lr;
                float v = acc[mt][nt][r];
                if (bnS) v = v * s + bb;
                if (act) v = lrelu(v);
                Cm[(size_t)row * BN_ALL + col] = v;
            }
        }
    }
}

__global__ __launch_bounds__(256) void gemm_pk(const short* __restrict__ packA,
                                               const bf16* __restrict__ X, float* __restrict__ Cm, int K,
                                               const void* __restrict__ bnS, const void* __restrict__ bnB,
                                               int act, const int* __restrict__ dflag) {
    gemm_core(blockIdx.x, blockIdx.y, threadIdx.x, packA, X, Cm, K, bnS, bnB, act, dflag);
}

// ---- fused topk || gemm (tier P2): blocks [0,512)=topk, rest=gemm -----------
// topk reads GRAM (dedicated buffer), gemm writes PS -> no overlap.
__global__ __launch_bounds__(256) void topk_gemm_k(const float* __restrict__ G, int* __restrict__ idx,
                                                   const short* __restrict__ packA,
                                                   const bf16* __restrict__ X, float* __restrict__ Cm,
                                                   int K, const int* __restrict__ dflag) {
    if (blockIdx.x < 512) {
        topk_core(blockIdx.x, threadIdx.x, G, idx);
    } else {
        int g = blockIdx.x - 512;
        gemm_core(g >> 5, g & 31, threadIdx.x, packA, X, Cm, K, nullptr, nullptr, 0, dflag);
    }
}

// ---- legacy kNN (fallback tiers) --------------------------------------------
template <typename S>
__global__ __launch_bounds__(128) void knn_topk(const S* __restrict__ X, int C, int* __restrict__ idx) {
    int b = blockIdx.x >> 7;
    int n = blockIdx.x & 127;
    int m = threadIdx.x;
    const S* base = X + b * 128;
    float s0 = 0, s1 = 0, q0 = 0, q1 = 0;
    for (int c = 0; c < C; c += 2) {
        const S* p = base + (size_t)c * BN_ALL;
        float xm0 = ld1(p + m),          xn0 = ld1(p + n);
        float xm1 = ld1(p + BN_ALL + m), xn1 = ld1(p + BN_ALL + n);
        s0 += xm0 * xn0; q0 += xm0 * xm0;
        s1 += xm1 * xn1; q1 += xm1 * xm1;
    }
    float inner = s0 + s1;
    float xxm   = q0 + q1;
    __shared__ float xx[128];
    __shared__ float dist[128];
    __shared__ float rv[128];
    __shared__ int   ri[128];
    xx[m] = xxm;
    __syncthreads();
    dist[m] = 2.0f * inner - xx[n] - xxm;
    for (int k = 0; k < 20; k++) {
        __syncthreads();
        rv[m] = dist[m]; ri[m] = m;
        __syncthreads();
        for (int off = 64; off > 0; off >>= 1) {
            if (m < off) {
                float a = rv[m], bv = rv[m + off];
                int ia = ri[m], ib = ri[m + off];
                if (bv > a || (bv == a && ib < ia)) { rv[m] = bv; ri[m] = ib; }
            }
            __syncthreads();
        }
        if (m == 0) { idx[blockIdx.x * 20 + k] = ri[0]; dist[ri[0]] = -3.0e38f; }
    }
}

// ---- R5 fallback GEMM (on-the-fly staging, 128x128, linear layouts) ---------
template <typename S>
__global__ __launch_bounds__(256) void gemm_mfma(const void* __restrict__ w, int ldw,
                                                 const void* __restrict__ res, int Cin, int O,
                                                 const S* __restrict__ X, S* __restrict__ Cm, int K,
                                                 const void* __restrict__ bnS, const void* __restrict__ bnB,
                                                 int act, const int* __restrict__ dflag) {
    int isb = *dflag;
    __shared__ short Asm[4096];
    __shared__ short Bsm[4096];
    int tid = threadIdx.x;
    int bm  = blockIdx.x << 7;
    int bn0 = blockIdx.y << 7;
    int lane = tid & 63, wv = tid >> 6;
    int wm = wv & 1, wn = wv >> 1;
    int lq = lane >> 4, lr = lane & 15;

    float4v acc[4][4];
#pragma unroll
    for (int i = 0; i < 4; i++)
#pragma unroll
        for (int j = 0; j < 4; j++) acc[i][j] = (float4v){0.f, 0.f, 0.f, 0.f};

    for (int k0 = 0; k0 < K; k0 += 32) {
#pragma unroll
        for (int it = 0; it < 2; ++it) {
            int i = tid + it * 256;
            int m = i >> 2, q = i & 3;
            int grow = bm + m;
            const void* asrc; size_t abase; int dif = 0;
            if (grow < O)          { asrc = w;   abase = (size_t)grow * ldw; }
            else if (grow < 2 * O) { asrc = w;   abase = (size_t)(grow - O) * ldw; dif = 1; }
            else                   { asrc = res; abase = (size_t)(grow - 2 * O) * Cin; }
            size_t kk = (size_t)k0 + q * 8;
            short8 pk;
#pragma unroll
            for (int j = 0; j < 8; ++j) {
                float v = ldin(asrc, abase + kk + j, isb);
                if (dif) v = ldin(asrc, abase + Cin + kk + j, isb) - v;
                pk[j] = f2bs(v);
            }
            *(short8*)&Asm[(size_t)(q * 128 + m) * 8] = pk;
        }
#pragma unroll
        for (int it = 0; it < 2; ++it) {
            int i = tid + it * 256;
            int q = i >> 7, c = i & 127;
            const S* xp = X + (size_t)(k0 + q * 8) * BN_ALL + bn0 + c;
            short8 pk;
#pragma unroll
            for (int j = 0; j < 8; ++j) pk[j] = f2bs(ld1(xp + (size_t)j * BN_ALL));
            *(short8*)&Bsm[(size_t)i * 8] = pk;
        }
        __syncthreads();
        short8 av[4], bv[4];
#pragma unroll
        for (int mt = 0; mt < 4; ++mt)
            av[mt] = *(const short8*)&Asm[(size_t)((lq << 7) + wm * 64 + mt * 16 + lr) * 8];
#pragma unroll
        for (int nt = 0; nt < 4; ++nt)
            bv[nt] = *(const short8*)&Bsm[(size_t)((lq << 7) + wn * 64 + nt * 16 + lr) * 8];
#pragma unroll
        for (int mt = 0; mt < 4; ++mt)
#pragma unroll
            for (int nt = 0; nt < 4; ++nt)
                acc[mt][nt] = __builtin_amdgcn_mfma_f32_16x16x32_bf16(av[mt], bv[nt], acc[mt][nt], 0, 0, 0);
        __syncthreads();
    }
#pragma unroll
    for (int mt = 0; mt < 4; ++mt) {
#pragma unroll
        for (int r = 0; r < 4; ++r) {
            int row = bm + wm * 64 + mt * 16 + lq * 4 + r;
            float s = 1.f, bb = 0.f;
            if (bnS) { s = ldin(bnS, row, isb); bb = ldin(bnB, row, isb); }
#pragma unroll
            for (int nt = 0; nt < 4; ++nt) {
                int col = bn0 + wn * 64 + nt * 16 + lr;
                float v = acc[mt][nt][r];
                if (bnS) v = v * s + bb;
                if (act) v = lrelu(v);
                st1(Cm + (size_t)row * BN_ALL + col, v);
            }
        }
    }
}

// ---- gather + k-pool + bn + lrelu; T written IN-PLACE over P row o ----------
// one WAVE per (o,b) row; 2 n's per lane; barrier-free shfl_xor butterfly.
template <typename S>
__global__ __launch_bounds__(256) void gather_pool(S* __restrict__ PS, const int* __restrict__ idx,
                                                   const void* __restrict__ bns, const void* __restrict__ bnb,
                                                   float* __restrict__ Mb, int O,
                                                   const int* __restrict__ dflag) {
    int isb = *dflag;
    int wv = threadIdx.x >> 6, lane = threadIdx.x & 63;
    int gw = blockIdx.x * 4 + wv;          // gw = o*16 + b
    int o = gw >> 4, b = gw & 15;
    S* Prow = PS + (size_t)o * BN_ALL + b * 128;
    const S* Srow = PS + (size_t)(O + o) * BN_ALL + b * 128;
    int n0 = lane, n1 = lane + 64;
    const int* id0 = idx + (b * 128 + n0) * 20;
    const int* id1 = idx + (b * 128 + n1) * 20;
    float mx0 = -3.0e38f, mn0 = 3.0e38f, sm0 = 0.f;
    float mx1 = -3.0e38f, mn1 = 3.0e38f, sm1 = 0.f;
#pragma unroll
    for (int k = 0; k < 20; k++) {
        float p = ld1(Prow + id0[k]);
        mx0 = fmaxf(mx0, p); mn0 = fminf(mn0, p); sm0 += p;
    }
#pragma unroll
    for (int k = 0; k < 20; k++) {
        float p = ld1(Prow + id1[k]);
        mx1 = fmaxf(mx1, p); mn1 = fminf(mn1, p); sm1 += p;
    }
    float Sv0 = ld1(Srow + n0), Sv1 = ld1(Srow + n1);
    float s = ldin(bns, o, isb), bb = ldin(bnb, o, isb);
    float ext0 = (s >= 0.f) ? mx0 : mn0;
    float ext1 = (s >= 0.f) ? mx1 : mn1;
    float t0 = lrelu(s * (ext0 + Sv0) + bb);
    float t1 = lrelu(s * (ext1 + Sv1) + bb);
    st1(Prow + n0, t0);
    st1(Prow + n1, t1);
    float r1 = sm0 + sm1;    // == halving-tree step off=64
    float r2 = Sv0 + Sv1;
#pragma unroll
    for (int off = 32; off > 0; off >>= 1) {
        r1 += __shfl_xor(r1, off, 64);
        r2 += __shfl_xor(r2, off, 64);
    }
    if (lane == 0) Mb[b * O + o] = s * (r1 * (1.f / 2560.f) + r2 * (1.f / 128.f)) + bb;
}

// ---- SE stage 1: z[b,t] = relu(w1[t,:] . M[b,:]) — one wave per (b,t) -------
__global__ __launch_bounds__(256) void se1_k(const float* __restrict__ Mb, const void* __restrict__ w1,
                                             float* __restrict__ Z, int O, int r,
                                             const int* __restrict__ dflag) {
    int isb = *dflag;
    int gw = (blockIdx.x * 256 + threadIdx.x) >> 6;   // b*r + t
    int lane = threadIdx.x & 63;
    int b = gw / r, t = gw - b * r;
    const float* mv = Mb + (size_t)b * O;
    float acc = 0.f;
    for (int c = lane; c < O; c += 64) acc += ldin(w1, (size_t)t * O + c, isb) * mv[c];
#pragma unroll
    for (int off = 32; off > 0; off >>= 1) acc += __shfl_xor(acc, off, 64);
    if (lane == 0) Z[b * r + t] = fmaxf(acc, 0.f);
}

// ---- SE stage 2: Y[b,o] = sigmoid(w2[o,:] . z[b,:]) — one wave per (b,o) ----
__global__ __launch_bounds__(256) void se2_k(const float* __restrict__ Z, const void* __restrict__ w2,
                                             float* __restrict__ Y, int O, int r,
                                             const int* __restrict__ dflag) {
    int isb = *dflag;
    int gw = (blockIdx.x * 256 + threadIdx.x) >> 6;   // b*O + o
    int lane = threadIdx.x & 63;
    int b = gw / O, o = gw - b * O;
    float acc = 0.f;
    if (lane < r) acc = ldin(w2, (size_t)o * r + lane, isb) * Z[b * r + lane];
#pragma unroll
    for (int off = 32; off > 0; off >>= 1) acc += __shfl_xor(acc, off, 64);
    if (lane == 0) Y[b * O + o] = 1.f / (1.f + expf(-acc));
}

// ---- legacy SE (fallback tiers) ---------------------------------------------
__global__ __launch_bounds__(256) void se_k(const float* __restrict__ Mb, const void* __restrict__ w1,
                                            const void* __restrict__ w2, float* __restrict__ Y, int O, int r,
                                            const int* __restrict__ dflag) {
    int isb = *dflag;
    int b = blockIdx.x, t = threadIdx.x;
    __shared__ float mloc[1024];
    __shared__ float z[64];
    for (int i = t; i < O; i += 256) mloc[i] = Mb[b * O + i];
    __syncthreads();
    if (t < r) {
        float acc = 0.f;
        for (int c = 0; c < O; c++) acc += ldin(w1, (size_t)t * O + c, isb) * mloc[c];
        z[t] = fmaxf(acc, 0.f);
    }
    __syncthreads();
    for (int o = t; o < O; o += 256) {
        float acc = 0.f;
        for (int j = 0; j < r; j++) acc += ldin(w2, (size_t)o * r + j, isb) * z[j];
        Y[b * O + o] = 1.f / (1.f + expf(-acc));
    }
}

// ---- finalize (tier P): x_next = y*T (+res) -> k-packed bf16 slice ----------
__global__ __launch_bounds__(256) void finalize_kp(const float* __restrict__ PS, const float* __restrict__ Y,
                                                   int useR, bf16* __restrict__ Xdst, int O) {
    int item = blockIdx.x * 256 + threadIdx.x;   // og*2048 + bn  (og = o/8)
    int og = item >> 11, bn = item & 2047;
    int b = bn >> 7;
    short8 pk;
#pragma unroll
    for (int j = 0; j < 8; ++j) {
        int r = og * 8 + j;
        float v = Y[b * O + r] * PS[(size_t)r * BN_ALL + bn];
        if (useR) v += PS[(size_t)(2 * O + r) * BN_ALL + bn];
        pk[j] = f2bs(v);
    }
    *(short8*)((short*)Xdst + ((size_t)og * BN_ALL + bn) * 8) = pk;
}

// ---- legacy finalize (fallback tiers, linear layout) ------------------------
template <typename SP, typename SD>
__global__ __launch_bounds__(256) void finalize(const SP* __restrict__ PS, const float* __restrict__ Y,
                                                int useR, SD* __restrict__ Xdst, int O) {
    int tid = blockIdx.x * 256 + threadIdx.x;   // tid = o*2048 + bn
    int o = tid >> 11, bn = tid & 2047;
    int b = bn >> 7;
    float v = Y[b * O + o] * ld1(PS + tid);
    if (useR) v += ld1(PS + (size_t)(2 * O + o) * BN_ALL + bn);
    st1(Xdst + tid, v);
}

// ---- legacy convert (fallback tiers) ----------------------------------------
template <typename S>
__global__ __launch_bounds__(256) void convert_x(const void* __restrict__ x, S* __restrict__ X0,
                                                 const int* __restrict__ dflag) {
    int isb = *dflag;
    int tid = blockIdx.x * 256 + threadIdx.x;
    int c = tid >> 11, bn = tid & 2047;
    int b = bn >> 7, n = bn & 127;
    st1(X0 + tid, ldin(x, (size_t)(b * 512 + c) * 128 + n, isb));
}

// ---- conv5 pool: one WAVE per (m,b); barrier-free butterfly -----------------
template <typename S>
__global__ __launch_bounds__(256) void pool5(const S* __restrict__ H, float* __restrict__ f) {
    int wv = threadIdx.x >> 6, lane = threadIdx.x & 63;
    int gw = blockIdx.x * 4 + wv;          // gw = m*16 + b
    int m = gw >> 4, b = gw & 15;
    const S* Hp = H + (size_t)m * BN_ALL + b * 128;
    float v0 = ld1(Hp + lane), v1 = ld1(Hp + 64 + lane);
    float mx = fmaxf(v0, v1);
    float sm = v0 + v1;
#pragma unroll
    for (int off = 32; off > 0; off >>= 1) {
        mx = fmaxf(mx, __shfl_xor(mx, off, 64));
        sm += __shfl_xor(sm, off, 64);
    }
    if (lane == 0) {
        f[b * 4096 + m] = mx;
        f[b * 4096 + 2048 + m] = sm * (1.f / 128.f);
    }
}

// ---- head: one wave per (b,o) dot product + optional bias/bn/lrelu ----------
__global__ __launch_bounds__(256) void head_k(const float* __restrict__ in, const void* __restrict__ W,
                                              const void* __restrict__ bias, const void* __restrict__ bns,
                                              const void* __restrict__ bnb, float* __restrict__ outf,
                                              void* __restrict__ outb, int Kd, int Od, int act,
                                              const int* __restrict__ dflag) {
    int isb = *dflag;
    int gw = (blockIdx.x * 256 + threadIdx.x) >> 6;
    int lane = threadIdx.x & 63;
    if (gw >= 16 * Od) return;
    int b = gw / Od, o = gw - b * Od;
    const float* iv = in + b * Kd;
    float acc = 0.f;
    for (int k = lane; k < Kd; k += 64) acc += iv[k] * ldin(W, (size_t)o * Kd + k, isb);
    for (int off = 32; off > 0; off >>= 1) acc += __shfl_xor(acc, off, 64);
    if (lane == 0) {
        float v = acc;
        if (bias) v += ldin(bias, o, isb);
        if (bns) v = v * ldin(bns, o, isb) + ldin(bnb, o, isb);
        if (act) v = lrelu(v);
        if (outb) {
            if (isb) ((bf16*)outb)[gw] = __float2bfloat16(v);
            else     ((float*)outb)[gw] = v;
        } else outf[gw] = v;
    }
}

// ---- ws-too-small signal ----------------------------------------------------
__global__ __launch_bounds__(256) void zero_out(bf16* o, int n) {
    int i = blockIdx.x * 256 + threadIdx.x;
    if (i < n) o[i] = __float2bfloat16(0.f);
}

// ---------------------------------------------------------------------------
#define UNPACK_INPUTS()                                                     \
    const void* x_in   = d_in[0];                                           \
    const void* conv1w = d_in[1];  const void* conv2w = d_in[2];            \
    const void* conv3w = d_in[3];  const void* conv4w = d_in[4];            \
    const void* conv5w = d_in[5];                                           \
    const void* bn1s = d_in[6],  * bn1b = d_in[7];                          \
    const void* bn2s = d_in[8],  * bn2b = d_in[9];                          \
    const void* bn3s = d_in[10], * bn3b = d_in[11];                         \
    const void* bn4s = d_in[12], * bn4b = d_in[13];                         \
    const void* bn5s = d_in[14], * bn5b = d_in[15];                         \
    const void* se1w1 = d_in[16], * se1w2 = d_in[17];                       \
    const void* se2w1 = d_in[18], * se2w2 = d_in[19];                       \
    const void* se3w1 = d_in[20], * se3w2 = d_in[21];                       \
    const void* se4w1 = d_in[22], * se4w2 = d_in[23];                       \
    const void* res1w = d_in[24]; const void* res2w = d_in[25];             \
    const void* res3w = d_in[26]; const void* lin1w = d_in[27];             \
    const void* bn6s = d_in[28], * bn6b = d_in[29];                         \
    const void* lin2w = d_in[30], * lin2b = d_in[31];                       \
    const void* bn7s = d_in[32], * bn7b = d_in[33];                         \
    const void* lin3w = d_in[34], * lin3b = d_in[35];

// ---- Tier P2: all packs upfront, fused topk||gemm, parallel 2-stage SE ------
static void run_net_packed2(void* const* d_in, void* d_out, void* d_ws, hipStream_t stream) {
    UNPACK_INPUTS();
    float* WS = (float*)d_ws;
    float* PS = WS;                                   // 3072 x 2048 f32
    bf16*  XC = (bf16*)(WS + 6291456);                // 3072 x 2048 bf16 k-packed
    // private PACK regions (shorts)
    short* P1 = (short*)(WS + 12582912);              // 524288 shorts
    short* P2 = P1 + 524288;                          // 786432
    short* P3 = P2 + 786432;                          // 1572864
    short* P4 = P3 + 1572864;                         // 3145728
    short* P5 = P4 + 3145728;                         // 6291456  (ends @ float 18743296)
    float* MB = WS + 18743296;
    float* YB = MB + 16384;
    float* FB = YB + 16384;
    float* F1 = FB + 65536;
    float* F2 = F1 + 8192;
    int* IDX  = (int*)(F2 + 4096);
    int* DFLAG = IDX + 40960;
    float* ZB = (float*)(DFLAG + 16);                 // 1024 floats (< GRAM start)
    float* GRAM = WS + 18900000;                      // 262144 floats, dedicated
    bf16*  X0 = (bf16*)(PS + (size_t)2048 * BN_ALL);  // PS rows 2048.. (block 1 only)
    bf16* X1 = XC;
    bf16* X2 = XC + (size_t)512 * BN_ALL;
    bf16* X3 = XC + (size_t)1024 * BN_ALL;
    bf16* X4 = XC + (size_t)2048 * BN_ALL;

    detect_dtype<<<1, 256, 0, stream>>>(x_in, DFLAG);
    convert_pack_all<<<6528, 256, 0, stream>>>(x_in, X0,
        conv1w, conv2w, conv3w, conv4w, conv5w, res1w, res2w, res3w,
        P1, P2, P3, P4, P5, DFLAG);

    // block 1: O=512, Mtot=1024, K=512, r=32
    gram_k<<<16, 256, 0, stream>>>(X0, 512, GRAM);
    topk_gemm_k<<<512 + 8 * 32, 256, 0, stream>>>(GRAM, IDX, P1, X0, PS, 512, DFLAG);
    gather_pool<float><<<2048, 256, 0, stream>>>(PS, IDX, bn1s, bn1b, MB, 512, DFLAG);
    se1_k<<<128, 256, 0, stream>>>(MB, se1w1, ZB, 512, 32, DFLAG);
    se2_k<<<2048, 256, 0, stream>>>(ZB, se1w2, YB, 512, 32, DFLAG);
    finalize_kp<<<512, 256, 0, stream>>>(PS, YB, 0, X1, 512);

    // block 2: Mtot=1536, K=512, res1, r=32
    gram_k<<<16, 256, 0, stream>>>(X1, 512, GRAM);
    topk_gemm_k<<<512 + 12 * 32, 256, 0, stream>>>(GRAM, IDX, P2, X1, PS, 512, DFLAG);
    gather_pool<float><<<2048, 256, 0, stream>>>(PS, IDX, bn2s, bn2b, MB, 512, DFLAG);
    se1_k<<<128, 256, 0, stream>>>(MB, se2w1, ZB, 512, 32, DFLAG);
    se2_k<<<2048, 256, 0, stream>>>(ZB, se2w2, YB, 512, 32, DFLAG);
    finalize_kp<<<512, 256, 0, stream>>>(PS, YB, 1, X2, 512);

    // block 3: O=1024, Mtot=3072, K=512, res2, r=64
    gram_k<<<16, 256, 0, stream>>>(X2, 512, GRAM);
    topk_gemm_k<<<512 + 24 * 32, 256, 0, stream>>>(GRAM, IDX, P3, X2, PS, 512, DFLAG);
    gather_pool<float><<<4096, 256, 0, stream>>>(PS, IDX, bn3s, bn3b, MB, 1024, DFLAG);
    se1_k<<<256, 256, 0, stream>>>(MB, se3w1, ZB, 1024, 64, DFLAG);
    se2_k<<<4096, 256, 0, stream>>>(ZB, se3w2, YB, 1024, 64, DFLAG);
    finalize_kp<<<1024, 256, 0, stream>>>(PS, YB, 1, X3, 1024);

    // block 4: O=1024, Mtot=3072, K=1024, res3, r=64
    gram_k<<<16, 256, 0, stream>>>(X3, 1024, GRAM);
    topk_gemm_k<<<512 + 24 * 32, 256, 0, stream>>>(GRAM, IDX, P4, X3, PS, 1024, DFLAG);
    gather_pool<float><<<4096, 256, 0, stream>>>(PS, IDX, bn4s, bn4b, MB, 1024, DFLAG);
    se1_k<<<256, 256, 0, stream>>>(MB, se4w1, ZB, 1024, 64, DFLAG);
    se2_k<<<4096, 256, 0, stream>>>(ZB, se4w2, YB, 1024, 64, DFLAG);
    finalize_kp<<<1024, 256, 0, stream>>>(PS, YB, 1, X4, 1024);

    // conv5: Mtot=2048, K=3072, bn5+lrelu
    gemm_pk<<<dim3(16, 32), 256, 0, stream>>>(P5, XC, PS, 3072, bn5s, bn5b, 1, DFLAG);
    pool5<float><<<8192, 256, 0, stream>>>(PS, FB);

    head_k<<<2048, 256, 0, stream>>>(FB, lin1w, nullptr, bn6s, bn6b, F1, nullptr, 4096, 512, 1, DFLAG);
    head_k<<<1024, 256, 0, stream>>>(F1, lin2w, lin2b, bn7s, bn7b, F2, nullptr, 512, 256, 1, DFLAG);
    head_k<<<160, 256, 0, stream>>>(F2, lin3w, lin3b, nullptr, nullptr, nullptr, d_out, 256, 40, 0, DFLAG);
}

// ---- Tier P: R15 path (fallback when ws < P2 but >= 63MB) -------------------
static void run_net_packed(void* const* d_in, void* d_out, void* d_ws, hipStream_t stream) {
    UNPACK_INPUTS();
    float* WS = (float*)d_ws;
    float* PS   = WS;
    bf16*  XC   = (bf16*)(WS + 6291456);
    short* PACK = (short*)(WS + 12582912);
    float* MB = WS + 15728640;
    float* YB = MB + 16384;
    float* FB = YB + 16384;
    float* F1 = FB + 65536;
    float* F2 = F1 + 8192;
    int* IDX  = (int*)(F2 + 4096);
    int* DFLAG = IDX + 40960;
    float* ZB = (float*)(DFLAG + 16);
    bf16*  X0 = (bf16*)(PS + (size_t)2048 * BN_ALL);
    float* GRAM = PS;
    bf16* X1 = XC;
    bf16* X2 = XC + (size_t)512 * BN_ALL;
    bf16* X3 = XC + (size_t)1024 * BN_ALL;
    bf16* X4 = XC + (size_t)2048 * BN_ALL;

    detect_dtype<<<1, 256, 0, stream>>>(x_in, DFLAG);
    convert_kp<<<512, 256, 0, stream>>>(x_in, X0, DFLAG);

    gram_k<<<16, 256, 0, stream>>>(X0, 512, GRAM);
    topk_k<<<512, 256, 0, stream>>>(GRAM, IDX);
    pack_w<<<256, 256, 0, stream>>>(conv1w, 1024, nullptr, 512, 512, 1024, 512, PACK, DFLAG);
    gemm_pk<<<dim3(8, 32), 256, 0, stream>>>(PACK, X0, PS, 512, nullptr, nullptr, 0, DFLAG);
    gather_pool<float><<<2048, 256, 0, stream>>>(PS, IDX, bn1s, bn1b, MB, 512, DFLAG);
    se1_k<<<128, 256, 0, stream>>>(MB, se1w1, ZB, 512, 32, DFLAG);
    se2_k<<<2048, 256, 0, stream>>>(ZB, se1w2, YB, 512, 32, DFLAG);
    finalize_kp<<<512, 256, 0, stream>>>(PS, YB, 0, X1, 512);

    gram_k<<<16, 256, 0, stream>>>(X1, 512, GRAM);
    topk_k<<<512, 256, 0, stream>>>(GRAM, IDX);
    pack_w<<<384, 256, 0, stream>>>(conv2w, 1024, res1w, 512, 512, 1536, 512, PACK, DFLAG);
    gemm_pk<<<dim3(12, 32), 256, 0, stream>>>(PACK, X1, PS, 512, nullptr, nullptr, 0, DFLAG);
    gather_pool<float><<<2048, 256, 0, stream>>>(PS, IDX, bn2s, bn2b, MB, 512, DFLAG);
    se1_k<<<128, 256, 0, stream>>>(MB, se2w1, ZB, 512, 32, DFLAG);
    se2_k<<<2048, 256, 0, stream>>>(ZB, se2w2, YB, 512, 32, DFLAG);
    finalize_kp<<<512, 256, 0, stream>>>(PS, YB, 1, X2, 512);

    gram_k<<<16, 256, 0, stream>>>(X2, 512, GRAM);
    topk_k<<<512, 256, 0, stream>>>(GRAM, IDX);
    pack_w<<<768, 256, 0, stream>>>(conv3w, 1024, res2w, 512, 1024, 3072, 512, PACK, DFLAG);
    gemm_pk<<<dim3(24, 32), 256, 0, stream>>>(PACK, X2, PS, 512, nullptr, nullptr, 0, DFLAG);
    gather_pool<float><<<4096, 256, 0, stream>>>(PS, IDX, bn3s, bn3b, MB, 1024, DFLAG);
    se1_k<<<256, 256, 0, stream>>>(MB, se3w1, ZB, 1024, 64, DFLAG);
    se2_k<<<4096, 256, 0, stream>>>(ZB, se3w2, YB, 1024, 64, DFLAG);
    finalize_kp<<<1024, 256, 0, stream>>>(PS, YB, 1, X3, 1024);

    gram_k<<<16, 256, 0, stream>>>(X3, 1024, GRAM);
    topk_k<<<512, 256, 0, stream>>>(GRAM, IDX);
    pack_w<<<1536, 256, 0, stream>>>(conv4w, 2048, res3w, 1024, 1024, 3072, 1024, PACK, DFLAG);
    gemm_pk<<<dim3(24, 32), 256, 0, stream>>>(PACK, X3, PS, 1024, nullptr, nullptr, 0, DFLAG);
    gather_pool<float><<<4096, 256, 0, stream>>>(PS, IDX, bn4s, bn4b, MB, 1024, DFLAG);
    se1_k<<<256, 256, 0, stream>>>(MB, se4w1, ZB, 1024, 64, DFLAG);
    se2_k<<<4096, 256, 0, stream>>>(ZB, se4w2, YB, 1024, 64, DFLAG);
    finalize_kp<<<1024, 256, 0, stream>>>(PS, YB, 1, X4, 1024);

    pack_w<<<3072, 256, 0, stream>>>(conv5w, 3072, nullptr, 3072, 2048, 2048, 3072, PACK, DFLAG);
    gemm_pk<<<dim3(16, 32), 256, 0, stream>>>(PACK, XC, PS, 3072, bn5s, bn5b, 1, DFLAG);
    pool5<float><<<8192, 256, 0, stream>>>(PS, FB);

    head_k<<<2048, 256, 0, stream>>>(FB, lin1w, nullptr, bn6s, bn6b, F1, nullptr, 4096, 512, 1, DFLAG);
    head_k<<<1024, 256, 0, stream>>>(F1, lin2w, lin2b, bn7s, bn7b, F2, nullptr, 512, 256, 1, DFLAG);
    head_k<<<160, 256, 0, stream>>>(F2, lin3w, lin3b, nullptr, nullptr, nullptr, d_out, 256, 40, 0, DFLAG);
}

// ---- Tier A/B fallback (R5 path, linear layouts) ----------------------------
template <typename S>
static void run_net(void* const* d_in, void* d_out, void* d_ws, hipStream_t stream) {
    UNPACK_INPUTS();
    const size_t RC = (size_t)3072 * BN_ALL;
    S* PS = (S*)d_ws;
    S* XC = PS + RC;
    S* X0 = PS + (size_t)2048 * BN_ALL;
    float* MB = (float*)(XC + RC);
    float* YB = MB + 16 * 1024;
    float* FB = YB + 16 * 1024;
    float* F1 = FB + 16 * 4096;
    float* F2 = F1 + 16 * 512;
    int* IDX  = (int*)(F2 + 16 * 256);
    int* DFLAG = IDX + 16 * 128 * 20;

    S* X1 = XC;
    S* X2 = XC + (size_t)512 * BN_ALL;
    S* X3 = XC + (size_t)1024 * BN_ALL;
    S* X4 = XC + (size_t)2048 * BN_ALL;

    detect_dtype<<<1, 256, 0, stream>>>(x_in, DFLAG);
    convert_x<S><<<4096, 256, 0, stream>>>(x_in, X0, DFLAG);

    knn_topk<S><<<2048, 128, 0, stream>>>(X0, 512, IDX);
    gemm_mfma<S><<<dim3(8, 16), 256, 0, stream>>>(conv1w, 1024, nullptr, 512, 512, X0, PS, 512, nullptr, nullptr, 0, DFLAG);
    gather_pool<S><<<2048, 256, 0, stream>>>(PS, IDX, bn1s, bn1b, MB, 512, DFLAG);
    se_k<<<16, 256, 0, stream>>>(MB, se1w1, se1w2, YB, 512, 32, DFLAG);
    finalize<S, S><<<4096, 256, 0, stream>>>(PS, YB, 0, X1, 512);

    knn_topk<S><<<2048, 128, 0, stream>>>(X1, 512, IDX);
    gemm_mfma<S><<<dim3(12, 16), 256, 0, stream>>>(conv2w, 1024, res1w, 512, 512, X1, PS, 512, nullptr, nullptr, 0, DFLAG);
    gather_pool<S><<<2048, 256, 0, stream>>>(PS, IDX, bn2s, bn2b, MB, 512, DFLAG);
    se_k<<<16, 256, 0, stream>>>(MB, se2w1, se2w2, YB, 512, 32, DFLAG);
    finalize<S, S><<<4096, 256, 0, stream>>>(PS, YB, 1, X2, 512);

    knn_topk<S><<<2048, 128, 0, stream>>>(X2, 512, IDX);
    gemm_mfma<S><<<dim3(24, 16), 256, 0, stream>>>(conv3w, 1024, res2w, 512, 1024, X2, PS, 512, nullptr, nullptr, 0, DFLAG);
    gather_pool<S><<<4096, 256, 0, stream>>>(PS, IDX, bn3s, bn3b, MB, 1024, DFLAG);
    se_k<<<16, 256, 0, stream>>>(MB, se3w1, se3w2, YB, 1024, 64, DFLAG);
    finalize<S, S><<<8192, 256, 0, stream>>>(PS, YB, 1, X3, 1024);

    knn_topk<S><<<2048, 128, 0, stream>>>(X3, 1024, IDX);
    gemm_mfma<S><<<dim3(24, 16), 256, 0, stream>>>(conv4w, 2048, res3w, 1024, 1024, X3, PS, 1024, nullptr, nullptr, 0, DFLAG);
    gather_pool<S><<<4096, 256, 0, stream>>>(PS, IDX, bn4s, bn4b, MB, 1024, DFLAG);
    se_k<<<16, 256, 0, stream>>>(MB, se4w1, se4w2, YB, 1024, 64, DFLAG);
    finalize<S, S><<<8192, 256, 0, stream>>>(PS, YB, 1, X4, 1024);

    gemm_mfma<S><<<dim3(16, 16), 256, 0, stream>>>(conv5w, 3072, nullptr, 3072, 2048, XC, PS, 3072, bn5s, bn5b, 1, DFLAG);
    pool5<S><<<8192, 256, 0, stream>>>(PS, FB);

    head_k<<<2048, 256, 0, stream>>>(FB, lin1w, nullptr, bn6s, bn6b, F1, nullptr, 4096, 512, 1, DFLAG);
    head_k<<<1024, 256, 0, stream>>>(F1, lin2w, lin2b, bn7s, bn7b, F2, nullptr, 512, 256, 1, DFLAG);
    head_k<<<160, 256, 0, stream>>>(F2, lin3w, lin3b, nullptr, nullptr, nullptr, d_out, 256, 40, 0, DFLAG);
}

extern "C" void kernel_launch(void* const* d_in, const int* in_sizes, int n_in,
                              void* d_out, int out_size, void* d_ws, size_t ws_size,
                              hipStream_t stream) {
    const size_t SMALL = (16 * 1024 + 16 * 1024 + 16 * 4096 + 16 * 512 + 16 * 256) * 4
                       + 16 * 128 * 20 * 4 + 8192;
    const size_t NEED_P2     = ((size_t)18900000 + 262144 + 4096) * 4;   // ~76.7MB
    const size_t NEED_PACKED = (size_t)15728640 * 4 + SMALL;
    const size_t NEED_F32    = 2 * ((size_t)3072 * BN_ALL * 4) + SMALL;
    const size_t NEED_BF16   = 2 * ((size_t)3072 * BN_ALL * 2) + SMALL;
    if (ws_size >= NEED_P2) {
        run_net_packed2(d_in, d_out, d_ws, stream);
    } else if (ws_size >= NEED_PACKED) {
        run_net_packed(d_in, d_out, d_ws, stream);
    } else if (ws_size >= NEED_F32) {
        run_net<float>(d_in, d_out, d_ws, stream);
    } else if (ws_size >= NEED_BF16) {
        run_net<bf16>(d_in, d_out, d_ws, stream);
    } else {
        zero_out<<<3, 256, 0, stream>>>((bf16*)d_out, out_size);
    }
}

// Round 10
// 544.575 us; speedup vs baseline: 2.3155x; 1.0140x over previous
//
#include <hip/hip_runtime.h>
#include <hip/hip_bf16.h>

// ---------------------------------------------------------------------------
// DGCNN-ish network, B=16, N=128, K=20.  (R20: gram||gemm fusion + se2-in-finalize)
// R19 counters: pack fixed (out of top-5); conv5 gemm at its structural
// plateau (~47us). Remaining lever = chain structure: gram_k ran ALONE at
// 16 blocks (6% of machine) 4x, and se2 was a separate 3us launch.
// R20: (1) gram||gemm fused via union 48KB LDS (cores take an LDS pointer;
// identical addresses + op order -> bit-identical). topk becomes standalone.
// (2) finalize2_kp recomputes its 16 needed Y values with se2_k's EXACT
// wave ops (ternary load, xor-reduce, lane0 sigmoid) from ZB -> bit-identical.
// Per-block chain: [gram||gemm] -> topk -> gather -> se1 -> fin2 (5 launches).
// Tier P (R15 path) and Tier A/B fallbacks unchanged.
// ---------------------------------------------------------------------------

#define BN_ALL 2048   // B*N = 16*128
typedef __hip_bfloat16 bf16;
typedef __attribute__((ext_vector_type(8))) short short8;
typedef __attribute__((ext_vector_type(4))) float float4v;

__device__ __forceinline__ float b2f(bf16 v) { return __bfloat162float(v); }
__device__ __forceinline__ float bs2f(short s) { return __bfloat162float(*reinterpret_cast<bf16*>(&s)); }
__device__ __forceinline__ float lrelu(float v) { return v >= 0.f ? v : 0.2f * v; }
__device__ __forceinline__ short f2bs(float v) {
    bf16 h = __float2bfloat16(v);
    return *reinterpret_cast<short*>(&h);
}

// async 16-byte global->LDS DMA. LDS dest must be linear in lane.
__device__ __forceinline__ void gll16(const void* g, void* l) {
    __builtin_amdgcn_global_load_lds(
        (const __attribute__((address_space(1))) unsigned int*)g,
        (__attribute__((address_space(3))) unsigned int*)l,
        16, 0, 0);
}

// dual-dtype input load: isb=1 -> bf16, isb=0 -> f32
__device__ __forceinline__ float ldin(const void* p, size_t i, int isb) {
    return isb ? __bfloat162float(((const bf16*)p)[i]) : ((const float*)p)[i];
}

__device__ __forceinline__ float ld1(const float* p) { return *p; }
__device__ __forceinline__ float ld1(const bf16* p)  { return __bfloat162float(*p); }
__device__ __forceinline__ void st1(float* p, float v) { *p = v; }
__device__ __forceinline__ void st1(bf16* p, float v)  { *p = __float2bfloat16(v); }

// ---- dtype detection: sample 4096 dwords of x; f32 data -> sane exponents ---
__global__ __launch_bounds__(256) void detect_dtype(const void* __restrict__ x, int* __restrict__ flag) {
    const unsigned* u = (const unsigned*)x;
    int sane = 0;
    for (int i = threadIdx.x; i < 4096; i += 256) {
        unsigned e = (u[i] >> 23) & 0xFF;
        sane += (e >= 87 && e <= 167) ? 1 : 0;   // |v| in [2^-40, 2^40]
    }
    __shared__ int sh[256];
    sh[threadIdx.x] = sane;
    __syncthreads();
    for (int off = 128; off > 0; off >>= 1) {
        if (threadIdx.x < off) sh[threadIdx.x] += sh[threadIdx.x + off];
        __syncthreads();
    }
    if (threadIdx.x == 0) *flag = (sh[0] < 2048) ? 1 : 0;   // 1 = bf16, 0 = f32
}

// ---- convert core: input x (B,C,N) -> X0 k-packed bf16 ----------------------
__device__ __forceinline__ void convert_core(int bid, int tid, const void* __restrict__ x,
                                             bf16* __restrict__ X0, int isb) {
    int item = bid * 256 + tid;   // cg*2048 + bn  (cg = c/8)
    int cg = item >> 11, bn = item & 2047;
    int b = bn >> 7, n = bn & 127;
    short8 pk;
#pragma unroll
    for (int j = 0; j < 8; ++j)
        pk[j] = f2bs(ldin(x, ((size_t)(b * 512 + cg * 8 + j)) * 128 + n, isb));
    *(short8*)((short*)X0 + ((size_t)cg * BN_ALL + bn) * 8) = pk;
}

__global__ __launch_bounds__(256) void convert_kp(const void* __restrict__ x, bf16* __restrict__ X0,
                                                  const int* __restrict__ dflag) {
    convert_core(blockIdx.x, threadIdx.x, x, X0, *dflag);
}

// ---- pack core: f32/bf16 weights -> bf16 in LDS-tile image ------------------
// R19: isb branched once; short8 / float4 vector loads. Bit-identical.
__device__ __forceinline__ void pack_core(int item, int isb, const void* __restrict__ w, int ldw,
                                          const void* __restrict__ res, int Cin, int O,
                                          int Mtot, int K, short* __restrict__ out) {
    if (item >= Mtot * (K >> 3)) return;
    int m_local = item & 127;
    int rest = item >> 7;            // (tm*KC + kc)*4 + q
    int q = rest & 3; rest >>= 2;
    int KC = K >> 5;
    int kc = rest % KC, tm = rest / KC;
    int grow = tm * 128 + m_local;
    int k = kc * 32 + q * 8;
    const void* src; size_t base; int dif = 0;
    if (grow < O)          { src = w;   base = (size_t)grow * ldw + k; }
    else if (grow < 2 * O) { src = w;   base = (size_t)(grow - O) * ldw + k; dif = 1; }
    else                   { src = res; base = (size_t)(grow - 2 * O) * Cin + k; }
    short8 pk;
    if (isb) {
        const short* s = (const short*)src + base;
        short8 a = *(const short8*)s;
        if (dif) {
            short8 b = *(const short8*)(s + Cin);
#pragma unroll
            for (int j = 0; j < 8; ++j) pk[j] = f2bs(bs2f(b[j]) - bs2f(a[j]));
        } else {
            pk = a;   // bf16 -> float -> bf16 is exact: direct copy identical
        }
    } else {
        const float* s = (const float*)src + base;
        float4v a0 = *(const float4v*)s;
        float4v a1 = *(const float4v*)(s + 4);
        if (dif) {
            float4v c0 = *(const float4v*)(s + Cin);
            float4v c1 = *(const float4v*)(s + Cin + 4);
#pragma unroll
            for (int j = 0; j < 4; ++j) {
                pk[j]     = f2bs(c0[j] - a0[j]);
                pk[4 + j] = f2bs(c1[j] - a1[j]);
            }
        } else {
#pragma unroll
            for (int j = 0; j < 4; ++j) {
                pk[j]     = f2bs(a0[j]);
                pk[4 + j] = f2bs(a1[j]);
            }
        }
    }
    *(short8*)&out[(size_t)item * 8] = pk;
}

__global__ __launch_bounds__(256) void pack_w(const void* __restrict__ w, int ldw,
                                              const void* __restrict__ res, int Cin, int O,
                                              int Mtot, int K, short* __restrict__ out,
                                              const int* __restrict__ dflag) {
    pack_core(blockIdx.x * 256 + threadIdx.x, *dflag, w, ldw, res, Cin, O, Mtot, K, out);
}

// ---- fused convert + ALL weight packs (tier P2) -----------------------------
__global__ __launch_bounds__(256) void convert_pack_all(
        const void* __restrict__ x, bf16* __restrict__ X0,
        const void* __restrict__ w1c, const void* __restrict__ w2c, const void* __restrict__ w3c,
        const void* __restrict__ w4c, const void* __restrict__ w5c,
        const void* __restrict__ r1, const void* __restrict__ r2, const void* __restrict__ r3,
        short* __restrict__ p1, short* __restrict__ p2, short* __restrict__ p3,
        short* __restrict__ p4, short* __restrict__ p5,
        const int* __restrict__ dflag) {
    int isb = *dflag;
    int bid = blockIdx.x, tid = threadIdx.x;
    if (bid < 512) { convert_core(bid, tid, x, X0, isb); return; }
    int pb = bid - 512;
    if (pb < 256)       pack_core(pb * 256 + tid,          isb, w1c, 1024, nullptr, 512, 512, 1024, 512, p1);
    else if (pb < 640)  pack_core((pb - 256) * 256 + tid,  isb, w2c, 1024, r1,      512, 512, 1536, 512, p2);
    else if (pb < 1408) pack_core((pb - 640) * 256 + tid,  isb, w3c, 1024, r2,      512, 1024, 3072, 512, p3);
    else if (pb < 2944) pack_core((pb - 1408) * 256 + tid, isb, w4c, 2048, r3,      1024, 1024, 3072, 1024, p4);
    else                pack_core((pb - 2944) * 256 + tid, isb, w5c, 3072, nullptr, 3072, 2048, 2048, 3072, p5);
}

// ---- Gram core: MFMA from k-packed X; LDS passed in (2 x 8192 shorts) -------
__device__ __forceinline__ void gram_core(int b, int tid, short* __restrict__ Bs,
                                          const bf16* __restrict__ X, int C,
                                          float* __restrict__ G) {
    int lane = tid & 63, wv = tid >> 6, wm = wv & 1, wn = wv >> 1;
    int lq = lane >> 4, lr = lane & 15;
    int KC = C >> 6;
    const short* Xs = (const short*)X;

    float4v acc[4][4];
#pragma unroll
    for (int i = 0; i < 4; i++)
#pragma unroll
        for (int j = 0; j < 4; j++) acc[i][j] = (float4v){0.f, 0.f, 0.f, 0.f};

#pragma unroll
    for (int it = 0; it < 4; ++it) {
        int i = tid + it * 256;
        int q = i >> 7, c = i & 127;
        gll16(Xs + ((size_t)q * BN_ALL + b * 128 + c) * 8, Bs + (size_t)i * 8);
    }
    __syncthreads();

    int p = 0;
    for (int kc = 0; kc < KC; ++kc) {
        if (kc + 1 < KC) {
#pragma unroll
            for (int it = 0; it < 4; ++it) {
                int i = tid + it * 256;
                int q = i >> 7, c = i & 127;
                gll16(Xs + ((size_t)((kc + 1) * 8 + q) * BN_ALL + b * 128 + c) * 8,
                      Bs + (size_t)(p ^ 1) * 8192 + (size_t)i * 8);
            }
        }
        const short* Bp = Bs + (size_t)p * 8192;
#pragma unroll
        for (int h = 0; h < 2; ++h) {
            short8 av[4], bv[4];
#pragma unroll
            for (int mt = 0; mt < 4; ++mt)
                av[mt] = *(const short8*)&Bp[(size_t)(h * 512 + (lq << 7) + wm * 64 + mt * 16 + lr) * 8];
#pragma unroll
            for (int nt = 0; nt < 4; ++nt)
                bv[nt] = *(const short8*)&Bp[(size_t)(h * 512 + (lq << 7) + wn * 64 + nt * 16 + lr) * 8];
#pragma unroll
            for (int mt = 0; mt < 4; ++mt)
#pragma unroll
                for (int nt = 0; nt < 4; ++nt)
                    acc[mt][nt] = __builtin_amdgcn_mfma_f32_16x16x32_bf16(av[mt], bv[nt], acc[mt][nt], 0, 0, 0);
        }
        __syncthreads();
        p ^= 1;
    }

    float* Gb = G + (size_t)b * 16384;
#pragma unroll
    for (int mt = 0; mt < 4; ++mt)
#pragma unroll
        for (int r = 0; r < 4; ++r) {
            int row = wm * 64 + mt * 16 + lq * 4 + r;
#pragma unroll
            for (int nt = 0; nt < 4; ++nt) {
                int col = wn * 64 + nt * 16 + lr;
                Gb[row * 128 + col] = acc[mt][nt][r];
            }
        }
}

__global__ __launch_bounds__(256) void gram_k(const bf16* __restrict__ X, int C,
                                              float* __restrict__ G) {
    __shared__ __align__(16) short SMEM[16384];
    gram_core(blockIdx.x, threadIdx.x, SMEM, X, C, G);
}

// ---- top-20 core: one wave per (b,n) row; ties -> lower index ---------------
__device__ __forceinline__ void topk_core(int bid, int tid, const float* __restrict__ G,
                                          int* __restrict__ idx) {
    int gw = (bid * 256 + tid) >> 6;   // 0..2047 = b*128+n
    int lane = tid & 63;
    int b = gw >> 7, n = gw & 127;
    const float* Gb = G + (size_t)b * 16384;
    float g0 = Gb[n * 128 + lane];
    float g1 = Gb[n * 128 + 64 + lane];
    float dnn = Gb[n * 129];
    float dm0 = Gb[lane * 129];
    float dm1 = Gb[(64 + lane) * 129];
    float d0 = 2.f * g0 - dnn - dm0;
    float d1 = 2.f * g1 - dnn - dm1;
#pragma unroll
    for (int k = 0; k < 20; ++k) {
        float v; int i;
        if (d1 > d0) { v = d1; i = 64 + lane; } else { v = d0; i = lane; }
#pragma unroll
        for (int off = 1; off < 64; off <<= 1) {
            float ov = __shfl_xor(v, off, 64);
            int   oi = __shfl_xor(i, off, 64);
            if (ov > v || (ov == v && oi < i)) { v = ov; i = oi; }
        }
        if (lane == 0) idx[gw * 20 + k] = i;
        if (i < 64) { if (lane == i) d0 = -3.0e38f; }
        else        { if (lane == i - 64) d1 = -3.0e38f; }
    }
}

__global__ __launch_bounds__(256) void topk_k(const float* __restrict__ G, int* __restrict__ idx) {
    topk_core(blockIdx.x, threadIdx.x, G, idx);
}

// ---- gemm core: packed-A / k-packed-B bf16 MFMA, 128x64 tile, BK=64 ---------
// LDS passed in: As = lds (2 x 8192 shorts), Bs = lds + 16384 (2 x 4096).
__device__ __forceinline__ void gemm_core(int bx, int by, int tid, short* __restrict__ lds,
        const short* __restrict__ packA, const bf16* __restrict__ X,
        float* __restrict__ Cm, int K,
        const void* __restrict__ bnS, const void* __restrict__ bnB,
        int act, const int* __restrict__ dflag) {
    short* As = lds;            // 2 x 8192
    short* Bs = lds + 16384;    // 2 x 4096
    int bm  = bx << 7;
    int bn0 = by << 6;
    int lane = tid & 63, wv = tid >> 6, wm = wv & 1, wn = wv >> 1;
    int lq = lane >> 4, lr = lane & 15;
    int KC = K >> 6;
    const short* abase = packA + (size_t)bx * (K >> 5) * 4096;
    const short* Xs = (const short*)X;
    int bq = tid >> 6, bc = tid & 63;

    float4v acc[4][2];
#pragma unroll
    for (int i = 0; i < 4; i++)
#pragma unroll
        for (int j = 0; j < 2; j++) acc[i][j] = (float4v){0.f, 0.f, 0.f, 0.f};

#pragma unroll
    for (int it = 0; it < 4; ++it)
        gll16(abase + (size_t)(tid + it * 256) * 8, As + (size_t)(tid + it * 256) * 8);
    gll16(Xs + ((size_t)bq * BN_ALL + bn0 + bc) * 8,       Bs + (size_t)tid * 8);
    gll16(Xs + ((size_t)(bq + 4) * BN_ALL + bn0 + bc) * 8, Bs + (size_t)(tid + 256) * 8);
    __syncthreads();

    int p = 0;
    for (int kc = 0; kc < KC; ++kc) {
        if (kc + 1 < KC) {
            const short* ab = abase + (size_t)(kc + 1) * 8192;
#pragma unroll
            for (int it = 0; it < 4; ++it)
                gll16(ab + (size_t)(tid + it * 256) * 8,
                      As + (size_t)(p ^ 1) * 8192 + (size_t)(tid + it * 256) * 8);
            gll16(Xs + ((size_t)((kc + 1) * 8 + bq) * BN_ALL + bn0 + bc) * 8,
                  Bs + (size_t)(p ^ 1) * 4096 + (size_t)tid * 8);
            gll16(Xs + ((size_t)((kc + 1) * 8 + bq + 4) * BN_ALL + bn0 + bc) * 8,
                  Bs + (size_t)(p ^ 1) * 4096 + (size_t)(tid + 256) * 8);
        }
        const short* Ap = As + (size_t)p * 8192;
        const short* Bp = Bs + (size_t)p * 4096;
#pragma unroll
        for (int h = 0; h < 2; ++h) {
            short8 av[4], bv[2];
#pragma unroll
            for (int mt = 0; mt < 4; ++mt)
                av[mt] = *(const short8*)&Ap[(size_t)(h * 512 + (lq << 7) + wm * 64 + mt * 16 + lr) * 8];
#pragma unroll
            for (int nt = 0; nt < 2; ++nt)
                bv[nt] = *(const short8*)&Bp[(size_t)(h * 256 + (lq << 6) + wn * 32 + nt * 16 + lr) * 8];
#pragma unroll
            for (int mt = 0; mt < 4; ++mt)
#pragma unroll
                for (int nt = 0; nt < 2; ++nt)
                    acc[mt][nt] = __builtin_amdgcn_mfma_f32_16x16x32_bf16(av[mt], bv[nt], acc[mt][nt], 0, 0, 0);
        }
        __syncthreads();
        p ^= 1;
    }

    int isb = *dflag;
#pragma unroll
    for (int mt = 0; mt < 4; ++mt) {
#pragma unroll
        for (int r = 0; r < 4; ++r) {
            int row = bm + wm * 64 + mt * 16 + lq * 4 + r;
            float s = 1.f, bb = 0.f;
            if (bnS) { s = ldin(bnS, row, isb); bb = ldin(bnB, row, isb); }
#pragma unroll
            for (int nt = 0; nt < 2; ++nt) {
                int col = bn0 + wn * 32 + nt * 16 + lr;
                float v = acc[mt][nt][r];
                if (bnS) v = v * s + bb;
                if (act) v = lrelu(v);
                Cm[(size_t)row * BN_ALL + col] = v;
            }
        }
    }
}

__global__ __launch_bounds__(256) void gemm_pk(const short* __restrict__ packA,
                                               const bf16* __restrict__ X, float* __restrict__ Cm, int K,
                                               const void* __restrict__ bnS, const void* __restrict__ bnB,
                                               int act, const int* __restrict__ dflag) {
    __shared__ __align__(16) short SMEM[24576];
    gemm_core(blockIdx.x, blockIdx.y, threadIdx.x, SMEM, packA, X, Cm, K, bnS, bnB, act, dflag);
}

// ---- fused gram || gemm (tier P2): blocks [0,16)=gram, rest=gemm ------------
// Both read only X_i (+pack); outputs GRAM vs PS disjoint. Union 48KB LDS.
// gram's C == gemm's K for every edge block.
__global__ __launch_bounds__(256) void gram_gemm_k(const bf16* __restrict__ X, float* __restrict__ G,
                                                   const short* __restrict__ packA,
                                                   float* __restrict__ Cm, int K,
                                                   const int* __restrict__ dflag) {
    __shared__ __align__(16) short SMEM[24576];
    if (blockIdx.x < 16) {
        gram_core(blockIdx.x, threadIdx.x, SMEM, X, K, G);
    } else {
        int g = blockIdx.x - 16;
        gemm_core(g >> 5, g & 31, threadIdx.x, SMEM, packA, X, Cm, K, nullptr, nullptr, 0, dflag);
    }
}

// ---- legacy kNN (fallback tiers) --------------------------------------------
template <typename S>
__global__ __launch_bounds__(128) void knn_topk(const S* __restrict__ X, int C, int* __restrict__ idx) {
    int b = blockIdx.x >> 7;
    int n = blockIdx.x & 127;
    int m = threadIdx.x;
    const S* base = X + b * 128;
    float s0 = 0, s1 = 0, q0 = 0, q1 = 0;
    for (int c = 0; c < C; c += 2) {
        const S* p = base + (size_t)c * BN_ALL;
        float xm0 = ld1(p + m),          xn0 = ld1(p + n);
        float xm1 = ld1(p + BN_ALL + m), xn1 = ld1(p + BN_ALL + n);
        s0 += xm0 * xn0; q0 += xm0 * xm0;
        s1 += xm1 * xn1; q1 += xm1 * xm1;
    }
    float inner = s0 + s1;
    float xxm   = q0 + q1;
    __shared__ float xx[128];
    __shared__ float dist[128];
    __shared__ float rv[128];
    __shared__ int   ri[128];
    xx[m] = xxm;
    __syncthreads();
    dist[m] = 2.0f * inner - xx[n] - xxm;
    for (int k = 0; k < 20; k++) {
        __syncthreads();
        rv[m] = dist[m]; ri[m] = m;
        __syncthreads();
        for (int off = 64; off > 0; off >>= 1) {
            if (m < off) {
                float a = rv[m], bv = rv[m + off];
                int ia = ri[m], ib = ri[m + off];
                if (bv > a || (bv == a && ib < ia)) { rv[m] = bv; ri[m] = ib; }
            }
            __syncthreads();
        }
        if (m == 0) { idx[blockIdx.x * 20 + k] = ri[0]; dist[ri[0]] = -3.0e38f; }
    }
}

// ---- R5 fallback GEMM (on-the-fly staging, 128x128, linear layouts) ---------
template <typename S>
__global__ __launch_bounds__(256) void gemm_mfma(const void* __restrict__ w, int ldw,
                                                 const void* __restrict__ res, int Cin, int O,
                                                 const S* __restrict__ X, S* __restrict__ Cm, int K,
                                                 const void* __restrict__ bnS, const void* __restrict__ bnB,
                                                 int act, const int* __restrict__ dflag) {
    int isb = *dflag;
    __shared__ short Asm[4096];
    __shared__ short Bsm[4096];
    int tid = threadIdx.x;
    int bm  = blockIdx.x << 7;
    int bn0 = blockIdx.y << 7;
    int lane = tid & 63, wv = tid >> 6;
    int wm = wv & 1, wn = wv >> 1;
    int lq = lane >> 4, lr = lane & 15;

    float4v acc[4][4];
#pragma unroll
    for (int i = 0; i < 4; i++)
#pragma unroll
        for (int j = 0; j < 4; j++) acc[i][j] = (float4v){0.f, 0.f, 0.f, 0.f};

    for (int k0 = 0; k0 < K; k0 += 32) {
#pragma unroll
        for (int it = 0; it < 2; ++it) {
            int i = tid + it * 256;
            int m = i >> 2, q = i & 3;
            int grow = bm + m;
            const void* asrc; size_t abase; int dif = 0;
            if (grow < O)          { asrc = w;   abase = (size_t)grow * ldw; }
            else if (grow < 2 * O) { asrc = w;   abase = (size_t)(grow - O) * ldw; dif = 1; }
            else                   { asrc = res; abase = (size_t)(grow - 2 * O) * Cin; }
            size_t kk = (size_t)k0 + q * 8;
            short8 pk;
#pragma unroll
            for (int j = 0; j < 8; ++j) {
                float v = ldin(asrc, abase + kk + j, isb);
                if (dif) v = ldin(asrc, abase + Cin + kk + j, isb) - v;
                pk[j] = f2bs(v);
            }
            *(short8*)&Asm[(size_t)(q * 128 + m) * 8] = pk;
        }
#pragma unroll
        for (int it = 0; it < 2; ++it) {
            int i = tid + it * 256;
            int q = i >> 7, c = i & 127;
            const S* xp = X + (size_t)(k0 + q * 8) * BN_ALL + bn0 + c;
            short8 pk;
#pragma unroll
            for (int j = 0; j < 8; ++j) pk[j] = f2bs(ld1(xp + (size_t)j * BN_ALL));
            *(short8*)&Bsm[(size_t)i * 8] = pk;
        }
        __syncthreads();
        short8 av[4], bv[4];
#pragma unroll
        for (int mt = 0; mt < 4; ++mt)
            av[mt] = *(const short8*)&Asm[(size_t)((lq << 7) + wm * 64 + mt * 16 + lr) * 8];
#pragma unroll
        for (int nt = 0; nt < 4; ++nt)
            bv[nt] = *(const short8*)&Bsm[(size_t)((lq << 7) + wn * 64 + nt * 16 + lr) * 8];
#pragma unroll
        for (int mt = 0; mt < 4; ++mt)
#pragma unroll
            for (int nt = 0; nt < 4; ++nt)
                acc[mt][nt] = __builtin_amdgcn_mfma_f32_16x16x32_bf16(av[mt], bv[nt], acc[mt][nt], 0, 0, 0);
        __syncthreads();
    }
#pragma unroll
    for (int mt = 0; mt < 4; ++mt) {
#pragma unroll
        for (int r = 0; r < 4; ++r) {
            int row = bm + wm * 64 + mt * 16 + lq * 4 + r;
            float s = 1.f, bb = 0.f;
            if (bnS) { s = ldin(bnS, row, isb); bb = ldin(bnB, row, isb); }
#pragma unroll
            for (int nt = 0; nt < 4; ++nt) {
                int col = bn0 + wn * 64 + nt * 16 + lr;
                float v = acc[mt][nt][r];
                if (bnS) v = v * s + bb;
                if (act) v = lrelu(v);
                st1(Cm + (size_t)row * BN_ALL + col, v);
            }
        }
    }
}

// ---- gather + k-pool + bn + lrelu; T written IN-PLACE over P row o ----------
// one WAVE per (o,b) row; 2 n's per lane; barrier-free shfl_xor butterfly.
template <typename S>
__global__ __launch_bounds__(256) void gather_pool(S* __restrict__ PS, const int* __restrict__ idx,
                                                   const void* __restrict__ bns, const void* __restrict__ bnb,
                                                   float* __restrict__ Mb, int O,
                                                   const int* __restrict__ dflag) {
    int isb = *dflag;
    int wv = threadIdx.x >> 6, lane = threadIdx.x & 63;
    int gw = blockIdx.x * 4 + wv;          // gw = o*16 + b
    int o = gw >> 4, b = gw & 15;
    S* Prow = PS + (size_t)o * BN_ALL + b * 128;
    const S* Srow = PS + (size_t)(O + o) * BN_ALL + b * 128;
    int n0 = lane, n1 = lane + 64;
    const int* id0 = idx + (b * 128 + n0) * 20;
    const int* id1 = idx + (b * 128 + n1) * 20;
    float mx0 = -3.0e38f, mn0 = 3.0e38f, sm0 = 0.f;
    float mx1 = -3.0e38f, mn1 = 3.0e38f, sm1 = 0.f;
#pragma unroll
    for (int k = 0; k < 20; k++) {
        float p = ld1(Prow + id0[k]);
        mx0 = fmaxf(mx0, p); mn0 = fminf(mn0, p); sm0 += p;
    }
#pragma unroll
    for (int k = 0; k < 20; k++) {
        float p = ld1(Prow + id1[k]);
        mx1 = fmaxf(mx1, p); mn1 = fminf(mn1, p); sm1 += p;
    }
    float Sv0 = ld1(Srow + n0), Sv1 = ld1(Srow + n1);
    float s = ldin(bns, o, isb), bb = ldin(bnb, o, isb);
    float ext0 = (s >= 0.f) ? mx0 : mn0;
    float ext1 = (s >= 0.f) ? mx1 : mn1;
    float t0 = lrelu(s * (ext0 + Sv0) + bb);
    float t1 = lrelu(s * (ext1 + Sv1) + bb);
    st1(Prow + n0, t0);
    st1(Prow + n1, t1);
    float r1 = sm0 + sm1;    // == halving-tree step off=64
    float r2 = Sv0 + Sv1;
#pragma unroll
    for (int off = 32; off > 0; off >>= 1) {
        r1 += __shfl_xor(r1, off, 64);
        r2 += __shfl_xor(r2, off, 64);
    }
    if (lane == 0) Mb[b * O + o] = s * (r1 * (1.f / 2560.f) + r2 * (1.f / 128.f)) + bb;
}

// ---- SE stage 1: z[b,t] = relu(w1[t,:] . M[b,:]) — one wave per (b,t) -------
__global__ __launch_bounds__(256) void se1_k(const float* __restrict__ Mb, const void* __restrict__ w1,
                                             float* __restrict__ Z, int O, int r,
                                             const int* __restrict__ dflag) {
    int isb = *dflag;
    int gw = (blockIdx.x * 256 + threadIdx.x) >> 6;   // b*r + t
    int lane = threadIdx.x & 63;
    int b = gw / r, t = gw - b * r;
    const float* mv = Mb + (size_t)b * O;
    float acc = 0.f;
    for (int c = lane; c < O; c += 64) acc += ldin(w1, (size_t)t * O + c, isb) * mv[c];
#pragma unroll
    for (int off = 32; off > 0; off >>= 1) acc += __shfl_xor(acc, off, 64);
    if (lane == 0) Z[b * r + t] = fmaxf(acc, 0.f);
}

// ---- SE stage 2: Y[b,o] = sigmoid(w2[o,:] . z[b,:]) — one wave per (b,o) ----
__global__ __launch_bounds__(256) void se2_k(const float* __restrict__ Z, const void* __restrict__ w2,
                                             float* __restrict__ Y, int O, int r,
                                             const int* __restrict__ dflag) {
    int isb = *dflag;
    int gw = (blockIdx.x * 256 + threadIdx.x) >> 6;   // b*O + o
    int lane = threadIdx.x & 63;
    int b = gw / O, o = gw - b * O;
    float acc = 0.f;
    if (lane < r) acc = ldin(w2, (size_t)o * r + lane, isb) * Z[b * r + lane];
#pragma unroll
    for (int off = 32; off > 0; off >>= 1) acc += __shfl_xor(acc, off, 64);
    if (lane == 0) Y[b * O + o] = 1.f / (1.f + expf(-acc));
}

// ---- legacy SE (fallback tiers) ---------------------------------------------
__global__ __launch_bounds__(256) void se_k(const float* __restrict__ Mb, const void* __restrict__ w1,
                                            const void* __restrict__ w2, float* __restrict__ Y, int O, int r,
                                            const int* __restrict__ dflag) {
    int isb = *dflag;
    int b = blockIdx.x, t = threadIdx.x;
    __shared__ float mloc[1024];
    __shared__ float z[64];
    for (int i = t; i < O; i += 256) mloc[i] = Mb[b * O + i];
    __syncthreads();
    if (t < r) {
        float acc = 0.f;
        for (int c = 0; c < O; c++) acc += ldin(w1, (size_t)t * O + c, isb) * mloc[c];
        z[t] = fmaxf(acc, 0.f);
    }
    __syncthreads();
    for (int o = t; o < O; o += 256) {
        float acc = 0.f;
        for (int j = 0; j < r; j++) acc += ldin(w2, (size_t)o * r + j, isb) * z[j];
        Y[b * O + o] = 1.f / (1.f + expf(-acc));
    }
}

// ---- fused se2 + finalize (tier P2): Y recomputed in-block from Z -----------
// Block covers one og x 256 bn (= 2 batches) -> needs 16 Y values. The 4
// waves compute 4 each using se2_k's EXACT op sequence (ternary load,
// xor-reduce 32..1, lane0 sigmoid) -> bit-identical Y; then finalize math
// identical to finalize_kp.
__global__ __launch_bounds__(256) void finalize2_kp(const float* __restrict__ PS,
                                                    const float* __restrict__ Z,
                                                    const void* __restrict__ w2,
                                                    int useR, bf16* __restrict__ Xdst, int O, int r,
                                                    const int* __restrict__ dflag) {
    int isb = *dflag;
    int og = blockIdx.x >> 3;
    int b0 = (blockIdx.x & 7) * 2;
    __shared__ float Ysm[16];
    int wv = threadIdx.x >> 6, lane = threadIdx.x & 63;
#pragma unroll
    for (int s = 0; s < 4; ++s) {
        int pp = wv * 4 + s;              // 0..15
        int b = b0 + (pp >> 3);
        int o = og * 8 + (pp & 7);
        float acc = 0.f;
        if (lane < r) acc = ldin(w2, (size_t)o * r + lane, isb) * Z[b * r + lane];
#pragma unroll
        for (int off = 32; off > 0; off >>= 1) acc += __shfl_xor(acc, off, 64);
        if (lane == 0) Ysm[pp] = 1.f / (1.f + expf(-acc));
    }
    __syncthreads();
    int item = blockIdx.x * 256 + threadIdx.x;
    int bn = item & 2047;
    int b = bn >> 7;
    short8 pk;
#pragma unroll
    for (int j = 0; j < 8; ++j) {
        int rr = og * 8 + j;
        float v = Ysm[(b - b0) * 8 + j] * PS[(size_t)rr * BN_ALL + bn];
        if (useR) v += PS[(size_t)(2 * O + rr) * BN_ALL + bn];
        pk[j] = f2bs(v);
    }
    *(short8*)((short*)Xdst + ((size_t)og * BN_ALL + bn) * 8) = pk;
}

// ---- finalize (tier P): x_next = y*T (+res) -> k-packed bf16 slice ----------
__global__ __launch_bounds__(256) void finalize_kp(const float* __restrict__ PS, const float* __restrict__ Y,
                                                   int useR, bf16* __restrict__ Xdst, int O) {
    int item = blockIdx.x * 256 + threadIdx.x;   // og*2048 + bn  (og = o/8)
    int og = item >> 11, bn = item & 2047;
    int b = bn >> 7;
    short8 pk;
#pragma unroll
    for (int j = 0; j < 8; ++j) {
        int r = og * 8 + j;
        float v = Y[b * O + r] * PS[(size_t)r * BN_ALL + bn];
        if (useR) v += PS[(size_t)(2 * O + r) * BN_ALL + bn];
        pk[j] = f2bs(v);
    }
    *(short8*)((short*)Xdst + ((size_t)og * BN_ALL + bn) * 8) = pk;
}

// ---- legacy finalize (fallback tiers, linear layout) ------------------------
template <typename SP, typename SD>
__global__ __launch_bounds__(256) void finalize(const SP* __restrict__ PS, const float* __restrict__ Y,
                                                int useR, SD* __restrict__ Xdst, int O) {
    int tid = blockIdx.x * 256 + threadIdx.x;   // tid = o*2048 + bn
    int o = tid >> 11, bn = tid & 2047;
    int b = bn >> 7;
    float v = Y[b * O + o] * ld1(PS + tid);
    if (useR) v += ld1(PS + (size_t)(2 * O + o) * BN_ALL + bn);
    st1(Xdst + tid, v);
}

// ---- legacy convert (fallback tiers) ----------------------------------------
template <typename S>
__global__ __launch_bounds__(256) void convert_x(const void* __restrict__ x, S* __restrict__ X0,
                                                 const int* __restrict__ dflag) {
    int isb = *dflag;
    int tid = blockIdx.x * 256 + threadIdx.x;
    int c = tid >> 11, bn = tid & 2047;
    int b = bn >> 7, n = bn & 127;
    st1(X0 + tid, ldin(x, (size_t)(b * 512 + c) * 128 + n, isb));
}

// ---- conv5 pool: one WAVE per (m,b); barrier-free butterfly -----------------
template <typename S>
__global__ __launch_bounds__(256) void pool5(const S* __restrict__ H, float* __restrict__ f) {
    int wv = threadIdx.x >> 6, lane = threadIdx.x & 63;
    int gw = blockIdx.x * 4 + wv;          // gw = m*16 + b
    int m = gw >> 4, b = gw & 15;
    const S* Hp = H + (size_t)m * BN_ALL + b * 128;
    float v0 = ld1(Hp + lane), v1 = ld1(Hp + 64 + lane);
    float mx = fmaxf(v0, v1);
    float sm = v0 + v1;
#pragma unroll
    for (int off = 32; off > 0; off >>= 1) {
        mx = fmaxf(mx, __shfl_xor(mx, off, 64));
        sm += __shfl_xor(sm, off, 64);
    }
    if (lane == 0) {
        f[b * 4096 + m] = mx;
        f[b * 4096 + 2048 + m] = sm * (1.f / 128.f);
    }
}

// ---- head: one wave per (b,o) dot product + optional bias/bn/lrelu ----------
__global__ __launch_bounds__(256) void head_k(const float* __restrict__ in, const void* __restrict__ W,
                                              const void* __restrict__ bias, const void* __restrict__ bns,
                                              const void* __restrict__ bnb, float* __restrict__ outf,
                                              void* __restrict__ outb, int Kd, int Od, int act,
                                              const int* __restrict__ dflag) {
    int isb = *dflag;
    int gw = (blockIdx.x * 256 + threadIdx.x) >> 6;
    int lane = threadIdx.x & 63;
    if (gw >= 16 * Od) return;
    int b = gw / Od, o = gw - b * Od;
    const float* iv = in + b * Kd;
    float acc = 0.f;
    for (int k = lane; k < Kd; k += 64) acc += iv[k] * ldin(W, (size_t)o * Kd + k, isb);
    for (int off = 32; off > 0; off >>= 1) acc += __shfl_xor(acc, off, 64);
    if (lane == 0) {
        float v = acc;
        if (bias) v += ldin(bias, o, isb);
        if (bns) v = v * ldin(bns, o, isb) + ldin(bnb, o, isb);
        if (act) v = lrelu(v);
        if (outb) {
            if (isb) ((bf16*)outb)[gw] = __float2bfloat16(v);
            else     ((float*)outb)[gw] = v;
        } else outf[gw] = v;
    }
}

// ---- ws-too-small signal ----------------------------------------------------
__global__ __launch_bounds__(256) void zero_out(bf16* o, int n) {
    int i = blockIdx.x * 256 + threadIdx.x;
    if (i < n) o[i] = __float2bfloat16(0.f);
}

// ---------------------------------------------------------------------------
#define UNPACK_INPUTS()                                                     \
    const void* x_in   = d_in[0];                                           \
    const void* conv1w = d_in[1];  const void* conv2w = d_in[2];            \
    const void* conv3w = d_in[3];  const void* conv4w = d_in[4];            \
    const void* conv5w = d_in[5];                                           \
    const void* bn1s = d_in[6],  * bn1b = d_in[7];                          \
    const void* bn2s = d_in[8],  * bn2b = d_in[9];                          \
    const void* bn3s = d_in[10], * bn3b = d_in[11];                         \
    const void* bn4s = d_in[12], * bn4b = d_in[13];                         \
    const void* bn5s = d_in[14], * bn5b = d_in[15];                         \
    const void* se1w1 = d_in[16], * se1w2 = d_in[17];                       \
    const void* se2w1 = d_in[18], * se2w2 = d_in[19];                       \
    const void* se3w1 = d_in[20], * se3w2 = d_in[21];                       \
    const void* se4w1 = d_in[22], * se4w2 = d_in[23];                       \
    const void* res1w = d_in[24]; const void* res2w = d_in[25];             \
    const void* res3w = d_in[26]; const void* lin1w = d_in[27];             \
    const void* bn6s = d_in[28], * bn6b = d_in[29];                         \
    const void* lin2w = d_in[30], * lin2b = d_in[31];                       \
    const void* bn7s = d_in[32], * bn7b = d_in[33];                         \
    const void* lin3w = d_in[34], * lin3b = d_in[35];

// ---- Tier P2: packs upfront, gram||gemm, topk, gather, se1, se2+finalize ----
static void run_net_packed2(void* const* d_in, void* d_out, void* d_ws, hipStream_t stream) {
    UNPACK_INPUTS();
    float* WS = (float*)d_ws;
    float* PS = WS;                                   // 3072 x 2048 f32
    bf16*  XC = (bf16*)(WS + 6291456);                // 3072 x 2048 bf16 k-packed
    short* P1 = (short*)(WS + 12582912);              // 524288 shorts
    short* P2 = P1 + 524288;                          // 786432
    short* P3 = P2 + 786432;                          // 1572864
    short* P4 = P3 + 1572864;                         // 3145728
    short* P5 = P4 + 3145728;                         // 6291456  (ends @ float 18743296)
    float* MB = WS + 18743296;
    float* YB = MB + 16384;
    float* FB = YB + 16384;
    float* F1 = FB + 65536;
    float* F2 = F1 + 8192;
    int* IDX  = (int*)(F2 + 4096);
    int* DFLAG = IDX + 40960;
    float* ZB = (float*)(DFLAG + 16);                 // 1024 floats
    float* GRAM = WS + 18900000;                      // 262144 floats, dedicated
    bf16*  X0 = (bf16*)(PS + (size_t)2048 * BN_ALL);  // PS rows 2048.. (block 1 only)
    bf16* X1 = XC;
    bf16* X2 = XC + (size_t)512 * BN_ALL;
    bf16* X3 = XC + (size_t)1024 * BN_ALL;
    bf16* X4 = XC + (size_t)2048 * BN_ALL;

    detect_dtype<<<1, 256, 0, stream>>>(x_in, DFLAG);
    convert_pack_all<<<6528, 256, 0, stream>>>(x_in, X0,
        conv1w, conv2w, conv3w, conv4w, conv5w, res1w, res2w, res3w,
        P1, P2, P3, P4, P5, DFLAG);

    // block 1: O=512, Mtot=1024, K=512, r=32
    gram_gemm_k<<<16 + 8 * 32, 256, 0, stream>>>(X0, GRAM, P1, PS, 512, DFLAG);
    topk_k<<<512, 256, 0, stream>>>(GRAM, IDX);
    gather_pool<float><<<2048, 256, 0, stream>>>(PS, IDX, bn1s, bn1b, MB, 512, DFLAG);
    se1_k<<<128, 256, 0, stream>>>(MB, se1w1, ZB, 512, 32, DFLAG);
    finalize2_kp<<<512, 256, 0, stream>>>(PS, ZB, se1w2, 0, X1, 512, 32, DFLAG);

    // block 2: Mtot=1536, K=512, res1, r=32
    gram_gemm_k<<<16 + 12 * 32, 256, 0, stream>>>(X1, GRAM, P2, PS, 512, DFLAG);
    topk_k<<<512, 256, 0, stream>>>(GRAM, IDX);
    gather_pool<float><<<2048, 256, 0, stream>>>(PS, IDX, bn2s, bn2b, MB, 512, DFLAG);
    se1_k<<<128, 256, 0, stream>>>(MB, se2w1, ZB, 512, 32, DFLAG);
    finalize2_kp<<<512, 256, 0, stream>>>(PS, ZB, se2w2, 1, X2, 512, 32, DFLAG);

    // block 3: O=1024, Mtot=3072, K=512, res2, r=64
    gram_gemm_k<<<16 + 24 * 32, 256, 0, stream>>>(X2, GRAM, P3, PS, 512, DFLAG);
    topk_k<<<512, 256, 0, stream>>>(GRAM, IDX);
    gather_pool<float><<<4096, 256, 0, stream>>>(PS, IDX, bn3s, bn3b, MB, 1024, DFLAG);
    se1_k<<<256, 256, 0, stream>>>(MB, se3w1, ZB, 1024, 64, DFLAG);
    finalize2_kp<<<1024, 256, 0, stream>>>(PS, ZB, se3w2, 1, X3, 1024, 64, DFLAG);

    // block 4: O=1024, Mtot=3072, K=1024, res3, r=64
    gram_gemm_k<<<16 + 24 * 32, 256, 0, stream>>>(X3, GRAM, P4, PS, 1024, DFLAG);
    topk_k<<<512, 256, 0, stream>>>(GRAM, IDX);
    gather_pool<float><<<4096, 256, 0, stream>>>(PS, IDX, bn4s, bn4b, MB, 1024, DFLAG);
    se1_k<<<256, 256, 0, stream>>>(MB, se4w1, ZB, 1024, 64, DFLAG);
    finalize2_kp<<<1024, 256, 0, stream>>>(PS, ZB, se4w2, 1, X4, 1024, 64, DFLAG);

    // conv5: Mtot=2048, K=3072, bn5+lrelu
    gemm_pk<<<dim3(16, 32), 256, 0, stream>>>(P5, XC, PS, 3072, bn5s, bn5b, 1, DFLAG);
    pool5<float><<<8192, 256, 0, stream>>>(PS, FB);

    head_k<<<2048, 256, 0, stream>>>(FB, lin1w, nullptr, bn6s, bn6b, F1, nullptr, 4096, 512, 1, DFLAG);
    head_k<<<1024, 256, 0, stream>>>(F1, lin2w, lin2b, bn7s, bn7b, F2, nullptr, 512, 256, 1, DFLAG);
    head_k<<<160, 256, 0, stream>>>(F2, lin3w, lin3b, nullptr, nullptr, nullptr, d_out, 256, 40, 0, DFLAG);
}

// ---- Tier P: R15 path (fallback when ws < P2 but >= 63MB) -------------------
static void run_net_packed(void* const* d_in, void* d_out, void* d_ws, hipStream_t stream) {
    UNPACK_INPUTS();
    float* WS = (float*)d_ws;
    float* PS   = WS;
    bf16*  XC   = (bf16*)(WS + 6291456);
    short* PACK = (short*)(WS + 12582912);
    float* MB = WS + 15728640;
    float* YB = MB + 16384;
    float* FB = YB + 16384;
    float* F1 = FB + 65536;
    float* F2 = F1 + 8192;
    int* IDX  = (int*)(F2 + 4096);
    int* DFLAG = IDX + 40960;
    float* ZB = (float*)(DFLAG + 16);
    bf16*  X0 = (bf16*)(PS + (size_t)2048 * BN_ALL);
    float* GRAM = PS;
    bf16* X1 = XC;
    bf16* X2 = XC + (size_t)512 * BN_ALL;
    bf16* X3 = XC + (size_t)1024 * BN_ALL;
    bf16* X4 = XC + (size_t)2048 * BN_ALL;

    detect_dtype<<<1, 256, 0, stream>>>(x_in, DFLAG);
    convert_kp<<<512, 256, 0, stream>>>(x_in, X0, DFLAG);

    gram_k<<<16, 256, 0, stream>>>(X0, 512, GRAM);
    topk_k<<<512, 256, 0, stream>>>(GRAM, IDX);
    pack_w<<<256, 256, 0, stream>>>(conv1w, 1024, nullptr, 512, 512, 1024, 512, PACK, DFLAG);
    gemm_pk<<<dim3(8, 32), 256, 0, stream>>>(PACK, X0, PS, 512, nullptr, nullptr, 0, DFLAG);
    gather_pool<float><<<2048, 256, 0, stream>>>(PS, IDX, bn1s, bn1b, MB, 512, DFLAG);
    se1_k<<<128, 256, 0, stream>>>(MB, se1w1, ZB, 512, 32, DFLAG);
    se2_k<<<2048, 256, 0, stream>>>(ZB, se1w2, YB, 512, 32, DFLAG);
    finalize_kp<<<512, 256, 0, stream>>>(PS, YB, 0, X1, 512);

    gram_k<<<16, 256, 0, stream>>>(X1, 512, GRAM);
    topk_k<<<512, 256, 0, stream>>>(GRAM, IDX);
    pack_w<<<384, 256, 0, stream>>>(conv2w, 1024, res1w, 512, 512, 1536, 512, PACK, DFLAG);
    gemm_pk<<<dim3(12, 32), 256, 0, stream>>>(PACK, X1, PS, 512, nullptr, nullptr, 0, DFLAG);
    gather_pool<float><<<2048, 256, 0, stream>>>(PS, IDX, bn2s, bn2b, MB, 512, DFLAG);
    se1_k<<<128, 256, 0, stream>>>(MB, se2w1, ZB, 512, 32, DFLAG);
    se2_k<<<2048, 256, 0, stream>>>(ZB, se2w2, YB, 512, 32, DFLAG);
    finalize_kp<<<512, 256, 0, stream>>>(PS, YB, 1, X2, 512);

    gram_k<<<16, 256, 0, stream>>>(X2, 512, GRAM);
    topk_k<<<512, 256, 0, stream>>>(GRAM, IDX);
    pack_w<<<768, 256, 0, stream>>>(conv3w, 1024, res2w, 512, 1024, 3072, 512, PACK, DFLAG);
    gemm_pk<<<dim3(24, 32), 256, 0, stream>>>(PACK, X2, PS, 512, nullptr, nullptr, 0, DFLAG);
    gather_pool<float><<<4096, 256, 0, stream>>>(PS, IDX, bn3s, bn3b, MB, 1024, DFLAG);
    se1_k<<<256, 256, 0, stream>>>(MB, se3w1, ZB, 1024, 64, DFLAG);
    se2_k<<<4096, 256, 0, stream>>>(ZB, se3w2, YB, 1024, 64, DFLAG);
    finalize_kp<<<1024, 256, 0, stream>>>(PS, YB, 1, X3, 1024);

    gram_k<<<16, 256, 0, stream>>>(X3, 1024, GRAM);
    topk_k<<<512, 256, 0, stream>>>(GRAM, IDX);
    pack_w<<<1536, 256, 0, stream>>>(conv4w, 2048, res3w, 1024, 1024, 3072, 1024, PACK, DFLAG);
    gemm_pk<<<dim3(24, 32), 256, 0, stream>>>(PACK, X3, PS, 1024, nullptr, nullptr, 0, DFLAG);
    gather_pool<float><<<4096, 256, 0, stream>>>(PS, IDX, bn4s, bn4b, MB, 1024, DFLAG);
    se1_k<<<256, 256, 0, stream>>>(MB, se4w1, ZB, 1024, 64, DFLAG);
    se2_k<<<4096, 256, 0, stream>>>(ZB, se4w2, YB, 1024, 64, DFLAG);
    finalize_kp<<<1024, 256, 0, stream>>>(PS, YB, 1, X4, 1024);

    pack_w<<<3072, 256, 0, stream>>>(conv5w, 3072, nullptr, 3072, 2048, 2048, 3072, PACK, DFLAG);
    gemm_pk<<<dim3(16, 32), 256, 0, stream>>>(PACK, XC, PS, 3072, bn5s, bn5b, 1, DFLAG);
    pool5<float><<<8192, 256, 0, stream>>>(PS, FB);

    head_k<<<2048, 256, 0, stream>>>(FB, lin1w, nullptr, bn6s, bn6b, F1, nullptr, 4096, 512, 1, DFLAG);
    head_k<<<1024, 256, 0, stream>>>(F1, lin2w, lin2b, bn7s, bn7b, F2, nullptr, 512, 256, 1, DFLAG);
    head_k<<<160, 256, 0, stream>>>(F2, lin3w, lin3b, nullptr, nullptr, nullptr, d_out, 256, 40, 0, DFLAG);
}

// ---- Tier A/B fallback (R5 path, linear layouts) ----------------------------
template <typename S>
static void run_net(void* const* d_in, void* d_out, void* d_ws, hipStream_t stream) {
    UNPACK_INPUTS();
    const size_t RC = (size_t)3072 * BN_ALL;
    S* PS = (S*)d_ws;
    S* XC = PS + RC;
    S* X0 = PS + (size_t)2048 * BN_ALL;
    float* MB = (float*)(XC + RC);
    float* YB = MB + 16 * 1024;
    float* FB = YB + 16 * 1024;
    float* F1 = FB + 16 * 4096;
    float* F2 = F1 + 16 * 512;
    int* IDX  = (int*)(F2 + 16 * 256);
    int* DFLAG = IDX + 16 * 128 * 20;

    S* X1 = XC;
    S* X2 = XC + (size_t)512 * BN_ALL;
    S* X3 = XC + (size_t)1024 * BN_ALL;
    S* X4 = XC + (size_t)2048 * BN_ALL;

    detect_dtype<<<1, 256, 0, stream>>>(x_in, DFLAG);
    convert_x<S><<<4096, 256, 0, stream>>>(x_in, X0, DFLAG);

    knn_topk<S><<<2048, 128, 0, stream>>>(X0, 512, IDX);
    gemm_mfma<S><<<dim3(8, 16), 256, 0, stream>>>(conv1w, 1024, nullptr, 512, 512, X0, PS, 512, nullptr, nullptr, 0, DFLAG);
    gather_pool<S><<<2048, 256, 0, stream>>>(PS, IDX, bn1s, bn1b, MB, 512, DFLAG);
    se_k<<<16, 256, 0, stream>>>(MB, se1w1, se1w2, YB, 512, 32, DFLAG);
    finalize<S, S><<<4096, 256, 0, stream>>>(PS, YB, 0, X1, 512);

    knn_topk<S><<<2048, 128, 0, stream>>>(X1, 512, IDX);
    gemm_mfma<S><<<dim3(12, 16), 256, 0, stream>>>(conv2w, 1024, res1w, 512, 512, X1, PS, 512, nullptr, nullptr, 0, DFLAG);
    gather_pool<S><<<2048, 256, 0, stream>>>(PS, IDX, bn2s, bn2b, MB, 512, DFLAG);
    se_k<<<16, 256, 0, stream>>>(MB, se2w1, se2w2, YB, 512, 32, DFLAG);
    finalize<S, S><<<4096, 256, 0, stream>>>(PS, YB, 1, X2, 512);

    knn_topk<S><<<2048, 128, 0, stream>>>(X2, 512, IDX);
    gemm_mfma<S><<<dim3(24, 16), 256, 0, stream>>>(conv3w, 1024, res2w, 512, 1024, X2, PS, 512, nullptr, nullptr, 0, DFLAG);
    gather_pool<S><<<4096, 256, 0, stream>>>(PS, IDX, bn3s, bn3b, MB, 1024, DFLAG);
    se_k<<<16, 256, 0, stream>>>(MB, se3w1, se3w2, YB, 1024, 64, DFLAG);
    finalize<S, S><<<8192, 256, 0, stream>>>(PS, YB, 1, X3, 1024);

    knn_topk<S><<<2048, 128, 0, stream>>>(X3, 1024, IDX);
    gemm_mfma<S><<<dim3(24, 16), 256, 0, stream>>>(conv4w, 2048, res3w, 1024, 1024, X3, PS, 1024, nullptr, nullptr, 0, DFLAG);
    gather_pool<S><<<4096, 256, 0, stream>>>(PS, IDX, bn4s, bn4b, MB, 1024, DFLAG);
    se_k<<<16, 256, 0, stream>>>(MB, se4w1, se4w2, YB, 1024, 64, DFLAG);
    finalize<S, S><<<8192, 256, 0, stream>>>(PS, YB, 1, X4, 1024);

    gemm_mfma<S><<<dim3(16, 16), 256, 0, stream>>>(conv5w, 3072, nullptr, 3072, 2048, XC, PS, 3072, bn5s, bn5b, 1, DFLAG);
    pool5<S><<<8192, 256, 0, stream>>>(PS, FB);

    head_k<<<2048, 256, 0, stream>>>(FB, lin1w, nullptr, bn6s, bn6b, F1, nullptr, 4096, 512, 1, DFLAG);
    head_k<<<1024, 256, 0, stream>>>(F1, lin2w, lin2b, bn7s, bn7b, F2, nullptr, 512, 256, 1, DFLAG);
    head_k<<<160, 256, 0, stream>>>(F2, lin3w, lin3b, nullptr, nullptr, nullptr, d_out, 256, 40, 0, DFLAG);
}

extern "C" void kernel_launch(void* const* d_in, const int* in_sizes, int n_in,
                              void* d_out, int out_size, void* d_ws, size_t ws_size,
                              hipStream_t stream) {
    const size_t SMALL = (16 * 1024 + 16 * 1024 + 16 * 4096 + 16 * 512 + 16 * 256) * 4
                       + 16 * 128 * 20 * 4 + 8192;
    const size_t NEED_P2     = ((size_t)18900000 + 262144 + 4096) * 4;   // ~76.7MB
    const size_t NEED_PACKED = (size_t)15728640 * 4 + SMALL;
    const size_t NEED_F32    = 2 * ((size_t)3072 * BN_ALL * 4) + SMALL;
    const size_t NEED_BF16   = 2 * ((size_t)3072 * BN_ALL * 2) + SMALL;
    if (ws_size >= NEED_P2) {
        run_net_packed2(d_in, d_out, d_ws, stream);
    } else if (ws_size >= NEED_PACKED) {
        run_net_packed(d_in, d_out, d_ws, stream);
    } else if (ws_size >= NEED_F32) {
        run_net<float>(d_in, d_out, d_ws, stream);
    } else if (ws_size >= NEED_BF16) {
        run_net<bf16>(d_in, d_out, d_ws, stream);
    } else {
        zero_out<<<3, 256, 0, stream>>>((bf16*)d_out, out_size);
    }
}

// Round 11
// 527.540 us; speedup vs baseline: 2.3903x; 1.0323x over previous
//
#include <hip/hip_runtime.h>
#include <hip/hip_bf16.h>

// ---------------------------------------------------------------------------
// DGCNN-ish network, B=16, N=128, K=20.  (R21: coalesced pack reads + int4 idx)
// R20 landed (544.6us): top-5 is harness poison fills (uncontrollable) +
// conv5 gemm (plateau). Largest controllable: convert_pack_all (~30us,
// HBM 1.5TB/s). Cause: consecutive lanes read 16B from consecutive ROWS
// (stride ldw*4 = 4KB) -> 64 uncoalesced requests/wave. Fix: permute the
// thread->item mapping within each 512-item (tm,kc) group so q (k-dir)
// varies fastest: lanes 0-3 read contiguous 128B(f32)/64B(bf16) runs of one
// row; scatter moves to the latency-tolerant write side. Same item set,
// same values, same destinations -> bit-identical.
// Also: gather_pool loads its 20 neighbor indices as 5x int4 (80B aligned).
// Everything else unchanged from R20.
// ---------------------------------------------------------------------------

#define BN_ALL 2048   // B*N = 16*128
typedef __hip_bfloat16 bf16;
typedef __attribute__((ext_vector_type(8))) short short8;
typedef __attribute__((ext_vector_type(4))) float float4v;
typedef __attribute__((ext_vector_type(4))) int int4v;

__device__ __forceinline__ float b2f(bf16 v) { return __bfloat162float(v); }
__device__ __forceinline__ float bs2f(short s) { return __bfloat162float(*reinterpret_cast<bf16*>(&s)); }
__device__ __forceinline__ float lrelu(float v) { return v >= 0.f ? v : 0.2f * v; }
__device__ __forceinline__ short f2bs(float v) {
    bf16 h = __float2bfloat16(v);
    return *reinterpret_cast<short*>(&h);
}

// async 16-byte global->LDS DMA. LDS dest must be linear in lane.
__device__ __forceinline__ void gll16(const void* g, void* l) {
    __builtin_amdgcn_global_load_lds(
        (const __attribute__((address_space(1))) unsigned int*)g,
        (__attribute__((address_space(3))) unsigned int*)l,
        16, 0, 0);
}

// dual-dtype input load: isb=1 -> bf16, isb=0 -> f32
__device__ __forceinline__ float ldin(const void* p, size_t i, int isb) {
    return isb ? __bfloat162float(((const bf16*)p)[i]) : ((const float*)p)[i];
}

__device__ __forceinline__ float ld1(const float* p) { return *p; }
__device__ __forceinline__ float ld1(const bf16* p)  { return __bfloat162float(*p); }
__device__ __forceinline__ void st1(float* p, float v) { *p = v; }
__device__ __forceinline__ void st1(bf16* p, float v)  { *p = __float2bfloat16(v); }

// ---- dtype detection: sample 4096 dwords of x; f32 data -> sane exponents ---
__global__ __launch_bounds__(256) void detect_dtype(const void* __restrict__ x, int* __restrict__ flag) {
    const unsigned* u = (const unsigned*)x;
    int sane = 0;
    for (int i = threadIdx.x; i < 4096; i += 256) {
        unsigned e = (u[i] >> 23) & 0xFF;
        sane += (e >= 87 && e <= 167) ? 1 : 0;   // |v| in [2^-40, 2^40]
    }
    __shared__ int sh[256];
    sh[threadIdx.x] = sane;
    __syncthreads();
    for (int off = 128; off > 0; off >>= 1) {
        if (threadIdx.x < off) sh[threadIdx.x] += sh[threadIdx.x + off];
        __syncthreads();
    }
    if (threadIdx.x == 0) *flag = (sh[0] < 2048) ? 1 : 0;   // 1 = bf16, 0 = f32
}

// ---- convert core: input x (B,C,N) -> X0 k-packed bf16 ----------------------
__device__ __forceinline__ void convert_core(int bid, int tid, const void* __restrict__ x,
                                             bf16* __restrict__ X0, int isb) {
    int item = bid * 256 + tid;   // cg*2048 + bn  (cg = c/8)
    int cg = item >> 11, bn = item & 2047;
    int b = bn >> 7, n = bn & 127;
    short8 pk;
#pragma unroll
    for (int j = 0; j < 8; ++j)
        pk[j] = f2bs(ldin(x, ((size_t)(b * 512 + cg * 8 + j)) * 128 + n, isb));
    *(short8*)((short*)X0 + ((size_t)cg * BN_ALL + bn) * 8) = pk;
}

__global__ __launch_bounds__(256) void convert_kp(const void* __restrict__ x, bf16* __restrict__ X0,
                                                  const int* __restrict__ dflag) {
    convert_core(blockIdx.x, threadIdx.x, x, X0, *dflag);
}

// ---- pack core: f32/bf16 weights -> bf16 in LDS-tile image ------------------
// R19: isb branched once; short8 / float4 vector loads. Bit-identical.
__device__ __forceinline__ void pack_core(int item, int isb, const void* __restrict__ w, int ldw,
                                          const void* __restrict__ res, int Cin, int O,
                                          int Mtot, int K, short* __restrict__ out) {
    if (item >= Mtot * (K >> 3)) return;
    int m_local = item & 127;
    int rest = item >> 7;            // (tm*KC + kc)*4 + q
    int q = rest & 3; rest >>= 2;
    int KC = K >> 5;
    int kc = rest % KC, tm = rest / KC;
    int grow = tm * 128 + m_local;
    int k = kc * 32 + q * 8;
    const void* src; size_t base; int dif = 0;
    if (grow < O)          { src = w;   base = (size_t)grow * ldw + k; }
    else if (grow < 2 * O) { src = w;   base = (size_t)(grow - O) * ldw + k; dif = 1; }
    else                   { src = res; base = (size_t)(grow - 2 * O) * Cin + k; }
    short8 pk;
    if (isb) {
        const short* s = (const short*)src + base;
        short8 a = *(const short8*)s;
        if (dif) {
            short8 b = *(const short8*)(s + Cin);
#pragma unroll
            for (int j = 0; j < 8; ++j) pk[j] = f2bs(bs2f(b[j]) - bs2f(a[j]));
        } else {
            pk = a;   // bf16 -> float -> bf16 is exact: direct copy identical
        }
    } else {
        const float* s = (const float*)src + base;
        float4v a0 = *(const float4v*)s;
        float4v a1 = *(const float4v*)(s + 4);
        if (dif) {
            float4v c0 = *(const float4v*)(s + Cin);
            float4v c1 = *(const float4v*)(s + Cin + 4);
#pragma unroll
            for (int j = 0; j < 4; ++j) {
                pk[j]     = f2bs(c0[j] - a0[j]);
                pk[4 + j] = f2bs(c1[j] - a1[j]);
            }
        } else {
#pragma unroll
            for (int j = 0; j < 4; ++j) {
                pk[j]     = f2bs(a0[j]);
                pk[4 + j] = f2bs(a1[j]);
            }
        }
    }
    *(short8*)&out[(size_t)item * 8] = pk;
}

// R21: coalesced-read permutation. Within each 512-item (tm,kc) group the
// item layout is q*128 + m (q = k-octet, m = row). Map consecutive work
// indices widx to q-fastest: lanes 0-3 read 4 consecutive 8-elem chunks of
// ONE row (contiguous 128B f32 / 64B bf16). Same item set -> bit-identical.
__device__ __forceinline__ int pack_perm(int widx) {
    int g = widx >> 9, r = widx & 511;
    return g * 512 + (r & 3) * 128 + (r >> 2);
}

__global__ __launch_bounds__(256) void pack_w(const void* __restrict__ w, int ldw,
                                              const void* __restrict__ res, int Cin, int O,
                                              int Mtot, int K, short* __restrict__ out,
                                              const int* __restrict__ dflag) {
    pack_core(pack_perm(blockIdx.x * 256 + threadIdx.x), *dflag, w, ldw, res, Cin, O, Mtot, K, out);
}

// ---- fused convert + ALL weight packs (tier P2) -----------------------------
__global__ __launch_bounds__(256) void convert_pack_all(
        const void* __restrict__ x, bf16* __restrict__ X0,
        const void* __restrict__ w1c, const void* __restrict__ w2c, const void* __restrict__ w3c,
        const void* __restrict__ w4c, const void* __restrict__ w5c,
        const void* __restrict__ r1, const void* __restrict__ r2, const void* __restrict__ r3,
        short* __restrict__ p1, short* __restrict__ p2, short* __restrict__ p3,
        short* __restrict__ p4, short* __restrict__ p5,
        const int* __restrict__ dflag) {
    int isb = *dflag;
    int bid = blockIdx.x, tid = threadIdx.x;
    if (bid < 512) { convert_core(bid, tid, x, X0, isb); return; }
    int pb = bid - 512;
    if (pb < 256)       pack_core(pack_perm(pb * 256 + tid),          isb, w1c, 1024, nullptr, 512, 512, 1024, 512, p1);
    else if (pb < 640)  pack_core(pack_perm((pb - 256) * 256 + tid),  isb, w2c, 1024, r1,      512, 512, 1536, 512, p2);
    else if (pb < 1408) pack_core(pack_perm((pb - 640) * 256 + tid),  isb, w3c, 1024, r2,      512, 1024, 3072, 512, p3);
    else if (pb < 2944) pack_core(pack_perm((pb - 1408) * 256 + tid), isb, w4c, 2048, r3,      1024, 1024, 3072, 1024, p4);
    else                pack_core(pack_perm((pb - 2944) * 256 + tid), isb, w5c, 3072, nullptr, 3072, 2048, 2048, 3072, p5);
}

// ---- Gram core: MFMA from k-packed X; LDS passed in (2 x 8192 shorts) -------
__device__ __forceinline__ void gram_core(int b, int tid, short* __restrict__ Bs,
                                          const bf16* __restrict__ X, int C,
                                          float* __restrict__ G) {
    int lane = tid & 63, wv = tid >> 6, wm = wv & 1, wn = wv >> 1;
    int lq = lane >> 4, lr = lane & 15;
    int KC = C >> 6;
    const short* Xs = (const short*)X;

    float4v acc[4][4];
#pragma unroll
    for (int i = 0; i < 4; i++)
#pragma unroll
        for (int j = 0; j < 4; j++) acc[i][j] = (float4v){0.f, 0.f, 0.f, 0.f};

#pragma unroll
    for (int it = 0; it < 4; ++it) {
        int i = tid + it * 256;
        int q = i >> 7, c = i & 127;
        gll16(Xs + ((size_t)q * BN_ALL + b * 128 + c) * 8, Bs + (size_t)i * 8);
    }
    __syncthreads();

    int p = 0;
    for (int kc = 0; kc < KC; ++kc) {
        if (kc + 1 < KC) {
#pragma unroll
            for (int it = 0; it < 4; ++it) {
                int i = tid + it * 256;
                int q = i >> 7, c = i & 127;
                gll16(Xs + ((size_t)((kc + 1) * 8 + q) * BN_ALL + b * 128 + c) * 8,
                      Bs + (size_t)(p ^ 1) * 8192 + (size_t)i * 8);
            }
        }
        const short* Bp = Bs + (size_t)p * 8192;
#pragma unroll
        for (int h = 0; h < 2; ++h) {
            short8 av[4], bv[4];
#pragma unroll
            for (int mt = 0; mt < 4; ++mt)
                av[mt] = *(const short8*)&Bp[(size_t)(h * 512 + (lq << 7) + wm * 64 + mt * 16 + lr) * 8];
#pragma unroll
            for (int nt = 0; nt < 4; ++nt)
                bv[nt] = *(const short8*)&Bp[(size_t)(h * 512 + (lq << 7) + wn * 64 + nt * 16 + lr) * 8];
#pragma unroll
            for (int mt = 0; mt < 4; ++mt)
#pragma unroll
                for (int nt = 0; nt < 4; ++nt)
                    acc[mt][nt] = __builtin_amdgcn_mfma_f32_16x16x32_bf16(av[mt], bv[nt], acc[mt][nt], 0, 0, 0);
        }
        __syncthreads();
        p ^= 1;
    }

    float* Gb = G + (size_t)b * 16384;
#pragma unroll
    for (int mt = 0; mt < 4; ++mt)
#pragma unroll
        for (int r = 0; r < 4; ++r) {
            int row = wm * 64 + mt * 16 + lq * 4 + r;
#pragma unroll
            for (int nt = 0; nt < 4; ++nt) {
                int col = wn * 64 + nt * 16 + lr;
                Gb[row * 128 + col] = acc[mt][nt][r];
            }
        }
}

__global__ __launch_bounds__(256) void gram_k(const bf16* __restrict__ X, int C,
                                              float* __restrict__ G) {
    __shared__ __align__(16) short SMEM[16384];
    gram_core(blockIdx.x, threadIdx.x, SMEM, X, C, G);
}

// ---- top-20 core: one wave per (b,n) row; ties -> lower index ---------------
__device__ __forceinline__ void topk_core(int bid, int tid, const float* __restrict__ G,
                                          int* __restrict__ idx) {
    int gw = (bid * 256 + tid) >> 6;   // 0..2047 = b*128+n
    int lane = tid & 63;
    int b = gw >> 7, n = gw & 127;
    const float* Gb = G + (size_t)b * 16384;
    float g0 = Gb[n * 128 + lane];
    float g1 = Gb[n * 128 + 64 + lane];
    float dnn = Gb[n * 129];
    float dm0 = Gb[lane * 129];
    float dm1 = Gb[(64 + lane) * 129];
    float d0 = 2.f * g0 - dnn - dm0;
    float d1 = 2.f * g1 - dnn - dm1;
#pragma unroll
    for (int k = 0; k < 20; ++k) {
        float v; int i;
        if (d1 > d0) { v = d1; i = 64 + lane; } else { v = d0; i = lane; }
#pragma unroll
        for (int off = 1; off < 64; off <<= 1) {
            float ov = __shfl_xor(v, off, 64);
            int   oi = __shfl_xor(i, off, 64);
            if (ov > v || (ov == v && oi < i)) { v = ov; i = oi; }
        }
        if (lane == 0) idx[gw * 20 + k] = i;
        if (i < 64) { if (lane == i) d0 = -3.0e38f; }
        else        { if (lane == i - 64) d1 = -3.0e38f; }
    }
}

__global__ __launch_bounds__(256) void topk_k(const float* __restrict__ G, int* __restrict__ idx) {
    topk_core(blockIdx.x, threadIdx.x, G, idx);
}

// ---- gemm core: packed-A / k-packed-B bf16 MFMA, 128x64 tile, BK=64 ---------
// LDS passed in: As = lds (2 x 8192 shorts), Bs = lds + 16384 (2 x 4096).
__device__ __forceinline__ void gemm_core(int bx, int by, int tid, short* __restrict__ lds,
        const short* __restrict__ packA, const bf16* __restrict__ X,
        float* __restrict__ Cm, int K,
        const void* __restrict__ bnS, const void* __restrict__ bnB,
        int act, const int* __restrict__ dflag) {
    short* As = lds;            // 2 x 8192
    short* Bs = lds + 16384;    // 2 x 4096
    int bm  = bx << 7;
    int bn0 = by << 6;
    int lane = tid & 63, wv = tid >> 6, wm = wv & 1, wn = wv >> 1;
    int lq = lane >> 4, lr = lane & 15;
    int KC = K >> 6;
    const short* abase = packA + (size_t)bx * (K >> 5) * 4096;
    const short* Xs = (const short*)X;
    int bq = tid >> 6, bc = tid & 63;

    float4v acc[4][2];
#pragma unroll
    for (int i = 0; i < 4; i++)
#pragma unroll
        for (int j = 0; j < 2; j++) acc[i][j] = (float4v){0.f, 0.f, 0.f, 0.f};

#pragma unroll
    for (int it = 0; it < 4; ++it)
        gll16(abase + (size_t)(tid + it * 256) * 8, As + (size_t)(tid + it * 256) * 8);
    gll16(Xs + ((size_t)bq * BN_ALL + bn0 + bc) * 8,       Bs + (size_t)tid * 8);
    gll16(Xs + ((size_t)(bq + 4) * BN_ALL + bn0 + bc) * 8, Bs + (size_t)(tid + 256) * 8);
    __syncthreads();

    int p = 0;
    for (int kc = 0; kc < KC; ++kc) {
        if (kc + 1 < KC) {
            const short* ab = abase + (size_t)(kc + 1) * 8192;
#pragma unroll
            for (int it = 0; it < 4; ++it)
                gll16(ab + (size_t)(tid + it * 256) * 8,
                      As + (size_t)(p ^ 1) * 8192 + (size_t)(tid + it * 256) * 8);
            gll16(Xs + ((size_t)((kc + 1) * 8 + bq) * BN_ALL + bn0 + bc) * 8,
                  Bs + (size_t)(p ^ 1) * 4096 + (size_t)tid * 8);
            gll16(Xs + ((size_t)((kc + 1) * 8 + bq + 4) * BN_ALL + bn0 + bc) * 8,
                  Bs + (size_t)(p ^ 1) * 4096 + (size_t)(tid + 256) * 8);
        }
        const short* Ap = As + (size_t)p * 8192;
        const short* Bp = Bs + (size_t)p * 4096;
#pragma unroll
        for (int h = 0; h < 2; ++h) {
            short8 av[4], bv[2];
#pragma unroll
            for (int mt = 0; mt < 4; ++mt)
                av[mt] = *(const short8*)&Ap[(size_t)(h * 512 + (lq << 7) + wm * 64 + mt * 16 + lr) * 8];
#pragma unroll
            for (int nt = 0; nt < 2; ++nt)
                bv[nt] = *(const short8*)&Bp[(size_t)(h * 256 + (lq << 6) + wn * 32 + nt * 16 + lr) * 8];
#pragma unroll
            for (int mt = 0; mt < 4; ++mt)
#pragma unroll
                for (int nt = 0; nt < 2; ++nt)
                    acc[mt][nt] = __builtin_amdgcn_mfma_f32_16x16x32_bf16(av[mt], bv[nt], acc[mt][nt], 0, 0, 0);
        }
        __syncthreads();
        p ^= 1;
    }

    int isb = *dflag;
#pragma unroll
    for (int mt = 0; mt < 4; ++mt) {
#pragma unroll
        for (int r = 0; r < 4; ++r) {
            int row = bm + wm * 64 + mt * 16 + lq * 4 + r;
            float s = 1.f, bb = 0.f;
            if (bnS) { s = ldin(bnS, row, isb); bb = ldin(bnB, row, isb); }
#pragma unroll
            for (int nt = 0; nt < 2; ++nt) {
                int col = bn0 + wn * 32 + nt * 16 + lr;
                float v = acc[mt][nt][r];
                if (bnS) v = v * s + bb;
                if (act) v = lrelu(v);
                Cm[(size_t)row * BN_ALL + col] = v;
            }
        }
    }
}

__global__ __launch_bounds__(256) void gemm_pk(const short* __restrict__ packA,
                                               const bf16* __restrict__ X, float* __restrict__ Cm, int K,
                                               const void* __restrict__ bnS, const void* __restrict__ bnB,
                                               int act, const int* __restrict__ dflag) {
    __shared__ __align__(16) short SMEM[24576];
    gemm_core(blockIdx.x, blockIdx.y, threadIdx.x, SMEM, packA, X, Cm, K, bnS, bnB, act, dflag);
}

// ---- fused gram || gemm (tier P2): blocks [0,16)=gram, rest=gemm ------------
__global__ __launch_bounds__(256) void gram_gemm_k(const bf16* __restrict__ X, float* __restrict__ G,
                                                   const short* __restrict__ packA,
                                                   float* __restrict__ Cm, int K,
                                                   const int* __restrict__ dflag) {
    __shared__ __align__(16) short SMEM[24576];
    if (blockIdx.x < 16) {
        gram_core(blockIdx.x, threadIdx.x, SMEM, X, K, G);
    } else {
        int g = blockIdx.x - 16;
        gemm_core(g >> 5, g & 31, threadIdx.x, SMEM, packA, X, Cm, K, nullptr, nullptr, 0, dflag);
    }
}

// ---- legacy kNN (fallback tiers) --------------------------------------------
template <typename S>
__global__ __launch_bounds__(128) void knn_topk(const S* __restrict__ X, int C, int* __restrict__ idx) {
    int b = blockIdx.x >> 7;
    int n = blockIdx.x & 127;
    int m = threadIdx.x;
    const S* base = X + b * 128;
    float s0 = 0, s1 = 0, q0 = 0, q1 = 0;
    for (int c = 0; c < C; c += 2) {
        const S* p = base + (size_t)c * BN_ALL;
        float xm0 = ld1(p + m),          xn0 = ld1(p + n);
        float xm1 = ld1(p + BN_ALL + m), xn1 = ld1(p + BN_ALL + n);
        s0 += xm0 * xn0; q0 += xm0 * xm0;
        s1 += xm1 * xn1; q1 += xm1 * xm1;
    }
    float inner = s0 + s1;
    float xxm   = q0 + q1;
    __shared__ float xx[128];
    __shared__ float dist[128];
    __shared__ float rv[128];
    __shared__ int   ri[128];
    xx[m] = xxm;
    __syncthreads();
    dist[m] = 2.0f * inner - xx[n] - xxm;
    for (int k = 0; k < 20; k++) {
        __syncthreads();
        rv[m] = dist[m]; ri[m] = m;
        __syncthreads();
        for (int off = 64; off > 0; off >>= 1) {
            if (m < off) {
                float a = rv[m], bv = rv[m + off];
                int ia = ri[m], ib = ri[m + off];
                if (bv > a || (bv == a && ib < ia)) { rv[m] = bv; ri[m] = ib; }
            }
            __syncthreads();
        }
        if (m == 0) { idx[blockIdx.x * 20 + k] = ri[0]; dist[ri[0]] = -3.0e38f; }
    }
}

// ---- R5 fallback GEMM (on-the-fly staging, 128x128, linear layouts) ---------
template <typename S>
__global__ __launch_bounds__(256) void gemm_mfma(const void* __restrict__ w, int ldw,
                                                 const void* __restrict__ res, int Cin, int O,
                                                 const S* __restrict__ X, S* __restrict__ Cm, int K,
                                                 const void* __restrict__ bnS, const void* __restrict__ bnB,
                                                 int act, const int* __restrict__ dflag) {
    int isb = *dflag;
    __shared__ short Asm[4096];
    __shared__ short Bsm[4096];
    int tid = threadIdx.x;
    int bm  = blockIdx.x << 7;
    int bn0 = blockIdx.y << 7;
    int lane = tid & 63, wv = tid >> 6;
    int wm = wv & 1, wn = wv >> 1;
    int lq = lane >> 4, lr = lane & 15;

    float4v acc[4][4];
#pragma unroll
    for (int i = 0; i < 4; i++)
#pragma unroll
        for (int j = 0; j < 4; j++) acc[i][j] = (float4v){0.f, 0.f, 0.f, 0.f};

    for (int k0 = 0; k0 < K; k0 += 32) {
#pragma unroll
        for (int it = 0; it < 2; ++it) {
            int i = tid + it * 256;
            int m = i >> 2, q = i & 3;
            int grow = bm + m;
            const void* asrc; size_t abase; int dif = 0;
            if (grow < O)          { asrc = w;   abase = (size_t)grow * ldw; }
            else if (grow < 2 * O) { asrc = w;   abase = (size_t)(grow - O) * ldw; dif = 1; }
            else                   { asrc = res; abase = (size_t)(grow - 2 * O) * Cin; }
            size_t kk = (size_t)k0 + q * 8;
            short8 pk;
#pragma unroll
            for (int j = 0; j < 8; ++j) {
                float v = ldin(asrc, abase + kk + j, isb);
                if (dif) v = ldin(asrc, abase + Cin + kk + j, isb) - v;
                pk[j] = f2bs(v);
            }
            *(short8*)&Asm[(size_t)(q * 128 + m) * 8] = pk;
        }
#pragma unroll
        for (int it = 0; it < 2; ++it) {
            int i = tid + it * 256;
            int q = i >> 7, c = i & 127;
            const S* xp = X + (size_t)(k0 + q * 8) * BN_ALL + bn0 + c;
            short8 pk;
#pragma unroll
            for (int j = 0; j < 8; ++j) pk[j] = f2bs(ld1(xp + (size_t)j * BN_ALL));
            *(short8*)&Bsm[(size_t)i * 8] = pk;
        }
        __syncthreads();
        short8 av[4], bv[4];
#pragma unroll
        for (int mt = 0; mt < 4; ++mt)
            av[mt] = *(const short8*)&Asm[(size_t)((lq << 7) + wm * 64 + mt * 16 + lr) * 8];
#pragma unroll
        for (int nt = 0; nt < 4; ++nt)
            bv[nt] = *(const short8*)&Bsm[(size_t)((lq << 7) + wn * 64 + nt * 16 + lr) * 8];
#pragma unroll
        for (int mt = 0; mt < 4; ++mt)
#pragma unroll
            for (int nt = 0; nt < 4; ++nt)
                acc[mt][nt] = __builtin_amdgcn_mfma_f32_16x16x32_bf16(av[mt], bv[nt], acc[mt][nt], 0, 0, 0);
        __syncthreads();
    }
#pragma unroll
    for (int mt = 0; mt < 4; ++mt) {
#pragma unroll
        for (int r = 0; r < 4; ++r) {
            int row = bm + wm * 64 + mt * 16 + lq * 4 + r;
            float s = 1.f, bb = 0.f;
            if (bnS) { s = ldin(bnS, row, isb); bb = ldin(bnB, row, isb); }
#pragma unroll
            for (int nt = 0; nt < 4; ++nt) {
                int col = bn0 + wn * 64 + nt * 16 + lr;
                float v = acc[mt][nt][r];
                if (bnS) v = v * s + bb;
                if (act) v = lrelu(v);
                st1(Cm + (size_t)row * BN_ALL + col, v);
            }
        }
    }
}

// ---- gather + k-pool + bn + lrelu; T written IN-PLACE over P row o ----------
// one WAVE per (o,b) row; 2 n's per lane; barrier-free shfl_xor butterfly.
// R21: 20 neighbor indices loaded as 5x int4 (80B, 16B-aligned).
template <typename S>
__global__ __launch_bounds__(256) void gather_pool(S* __restrict__ PS, const int* __restrict__ idx,
                                                   const void* __restrict__ bns, const void* __restrict__ bnb,
                                                   float* __restrict__ Mb, int O,
                                                   const int* __restrict__ dflag) {
    int isb = *dflag;
    int wv = threadIdx.x >> 6, lane = threadIdx.x & 63;
    int gw = blockIdx.x * 4 + wv;          // gw = o*16 + b
    int o = gw >> 4, b = gw & 15;
    S* Prow = PS + (size_t)o * BN_ALL + b * 128;
    const S* Srow = PS + (size_t)(O + o) * BN_ALL + b * 128;
    int n0 = lane, n1 = lane + 64;
    const int4v* id0v = (const int4v*)(idx + (b * 128 + n0) * 20);
    const int4v* id1v = (const int4v*)(idx + (b * 128 + n1) * 20);
    int id0[20], id1[20];
#pragma unroll
    for (int t = 0; t < 5; ++t) {
        int4v v0 = id0v[t], v1 = id1v[t];
#pragma unroll
        for (int j = 0; j < 4; ++j) { id0[t * 4 + j] = v0[j]; id1[t * 4 + j] = v1[j]; }
    }
    float mx0 = -3.0e38f, mn0 = 3.0e38f, sm0 = 0.f;
    float mx1 = -3.0e38f, mn1 = 3.0e38f, sm1 = 0.f;
#pragma unroll
    for (int k = 0; k < 20; k++) {
        float p = ld1(Prow + id0[k]);
        mx0 = fmaxf(mx0, p); mn0 = fminf(mn0, p); sm0 += p;
    }
#pragma unroll
    for (int k = 0; k < 20; k++) {
        float p = ld1(Prow + id1[k]);
        mx1 = fmaxf(mx1, p); mn1 = fminf(mn1, p); sm1 += p;
    }
    float Sv0 = ld1(Srow + n0), Sv1 = ld1(Srow + n1);
    float s = ldin(bns, o, isb), bb = ldin(bnb, o, isb);
    float ext0 = (s >= 0.f) ? mx0 : mn0;
    float ext1 = (s >= 0.f) ? mx1 : mn1;
    float t0 = lrelu(s * (ext0 + Sv0) + bb);
    float t1 = lrelu(s * (ext1 + Sv1) + bb);
    st1(Prow + n0, t0);
    st1(Prow + n1, t1);
    float r1 = sm0 + sm1;    // == halving-tree step off=64
    float r2 = Sv0 + Sv1;
#pragma unroll
    for (int off = 32; off > 0; off >>= 1) {
        r1 += __shfl_xor(r1, off, 64);
        r2 += __shfl_xor(r2, off, 64);
    }
    if (lane == 0) Mb[b * O + o] = s * (r1 * (1.f / 2560.f) + r2 * (1.f / 128.f)) + bb;
}

// ---- SE stage 1: z[b,t] = relu(w1[t,:] . M[b,:]) — one wave per (b,t) -------
__global__ __launch_bounds__(256) void se1_k(const float* __restrict__ Mb, const void* __restrict__ w1,
                                             float* __restrict__ Z, int O, int r,
                                             const int* __restrict__ dflag) {
    int isb = *dflag;
    int gw = (blockIdx.x * 256 + threadIdx.x) >> 6;   // b*r + t
    int lane = threadIdx.x & 63;
    int b = gw / r, t = gw - b * r;
    const float* mv = Mb + (size_t)b * O;
    float acc = 0.f;
    for (int c = lane; c < O; c += 64) acc += ldin(w1, (size_t)t * O + c, isb) * mv[c];
#pragma unroll
    for (int off = 32; off > 0; off >>= 1) acc += __shfl_xor(acc, off, 64);
    if (lane == 0) Z[b * r + t] = fmaxf(acc, 0.f);
}

// ---- SE stage 2: Y[b,o] = sigmoid(w2[o,:] . z[b,:]) — one wave per (b,o) ----
__global__ __launch_bounds__(256) void se2_k(const float* __restrict__ Z, const void* __restrict__ w2,
                                             float* __restrict__ Y, int O, int r,
                                             const int* __restrict__ dflag) {
    int isb = *dflag;
    int gw = (blockIdx.x * 256 + threadIdx.x) >> 6;   // b*O + o
    int lane = threadIdx.x & 63;
    int b = gw / O, o = gw - b * O;
    float acc = 0.f;
    if (lane < r) acc = ldin(w2, (size_t)o * r + lane, isb) * Z[b * r + lane];
#pragma unroll
    for (int off = 32; off > 0; off >>= 1) acc += __shfl_xor(acc, off, 64);
    if (lane == 0) Y[b * O + o] = 1.f / (1.f + expf(-acc));
}

// ---- legacy SE (fallback tiers) ---------------------------------------------
__global__ __launch_bounds__(256) void se_k(const float* __restrict__ Mb, const void* __restrict__ w1,
                                            const void* __restrict__ w2, float* __restrict__ Y, int O, int r,
                                            const int* __restrict__ dflag) {
    int isb = *dflag;
    int b = blockIdx.x, t = threadIdx.x;
    __shared__ float mloc[1024];
    __shared__ float z[64];
    for (int i = t; i < O; i += 256) mloc[i] = Mb[b * O + i];
    __syncthreads();
    if (t < r) {
        float acc = 0.f;
        for (int c = 0; c < O; c++) acc += ldin(w1, (size_t)t * O + c, isb) * mloc[c];
        z[t] = fmaxf(acc, 0.f);
    }
    __syncthreads();
    for (int o = t; o < O; o += 256) {
        float acc = 0.f;
        for (int j = 0; j < r; j++) acc += ldin(w2, (size_t)o * r + j, isb) * z[j];
        Y[b * O + o] = 1.f / (1.f + expf(-acc));
    }
}

// ---- fused se2 + finalize (tier P2): Y recomputed in-block from Z -----------
__global__ __launch_bounds__(256) void finalize2_kp(const float* __restrict__ PS,
                                                    const float* __restrict__ Z,
                                                    const void* __restrict__ w2,
                                                    int useR, bf16* __restrict__ Xdst, int O, int r,
                                                    const int* __restrict__ dflag) {
    int isb = *dflag;
    int og = blockIdx.x >> 3;
    int b0 = (blockIdx.x & 7) * 2;
    __shared__ float Ysm[16];
    int wv = threadIdx.x >> 6, lane = threadIdx.x & 63;
#pragma unroll
    for (int s = 0; s < 4; ++s) {
        int pp = wv * 4 + s;              // 0..15
        int b = b0 + (pp >> 3);
        int o = og * 8 + (pp & 7);
        float acc = 0.f;
        if (lane < r) acc = ldin(w2, (size_t)o * r + lane, isb) * Z[b * r + lane];
#pragma unroll
        for (int off = 32; off > 0; off >>= 1) acc += __shfl_xor(acc, off, 64);
        if (lane == 0) Ysm[pp] = 1.f / (1.f + expf(-acc));
    }
    __syncthreads();
    int item = blockIdx.x * 256 + threadIdx.x;
    int bn = item & 2047;
    int b = bn >> 7;
    short8 pk;
#pragma unroll
    for (int j = 0; j < 8; ++j) {
        int rr = og * 8 + j;
        float v = Ysm[(b - b0) * 8 + j] * PS[(size_t)rr * BN_ALL + bn];
        if (useR) v += PS[(size_t)(2 * O + rr) * BN_ALL + bn];
        pk[j] = f2bs(v);
    }
    *(short8*)((short*)Xdst + ((size_t)og * BN_ALL + bn) * 8) = pk;
}

// ---- finalize (tier P): x_next = y*T (+res) -> k-packed bf16 slice ----------
__global__ __launch_bounds__(256) void finalize_kp(const float* __restrict__ PS, const float* __restrict__ Y,
                                                   int useR, bf16* __restrict__ Xdst, int O) {
    int item = blockIdx.x * 256 + threadIdx.x;   // og*2048 + bn  (og = o/8)
    int og = item >> 11, bn = item & 2047;
    int b = bn >> 7;
    short8 pk;
#pragma unroll
    for (int j = 0; j < 8; ++j) {
        int r = og * 8 + j;
        float v = Y[b * O + r] * PS[(size_t)r * BN_ALL + bn];
        if (useR) v += PS[(size_t)(2 * O + r) * BN_ALL + bn];
        pk[j] = f2bs(v);
    }
    *(short8*)((short*)Xdst + ((size_t)og * BN_ALL + bn) * 8) = pk;
}

// ---- legacy finalize (fallback tiers, linear layout) ------------------------
template <typename SP, typename SD>
__global__ __launch_bounds__(256) void finalize(const SP* __restrict__ PS, const float* __restrict__ Y,
                                                int useR, SD* __restrict__ Xdst, int O) {
    int tid = blockIdx.x * 256 + threadIdx.x;   // tid = o*2048 + bn
    int o = tid >> 11, bn = tid & 2047;
    int b = bn >> 7;
    float v = Y[b * O + o] * ld1(PS + tid);
    if (useR) v += ld1(PS + (size_t)(2 * O + o) * BN_ALL + bn);
    st1(Xdst + tid, v);
}

// ---- legacy convert (fallback tiers) ----------------------------------------
template <typename S>
__global__ __launch_bounds__(256) void convert_x(const void* __restrict__ x, S* __restrict__ X0,
                                                 const int* __restrict__ dflag) {
    int isb = *dflag;
    int tid = blockIdx.x * 256 + threadIdx.x;
    int c = tid >> 11, bn = tid & 2047;
    int b = bn >> 7, n = bn & 127;
    st1(X0 + tid, ldin(x, (size_t)(b * 512 + c) * 128 + n, isb));
}

// ---- conv5 pool: one WAVE per (m,b); barrier-free butterfly -----------------
template <typename S>
__global__ __launch_bounds__(256) void pool5(const S* __restrict__ H, float* __restrict__ f) {
    int wv = threadIdx.x >> 6, lane = threadIdx.x & 63;
    int gw = blockIdx.x * 4 + wv;          // gw = m*16 + b
    int m = gw >> 4, b = gw & 15;
    const S* Hp = H + (size_t)m * BN_ALL + b * 128;
    float v0 = ld1(Hp + lane), v1 = ld1(Hp + 64 + lane);
    float mx = fmaxf(v0, v1);
    float sm = v0 + v1;
#pragma unroll
    for (int off = 32; off > 0; off >>= 1) {
        mx = fmaxf(mx, __shfl_xor(mx, off, 64));
        sm += __shfl_xor(sm, off, 64);
    }
    if (lane == 0) {
        f[b * 4096 + m] = mx;
        f[b * 4096 + 2048 + m] = sm * (1.f / 128.f);
    }
}

// ---- head: one wave per (b,o) dot product + optional bias/bn/lrelu ----------
__global__ __launch_bounds__(256) void head_k(const float* __restrict__ in, const void* __restrict__ W,
                                              const void* __restrict__ bias, const void* __restrict__ bns,
                                              const void* __restrict__ bnb, float* __restrict__ outf,
                                              void* __restrict__ outb, int Kd, int Od, int act,
                                              const int* __restrict__ dflag) {
    int isb = *dflag;
    int gw = (blockIdx.x * 256 + threadIdx.x) >> 6;
    int lane = threadIdx.x & 63;
    if (gw >= 16 * Od) return;
    int b = gw / Od, o = gw - b * Od;
    const float* iv = in + b * Kd;
    float acc = 0.f;
    for (int k = lane; k < Kd; k += 64) acc += iv[k] * ldin(W, (size_t)o * Kd + k, isb);
    for (int off = 32; off > 0; off >>= 1) acc += __shfl_xor(acc, off, 64);
    if (lane == 0) {
        float v = acc;
        if (bias) v += ldin(bias, o, isb);
        if (bns) v = v * ldin(bns, o, isb) + ldin(bnb, o, isb);
        if (act) v = lrelu(v);
        if (outb) {
            if (isb) ((bf16*)outb)[gw] = __float2bfloat16(v);
            else     ((float*)outb)[gw] = v;
        } else outf[gw] = v;
    }
}

// ---- ws-too-small signal ----------------------------------------------------
__global__ __launch_bounds__(256) void zero_out(bf16* o, int n) {
    int i = blockIdx.x * 256 + threadIdx.x;
    if (i < n) o[i] = __float2bfloat16(0.f);
}

// ---------------------------------------------------------------------------
#define UNPACK_INPUTS()                                                     \
    const void* x_in   = d_in[0];                                           \
    const void* conv1w = d_in[1];  const void* conv2w = d_in[2];            \
    const void* conv3w = d_in[3];  const void* conv4w = d_in[4];            \
    const void* conv5w = d_in[5];                                           \
    const void* bn1s = d_in[6],  * bn1b = d_in[7];                          \
    const void* bn2s = d_in[8],  * bn2b = d_in[9];                          \
    const void* bn3s = d_in[10], * bn3b = d_in[11];                         \
    const void* bn4s = d_in[12], * bn4b = d_in[13];                         \
    const void* bn5s = d_in[14], * bn5b = d_in[15];                         \
    const void* se1w1 = d_in[16], * se1w2 = d_in[17];                       \
    const void* se2w1 = d_in[18], * se2w2 = d_in[19];                       \
    const void* se3w1 = d_in[20], * se3w2 = d_in[21];                       \
    const void* se4w1 = d_in[22], * se4w2 = d_in[23];                       \
    const void* res1w = d_in[24]; const void* res2w = d_in[25];             \
    const void* res3w = d_in[26]; const void* lin1w = d_in[27];             \
    const void* bn6s = d_in[28], * bn6b = d_in[29];                         \
    const void* lin2w = d_in[30], * lin2b = d_in[31];                       \
    const void* bn7s = d_in[32], * bn7b = d_in[33];                         \
    const void* lin3w = d_in[34], * lin3b = d_in[35];

// ---- Tier P2: packs upfront, gram||gemm, topk, gather, se1, se2+finalize ----
static void run_net_packed2(void* const* d_in, void* d_out, void* d_ws, hipStream_t stream) {
    UNPACK_INPUTS();
    float* WS = (float*)d_ws;
    float* PS = WS;                                   // 3072 x 2048 f32
    bf16*  XC = (bf16*)(WS + 6291456);                // 3072 x 2048 bf16 k-packed
    short* P1 = (short*)(WS + 12582912);              // 524288 shorts
    short* P2 = P1 + 524288;                          // 786432
    short* P3 = P2 + 786432;                          // 1572864
    short* P4 = P3 + 1572864;                         // 3145728
    short* P5 = P4 + 3145728;                         // 6291456  (ends @ float 18743296)
    float* MB = WS + 18743296;
    float* YB = MB + 16384;
    float* FB = YB + 16384;
    float* F1 = FB + 65536;
    float* F2 = F1 + 8192;
    int* IDX  = (int*)(F2 + 4096);
    int* DFLAG = IDX + 40960;
    float* ZB = (float*)(DFLAG + 16);                 // 1024 floats
    float* GRAM = WS + 18900000;                      // 262144 floats, dedicated
    bf16*  X0 = (bf16*)(PS + (size_t)2048 * BN_ALL);  // PS rows 2048.. (block 1 only)
    bf16* X1 = XC;
    bf16* X2 = XC + (size_t)512 * BN_ALL;
    bf16* X3 = XC + (size_t)1024 * BN_ALL;
    bf16* X4 = XC + (size_t)2048 * BN_ALL;

    detect_dtype<<<1, 256, 0, stream>>>(x_in, DFLAG);
    convert_pack_all<<<6528, 256, 0, stream>>>(x_in, X0,
        conv1w, conv2w, conv3w, conv4w, conv5w, res1w, res2w, res3w,
        P1, P2, P3, P4, P5, DFLAG);

    // block 1: O=512, Mtot=1024, K=512, r=32
    gram_gemm_k<<<16 + 8 * 32, 256, 0, stream>>>(X0, GRAM, P1, PS, 512, DFLAG);
    topk_k<<<512, 256, 0, stream>>>(GRAM, IDX);
    gather_pool<float><<<2048, 256, 0, stream>>>(PS, IDX, bn1s, bn1b, MB, 512, DFLAG);
    se1_k<<<128, 256, 0, stream>>>(MB, se1w1, ZB, 512, 32, DFLAG);
    finalize2_kp<<<512, 256, 0, stream>>>(PS, ZB, se1w2, 0, X1, 512, 32, DFLAG);

    // block 2: Mtot=1536, K=512, res1, r=32
    gram_gemm_k<<<16 + 12 * 32, 256, 0, stream>>>(X1, GRAM, P2, PS, 512, DFLAG);
    topk_k<<<512, 256, 0, stream>>>(GRAM, IDX);
    gather_pool<float><<<2048, 256, 0, stream>>>(PS, IDX, bn2s, bn2b, MB, 512, DFLAG);
    se1_k<<<128, 256, 0, stream>>>(MB, se2w1, ZB, 512, 32, DFLAG);
    finalize2_kp<<<512, 256, 0, stream>>>(PS, ZB, se2w2, 1, X2, 512, 32, DFLAG);

    // block 3: O=1024, Mtot=3072, K=512, res2, r=64
    gram_gemm_k<<<16 + 24 * 32, 256, 0, stream>>>(X2, GRAM, P3, PS, 512, DFLAG);
    topk_k<<<512, 256, 0, stream>>>(GRAM, IDX);
    gather_pool<float><<<4096, 256, 0, stream>>>(PS, IDX, bn3s, bn3b, MB, 1024, DFLAG);
    se1_k<<<256, 256, 0, stream>>>(MB, se3w1, ZB, 1024, 64, DFLAG);
    finalize2_kp<<<1024, 256, 0, stream>>>(PS, ZB, se3w2, 1, X3, 1024, 64, DFLAG);

    // block 4: O=1024, Mtot=3072, K=1024, res3, r=64
    gram_gemm_k<<<16 + 24 * 32, 256, 0, stream>>>(X3, GRAM, P4, PS, 1024, DFLAG);
    topk_k<<<512, 256, 0, stream>>>(GRAM, IDX);
    gather_pool<float><<<4096, 256, 0, stream>>>(PS, IDX, bn4s, bn4b, MB, 1024, DFLAG);
    se1_k<<<256, 256, 0, stream>>>(MB, se4w1, ZB, 1024, 64, DFLAG);
    finalize2_kp<<<1024, 256, 0, stream>>>(PS, ZB, se4w2, 1, X4, 1024, 64, DFLAG);

    // conv5: Mtot=2048, K=3072, bn5+lrelu
    gemm_pk<<<dim3(16, 32), 256, 0, stream>>>(P5, XC, PS, 3072, bn5s, bn5b, 1, DFLAG);
    pool5<float><<<8192, 256, 0, stream>>>(PS, FB);

    head_k<<<2048, 256, 0, stream>>>(FB, lin1w, nullptr, bn6s, bn6b, F1, nullptr, 4096, 512, 1, DFLAG);
    head_k<<<1024, 256, 0, stream>>>(F1, lin2w, lin2b, bn7s, bn7b, F2, nullptr, 512, 256, 1, DFLAG);
    head_k<<<160, 256, 0, stream>>>(F2, lin3w, lin3b, nullptr, nullptr, nullptr, d_out, 256, 40, 0, DFLAG);
}

// ---- Tier P: R15 path (fallback when ws < P2 but >= 63MB) -------------------
static void run_net_packed(void* const* d_in, void* d_out, void* d_ws, hipStream_t stream) {
    UNPACK_INPUTS();
    float* WS = (float*)d_ws;
    float* PS   = WS;
    bf16*  XC   = (bf16*)(WS + 6291456);
    short* PACK = (short*)(WS + 12582912);
    float* MB = WS + 15728640;
    float* YB = MB + 16384;
    float* FB = YB + 16384;
    float* F1 = FB + 65536;
    float* F2 = F1 + 8192;
    int* IDX  = (int*)(F2 + 4096);
    int* DFLAG = IDX + 40960;
    float* ZB = (float*)(DFLAG + 16);
    bf16*  X0 = (bf16*)(PS + (size_t)2048 * BN_ALL);
    float* GRAM = PS;
    bf16* X1 = XC;
    bf16* X2 = XC + (size_t)512 * BN_ALL;
    bf16* X3 = XC + (size_t)1024 * BN_ALL;
    bf16* X4 = XC + (size_t)2048 * BN_ALL;

    detect_dtype<<<1, 256, 0, stream>>>(x_in, DFLAG);
    convert_kp<<<512, 256, 0, stream>>>(x_in, X0, DFLAG);

    gram_k<<<16, 256, 0, stream>>>(X0, 512, GRAM);
    topk_k<<<512, 256, 0, stream>>>(GRAM, IDX);
    pack_w<<<256, 256, 0, stream>>>(conv1w, 1024, nullptr, 512, 512, 1024, 512, PACK, DFLAG);
    gemm_pk<<<dim3(8, 32), 256, 0, stream>>>(PACK, X0, PS, 512, nullptr, nullptr, 0, DFLAG);
    gather_pool<float><<<2048, 256, 0, stream>>>(PS, IDX, bn1s, bn1b, MB, 512, DFLAG);
    se1_k<<<128, 256, 0, stream>>>(MB, se1w1, ZB, 512, 32, DFLAG);
    se2_k<<<2048, 256, 0, stream>>>(ZB, se1w2, YB, 512, 32, DFLAG);
    finalize_kp<<<512, 256, 0, stream>>>(PS, YB, 0, X1, 512);

    gram_k<<<16, 256, 0, stream>>>(X1, 512, GRAM);
    topk_k<<<512, 256, 0, stream>>>(GRAM, IDX);
    pack_w<<<384, 256, 0, stream>>>(conv2w, 1024, res1w, 512, 512, 1536, 512, PACK, DFLAG);
    gemm_pk<<<dim3(12, 32), 256, 0, stream>>>(PACK, X1, PS, 512, nullptr, nullptr, 0, DFLAG);
    gather_pool<float><<<2048, 256, 0, stream>>>(PS, IDX, bn2s, bn2b, MB, 512, DFLAG);
    se1_k<<<128, 256, 0, stream>>>(MB, se2w1, ZB, 512, 32, DFLAG);
    se2_k<<<2048, 256, 0, stream>>>(ZB, se2w2, YB, 512, 32, DFLAG);
    finalize_kp<<<512, 256, 0, stream>>>(PS, YB, 1, X2, 512);

    gram_k<<<16, 256, 0, stream>>>(X2, 512, GRAM);
    topk_k<<<512, 256, 0, stream>>>(GRAM, IDX);
    pack_w<<<768, 256, 0, stream>>>(conv3w, 1024, res2w, 512, 1024, 3072, 512, PACK, DFLAG);
    gemm_pk<<<dim3(24, 32), 256, 0, stream>>>(PACK, X2, PS, 512, nullptr, nullptr, 0, DFLAG);
    gather_pool<float><<<4096, 256, 0, stream>>>(PS, IDX, bn3s, bn3b, MB, 1024, DFLAG);
    se1_k<<<256, 256, 0, stream>>>(MB, se3w1, ZB, 1024, 64, DFLAG);
    se2_k<<<4096, 256, 0, stream>>>(ZB, se3w2, YB, 1024, 64, DFLAG);
    finalize_kp<<<1024, 256, 0, stream>>>(PS, YB, 1, X3, 1024);

    gram_k<<<16, 256, 0, stream>>>(X3, 1024, GRAM);
    topk_k<<<512, 256, 0, stream>>>(GRAM, IDX);
    pack_w<<<1536, 256, 0, stream>>>(conv4w, 2048, res3w, 1024, 1024, 3072, 1024, PACK, DFLAG);
    gemm_pk<<<dim3(24, 32), 256, 0, stream>>>(PACK, X3, PS, 1024, nullptr, nullptr, 0, DFLAG);
    gather_pool<float><<<4096, 256, 0, stream>>>(PS, IDX, bn4s, bn4b, MB, 1024, DFLAG);
    se1_k<<<256, 256, 0, stream>>>(MB, se4w1, ZB, 1024, 64, DFLAG);
    se2_k<<<4096, 256, 0, stream>>>(ZB, se4w2, YB, 1024, 64, DFLAG);
    finalize_kp<<<1024, 256, 0, stream>>>(PS, YB, 1, X4, 1024);

    pack_w<<<3072, 256, 0, stream>>>(conv5w, 3072, nullptr, 3072, 2048, 2048, 3072, PACK, DFLAG);
    gemm_pk<<<dim3(16, 32), 256, 0, stream>>>(PACK, XC, PS, 3072, bn5s, bn5b, 1, DFLAG);
    pool5<float><<<8192, 256, 0, stream>>>(PS, FB);

    head_k<<<2048, 256, 0, stream>>>(FB, lin1w, nullptr, bn6s, bn6b, F1, nullptr, 4096, 512, 1, DFLAG);
    head_k<<<1024, 256, 0, stream>>>(F1, lin2w, lin2b, bn7s, bn7b, F2, nullptr, 512, 256, 1, DFLAG);
    head_k<<<160, 256, 0, stream>>>(F2, lin3w, lin3b, nullptr, nullptr, nullptr, d_out, 256, 40, 0, DFLAG);
}

// ---- Tier A/B fallback (R5 path, linear layouts) ----------------------------
template <typename S>
static void run_net(void* const* d_in, void* d_out, void* d_ws, hipStream_t stream) {
    UNPACK_INPUTS();
    const size_t RC = (size_t)3072 * BN_ALL;
    S* PS = (S*)d_ws;
    S* XC = PS + RC;
    S* X0 = PS + (size_t)2048 * BN_ALL;
    float* MB = (float*)(XC + RC);
    float* YB = MB + 16 * 1024;
    float* FB = YB + 16 * 1024;
    float* F1 = FB + 16 * 4096;
    float* F2 = F1 + 16 * 512;
    int* IDX  = (int*)(F2 + 16 * 256);
    int* DFLAG = IDX + 16 * 128 * 20;

    S* X1 = XC;
    S* X2 = XC + (size_t)512 * BN_ALL;
    S* X3 = XC + (size_t)1024 * BN_ALL;
    S* X4 = XC + (size_t)2048 * BN_ALL;

    detect_dtype<<<1, 256, 0, stream>>>(x_in, DFLAG);
    convert_x<S><<<4096, 256, 0, stream>>>(x_in, X0, DFLAG);

    knn_topk<S><<<2048, 128, 0, stream>>>(X0, 512, IDX);
    gemm_mfma<S><<<dim3(8, 16), 256, 0, stream>>>(conv1w, 1024, nullptr, 512, 512, X0, PS, 512, nullptr, nullptr, 0, DFLAG);
    gather_pool<S><<<2048, 256, 0, stream>>>(PS, IDX, bn1s, bn1b, MB, 512, DFLAG);
    se_k<<<16, 256, 0, stream>>>(MB, se1w1, se1w2, YB, 512, 32, DFLAG);
    finalize<S, S><<<4096, 256, 0, stream>>>(PS, YB, 0, X1, 512);

    knn_topk<S><<<2048, 128, 0, stream>>>(X1, 512, IDX);
    gemm_mfma<S><<<dim3(12, 16), 256, 0, stream>>>(conv2w, 1024, res1w, 512, 512, X1, PS, 512, nullptr, nullptr, 0, DFLAG);
    gather_pool<S><<<2048, 256, 0, stream>>>(PS, IDX, bn2s, bn2b, MB, 512, DFLAG);
    se_k<<<16, 256, 0, stream>>>(MB, se2w1, se2w2, YB, 512, 32, DFLAG);
    finalize<S, S><<<4096, 256, 0, stream>>>(PS, YB, 1, X2, 512);

    knn_topk<S><<<2048, 128, 0, stream>>>(X2, 512, IDX);
    gemm_mfma<S><<<dim3(24, 16), 256, 0, stream>>>(conv3w, 1024, res2w, 512, 1024, X2, PS, 512, nullptr, nullptr, 0, DFLAG);
    gather_pool<S><<<4096, 256, 0, stream>>>(PS, IDX, bn3s, bn3b, MB, 1024, DFLAG);
    se_k<<<16, 256, 0, stream>>>(MB, se3w1, se3w2, YB, 1024, 64, DFLAG);
    finalize<S, S><<<8192, 256, 0, stream>>>(PS, YB, 1, X3, 1024);

    knn_topk<S><<<2048, 128, 0, stream>>>(X3, 1024, IDX);
    gemm_mfma<S><<<dim3(24, 16), 256, 0, stream>>>(conv4w, 2048, res3w, 1024, 1024, X3, PS, 1024, nullptr, nullptr, 0, DFLAG);
    gather_pool<S><<<4096, 256, 0, stream>>>(PS, IDX, bn4s, bn4b, MB, 1024, DFLAG);
    se_k<<<16, 256, 0, stream>>>(MB, se4w1, se4w2, YB, 1024, 64, DFLAG);
    finalize<S, S><<<8192, 256, 0, stream>>>(PS, YB, 1, X4, 1024);

    gemm_mfma<S><<<dim3(16, 16), 256, 0, stream>>>(conv5w, 3072, nullptr, 3072, 2048, XC, PS, 3072, bn5s, bn5b, 1, DFLAG);
    pool5<S><<<8192, 256, 0, stream>>>(PS, FB);

    head_k<<<2048, 256, 0, stream>>>(FB, lin1w, nullptr, bn6s, bn6b, F1, nullptr, 4096, 512, 1, DFLAG);
    head_k<<<1024, 256, 0, stream>>>(F1, lin2w, lin2b, bn7s, bn7b, F2, nullptr, 512, 256, 1, DFLAG);
    head_k<<<160, 256, 0, stream>>>(F2, lin3w, lin3b, nullptr, nullptr, nullptr, d_out, 256, 40, 0, DFLAG);
}

extern "C" void kernel_launch(void* const* d_in, const int* in_sizes, int n_in,
                              void* d_out, int out_size, void* d_ws, size_t ws_size,
                              hipStream_t stream) {
    const size_t SMALL = (16 * 1024 + 16 * 1024 + 16 * 4096 + 16 * 512 + 16 * 256) * 4
                       + 16 * 128 * 20 * 4 + 8192;
    const size_t NEED_P2     = ((size_t)18900000 + 262144 + 4096) * 4;   // ~76.7MB
    const size_t NEED_PACKED = (size_t)15728640 * 4 + SMALL;
    const size_t NEED_F32    = 2 * ((size_t)3072 * BN_ALL * 4) + SMALL;
    const size_t NEED_BF16   = 2 * ((size_t)3072 * BN_ALL * 2) + SMALL;
    if (ws_size >= NEED_P2) {
        run_net_packed2(d_in, d_out, d_ws, stream);
    } else if (ws_size >= NEED_PACKED) {
        run_net_packed(d_in, d_out, d_ws, stream);
    } else if (ws_size >= NEED_F32) {
        run_net<float>(d_in, d_out, d_ws, stream);
    } else if (ws_size >= NEED_BF16) {
        run_net<bf16>(d_in, d_out, d_ws, stream);
    } else {
        zero_out<<<3, 256, 0, stream>>>((bf16*)d_out, out_size);
    }
}